// Round 6
// baseline (5963.226 us; speedup 1.0000x reference)
//
#include <hip/hip_runtime.h>

typedef unsigned short u16;

__device__ __forceinline__ float bf2f(u16 h){
  union { unsigned u; float f; } v; v.u = ((unsigned)h) << 16; return v.f;
}
__device__ __forceinline__ u16 f2bf(float f){
  union { float f; unsigned u; } v; v.f = f;
  unsigned u = v.u;
  return (u16)((u + 0x7fffu + ((u >> 16) & 1u)) >> 16);
}

#define WREDUCE64(s) { s += __shfl_xor(s,1); s += __shfl_xor(s,2); s += __shfl_xor(s,4); \
                       s += __shfl_xor(s,8); s += __shfl_xor(s,16); s += __shfl_xor(s,32); }
#define QREDUCE16(s) { s += __shfl_xor(s,1); s += __shfl_xor(s,2); s += __shfl_xor(s,4); s += __shfl_xor(s,8); }

// ---------------- r per edge ----------------
__global__ __launch_bounds__(256) void k_r(const float* evec, float* r_arr, int E){
  int e = blockIdx.x*256 + threadIdx.x;
  if(e >= E) return;
  float vx = evec[(size_t)e*3+0], vy = evec[(size_t)e*3+1], vz = evec[(size_t)e*3+2];
  r_arr[e] = sqrtf(vx*vx + vy*vy + vz*vz);
}

// ---------------- rbf[e][j] = exp(-(r - 10j/63)^2 * 81.92) ----------------
__global__ __launch_bounds__(256) void k_rbf(const float* r_arr, u16* rbfb, int E){
  int tid = blockIdx.x*256 + threadIdx.x;
  if(tid >= E*64) return;
  int e = tid >> 6, j = tid & 63;
  float d = r_arr[e] - (10.f/63.f)*(float)j;
  rbfb[tid] = f2bf(__expf(-81.92f*d*d));
}

// ---------------- x = ele[atom] @ W_embed (K=32) ----------------
__global__ __launch_bounds__(256) void k_embed(const int* atom, const float* ele, const float* W, float* xb, int N){
  int idx = blockIdx.x*256 + threadIdx.x;
  if(idx >= N*64) return;
  int m = idx >> 6, col = idx & 63;
  int a = atom[m]*32;
  float acc = 0.f;
  #pragma unroll 8
  for(int k=0;k<32;k++) acc += ele[a+k] * W[k*64+col];
  xb[idx] = acc;
}

// ---------------- e = [nf_src, nf_dst, sh, rbf] @ W_edge ----------------
__global__ __launch_bounds__(256) void k_edge_embed(const int* srcI, const int* dstI, const int* atom,
    const float* ele, const float* evec, const u16* rbfb, const float* W, u16* ebf, int E){
  int idx = blockIdx.x*256 + threadIdx.x;
  if(idx >= E*64) return;
  int e = idx >> 6, col = idx & 63;
  float acc = 0.f;
  int sa = atom[srcI[e]]*32, da = atom[dstI[e]]*32;
  #pragma unroll 8
  for(int k=0;k<32;k++) acc += ele[sa+k] * W[k*64+col];
  #pragma unroll 8
  for(int k=0;k<32;k++) acc += ele[da+k] * W[(32+k)*64+col];
  // spherical harmonics: u = vec[[1,2,0]]/r -> x=v1, y=v2, z=v0
  float vx = evec[(size_t)e*3+0], vy = evec[(size_t)e*3+1], vz = evec[(size_t)e*3+2];
  float r = sqrtf(vx*vx + vy*vy + vz*vz);
  float inv = 1.f/(r + 1e-12f);
  float x = vy*inv, y = vz*inv, z = vx*inv;
  const float s3 = 1.7320508075688772f, s15 = 3.872983346207417f;
  const float s5h = 1.118033988749895f, s15h = 1.9364916731037085f;
  float sh[9];
  sh[0] = 1.f; sh[1] = s3*x; sh[2] = s3*y; sh[3] = s3*z;
  sh[4] = s15*x*y; sh[5] = s15*y*z; sh[6] = s5h*(3.f*z*z - 1.f);
  sh[7] = s15*x*z; sh[8] = s15h*(x*x - y*y);
  #pragma unroll
  for(int i=0;i<9;i++) acc += sh[i] * W[(64+i)*64+col];
  #pragma unroll 8
  for(int j=0;j<64;j++) acc += bf2f(rbfb[(size_t)e*64+j]) * W[(73+j)*64+col];
  ebf[idx] = f2bf(acc);
}

// ---------------- LN over 64, f32 out (optional relu) ----------------
__global__ __launch_bounds__(256) void k_ln64(const float* x, float* out, int N){
  int wave = (blockIdx.x*256 + threadIdx.x) >> 6;
  int lane = threadIdx.x & 63;
  if(wave >= N) return;
  float v = x[(size_t)wave*64 + lane];
  float s = v; WREDUCE64(s);
  float m = s*(1.f/64.f);
  float d = v - m;
  float s2 = d*d; WREDUCE64(s2);
  out[(size_t)wave*64 + lane] = d * rsqrtf(s2*(1.f/64.f) + 1e-6f);
}
__global__ __launch_bounds__(256) void k_lnrelu64(const float* x, float* out, int N){
  int wave = (blockIdx.x*256 + threadIdx.x) >> 6;
  int lane = threadIdx.x & 63;
  if(wave >= N) return;
  float v = x[(size_t)wave*64 + lane];
  float s = v; WREDUCE64(s);
  float m = s*(1.f/64.f);
  float d = v - m;
  float s2 = d*d; WREDUCE64(s2);
  out[(size_t)wave*64 + lane] = fmaxf(d * rsqrtf(s2*(1.f/64.f) + 1e-6f), 0.f);
}

// ---------------- generic dense: out[m][n] = sum_k A[m][k]*W[k][n], K=64 ----------------
__global__ __launch_bounds__(256) void k_gemm64(const float* A, const float* W, float* out, int N){
  int idx = blockIdx.x*256 + threadIdx.x;
  if(idx >= N*64) return;
  int m = idx >> 6, n = idx & 63;
  const float* a = A + (size_t)m*64;
  float acc = 0.f;
  #pragma unroll 8
  for(int k=0;k<64;k++) acc += a[k] * W[k*64+n];
  out[idx] = acc;
}
// out += A@W (residual)
__global__ __launch_bounds__(256) void k_gemm64_add(const float* A, const float* W, float* x, int N){
  int idx = blockIdx.x*256 + threadIdx.x;
  if(idx >= N*64) return;
  int m = idx >> 6, n = idx & 63;
  const float* a = A + (size_t)m*64;
  float acc = 0.f;
  #pragma unroll 8
  for(int k=0;k<64;k++) acc += a[k] * W[k*64+n];
  x[idx] += acc;
}
// out = A@W + bias (64x64)
__global__ __launch_bounds__(256) void k_gemm64_bias(const float* A, const float* W, const float* bias, float* out, int N){
  int idx = blockIdx.x*256 + threadIdx.x;
  if(idx >= N*64) return;
  int m = idx >> 6, n = idx & 63;
  const float* a = A + (size_t)m*64;
  float acc = bias[n];
  #pragma unroll 8
  for(int k=0;k<64;k++) acc += a[k] * W[k*64+n];
  out[idx] = acc;
}

// ---------------- radial: wave per edge; lane j computes hid[j]; 4 reductions ----------------
__global__ __launch_bounds__(256) void k_radial(const u16* rbfb, const float* Wr1, const float* Wr2, float* radial, int E){
  int e = (blockIdx.x*256 + threadIdx.x) >> 6;
  int j = threadIdx.x & 63;
  if(e >= E) return;
  float acc = 0.f;
  #pragma unroll 8
  for(int k=0;k<64;k++) acc += bf2f(rbfb[(size_t)e*64+k]) * Wr1[k*64+j];
  float sv = acc / (1.f + __expf(-acc));
  #pragma unroll
  for(int h=0;h<4;h++){
    float t = sv * Wr2[j*4+h];
    WREDUCE64(t);
    if(j == h) radial[(size_t)e*4+h] = t;
  }
}

// ---------------- k,v + logits: wave per edge; lane n ----------------
__global__ __launch_bounds__(256) void k_kv_logits(const float* hbuf, const u16* ebf, const int* srcI, const int* dstI,
    const float* Qb, const float* radial, const float* r_arr, const float* Wk, const float* Wv,
    u16* vbf, float* exb, int E){
  int e = (blockIdx.x*256 + threadIdx.x) >> 6;
  int n = threadIdx.x & 63;
  if(e >= E) return;
  int src = srcI[e], dst = dstI[e];
  const float* hr = hbuf + (size_t)src*64;
  const u16*  er = ebf + (size_t)e*64;
  float kacc = 0.f, vacc = 0.f;
  #pragma unroll 8
  for(int k=0;k<64;k++){
    float s = hr[k] + bf2f(er[k]);
    kacc += s * Wk[k*64+n];
    vacc += s * Wv[k*64+n];
  }
  vbf[(size_t)e*64+n] = f2bf(vacc);
  float t = kacc * Qb[(size_t)dst*64+n];
  QREDUCE16(t);
  if((n & 15) == 0){
    int h = n >> 4;
    float logit = t*0.25f + radial[(size_t)e*4+h];
    exb[(size_t)e*4+h] = (r_arr[e] < 10.f) ? __expf(logit) : 0.f;
  }
}

// ---------------- CSR build ----------------
__global__ __launch_bounds__(256) void k_count(const int* dstI, int* deg, int E){
  int tid = blockIdx.x*256 + threadIdx.x;
  if(tid < E) atomicAdd(&deg[dstI[tid]], 1);
}
__global__ __launch_bounds__(1024) void k_scan(const int* deg, int* rowptr, int* cursor, int N){
  __shared__ int wsum[17];
  int tid = threadIdx.x;
  int per = (N + 1023) >> 10;
  int base = tid * per;
  int s = 0;
  for(int i=0;i<per;i++){ int idx = base+i; if(idx < N) s += deg[idx]; }
  int lane = tid & 63, wid = tid >> 6;
  int inc = s;
  for(int d=1; d<64; d<<=1){
    int t = __shfl_up(inc, d);
    if(lane >= d) inc += t;
  }
  if(lane == 63) wsum[wid+1] = inc;
  if(tid == 0) wsum[0] = 0;
  __syncthreads();
  if(tid == 0){ for(int w=1; w<=16; w++) wsum[w] += wsum[w-1]; }
  __syncthreads();
  int run = inc - s + wsum[wid];
  for(int i=0;i<per;i++){
    int idx = base + i;
    if(idx < N){ rowptr[idx] = run; cursor[idx] = run; run += deg[idx]; }
  }
  if(tid == 1023) rowptr[N] = wsum[16];
}
__global__ __launch_bounds__(256) void k_scatter(const int* dstI, int* cursor, int* csr, int E){
  int tid = blockIdx.x*256 + threadIdx.x;
  if(tid < E){
    int p = atomicAdd(&cursor[dstI[tid]], 1);
    csr[p] = tid;
  }
}

// ---------------- softmax-denominator + aggregation (wave per node) ----------------
__global__ __launch_bounds__(256) void k_agg(const int* rowptr, const int* csr, const float* exb, const u16* vbf, float* aggb, int N){
  int wave = (blockIdx.x*256 + threadIdx.x) >> 6;
  int lane = threadIdx.x & 63;
  if(wave >= N) return;
  int s0 = rowptr[wave], s1 = rowptr[wave+1];
  float s[4] = {0.f,0.f,0.f,0.f};
  for(int p = s0 + lane; p < s1; p += 64){
    int e = csr[p];
    float4 ev = *reinterpret_cast<const float4*>(exb + (size_t)e*4);
    s[0] += ev.x; s[1] += ev.y; s[2] += ev.z; s[3] += ev.w;
  }
  #pragma unroll
  for(int i=0;i<4;i++){ WREDUCE64(s[i]); }
  int h = lane >> 4;
  float sumh = (h==0)?s[0]:(h==1)?s[1]:(h==2)?s[2]:s[3];
  float invh = 1.f/(sumh + 1e-9f);
  float acc = 0.f;
  for(int p = s0; p < s1; p++){
    int e = csr[p];
    acc += exb[(size_t)e*4 + h] * bf2f(vbf[(size_t)e*64 + lane]);
  }
  aggb[(size_t)wave*64 + lane] = acc * invh;
}

// ---------------- FFN ----------------
__global__ __launch_bounds__(256) void k_ffn1(const float* A, const float* W1, float* tb, int N){
  int idx = blockIdx.x*256 + threadIdx.x;
  if(idx >= N*256) return;
  int m = idx >> 8, j = idx & 255;
  const float* a = A + (size_t)m*64;
  float acc = 0.f;
  #pragma unroll 8
  for(int k=0;k<64;k++) acc += a[k] * W1[k*256+j];
  tb[idx] = acc / (1.f + __expf(-acc));
}
__global__ __launch_bounds__(256) void k_ffn2(const float* tb, const float* W2, float* x, int N){
  int idx = blockIdx.x*256 + threadIdx.x;
  if(idx >= N*64) return;
  int m = idx >> 6, n = idx & 63;
  const float* a = tb + (size_t)m*256;
  float acc = 0.f;
  #pragma unroll 8
  for(int k=0;k<256;k++) acc += a[k] * W2[k*64+n];
  x[idx] += acc;
}

// ---------------- feat = x @ W_feat ----------------
__global__ __launch_bounds__(256) void k_feat(const float* xb, const float* Wf, float* out, int N){
  int idx = blockIdx.x*256 + threadIdx.x;
  if(idx >= N*512) return;
  int m = idx >> 9, j = idx & 511;
  const float* a = xb + (size_t)m*64;
  float acc = 0.f;
  #pragma unroll 8
  for(int k=0;k<64;k++) acc += a[k] * Wf[k*512+j];
  out[idx] = acc;
}

// ---------------- LN over 512, f32 out ----------------
__global__ __launch_bounds__(256) void k_ln512(const float* fr, float* out, int N){
  int wave = (blockIdx.x*256 + threadIdx.x) >> 6;
  int lane = threadIdx.x & 63;
  if(wave >= N) return;
  const float* row = fr + (size_t)wave*512 + lane*8;
  float v[8];
  #pragma unroll
  for(int i=0;i<8;i++) v[i] = row[i];
  float s = 0.f;
  #pragma unroll
  for(int i=0;i<8;i++) s += v[i];
  WREDUCE64(s);
  float m = s*(1.f/512.f);
  float vv = 0.f;
  #pragma unroll
  for(int i=0;i<8;i++){ float d = v[i]-m; vv += d*d; }
  WREDUCE64(vv);
  float rs = rsqrtf(vv*(1.f/512.f) + 1e-6f);
  float* orow = out + (size_t)wave*512 + lane*8;
  #pragma unroll
  for(int i=0;i<8;i++) orow[i] = (v[i]-m)*rs;
}

// ---------------- head1: y1 = featn @ hW1 + hb1 (K=512) ----------------
__global__ __launch_bounds__(256) void k_head1(const float* A, const float* W, const float* bias, float* out, int N){
  int idx = blockIdx.x*256 + threadIdx.x;
  if(idx >= N*64) return;
  int m = idx >> 6, n = idx & 63;
  const float* a = A + (size_t)m*512;
  float acc = bias[n];
  #pragma unroll 8
  for(int k=0;k<512;k++) acc += a[k] * W[k*64+n];
  out[idx] = acc;
}

// ---------------- per-node: LN+relu, dot hW3, pooled atomicAdd ----------------
__global__ __launch_bounds__(256) void k_energy(const float* y2, const float* hW3, const float* hb3,
    const int* batch, float* pooled, int N){
  int wave = (blockIdx.x*256 + threadIdx.x) >> 6;
  int lane = threadIdx.x & 63;
  if(wave >= N) return;
  float v = y2[(size_t)wave*64 + lane];
  float s = v; WREDUCE64(s);
  float m = s*(1.f/64.f);
  float d = v - m;
  float s2 = d*d; WREDUCE64(s2);
  float z = fmaxf(d * rsqrtf(s2*(1.f/64.f) + 1e-6f), 0.f);
  float e_ = z * hW3[lane];
  WREDUCE64(e_);
  if(lane == 0) atomicAdd(&pooled[batch[wave]], e_ + hb3[0]);
}

// ---------------- output is FLOAT32 (reference output dtype) ----------------
__global__ __launch_bounds__(256) void k_out(const float* pooled, float* out, int G){
  int tid = blockIdx.x*256 + threadIdx.x;
  if(tid < G) out[tid] = pooled[tid] * 0.11785113019775793f; // 1/sqrt(72)
}

extern "C" void kernel_launch(void* const* d_in, const int* in_sizes, int n_in,
                              void* d_out, int out_size, void* d_ws, size_t ws_size,
                              hipStream_t stream){
  const int*   edge_src  = (const int*)d_in[1];
  const int*   edge_dst  = (const int*)d_in[2];
  const float* edge_vec  = (const float*)d_in[3];
  const int*   batch     = (const int*)d_in[4];
  const int*   node_atom = (const int*)d_in[5];
  const float* ele    = (const float*)d_in[6];
  const float* W_embed= (const float*)d_in[7];
  const float* W_edge = (const float*)d_in[8];
  const float* Wq = (const float*)d_in[9];
  const float* Wk = (const float*)d_in[10];
  const float* Wv = (const float*)d_in[11];
  const float* Wr1= (const float*)d_in[12];
  const float* Wr2= (const float*)d_in[13];
  const float* Wo = (const float*)d_in[14];
  const float* W1 = (const float*)d_in[15];
  const float* W2 = (const float*)d_in[16];
  const float* W_feat=(const float*)d_in[17];
  const float* hW1= (const float*)d_in[18];
  const float* hb1= (const float*)d_in[19];
  const float* hW2= (const float*)d_in[20];
  const float* hb2= (const float*)d_in[21];
  const float* hW3= (const float*)d_in[22];
  const float* hb3= (const float*)d_in[23];
  (void)n_in; (void)ws_size;

  const int E = in_sizes[1];
  const int N = in_sizes[4];
  const int G = out_size;

  // ---- workspace: peak ~142 MB (proven crash-free in R4) ----
  char* base = (char*)d_ws;
  size_t off = 0;
  #define ALLOC(ty, name, count) ty* name = (ty*)(base + off); off = (off + (size_t)(count)*sizeof(ty) + 255) & ~(size_t)255;
  ALLOC(float, r_arr, E)                  // 1 MB
  ALLOC(u16,   rbfb,  (size_t)E*64)       // 32 MB
  ALLOC(u16,   ebf,   (size_t)E*64)       // 32 MB (dead after loop -> featn alias)
  ALLOC(u16,   vbf,   (size_t)E*64)       // 32 MB (dead after loop -> featraw alias)
  ALLOC(float, exb,   (size_t)E*4)        // 4 MB  (-> y1)
  ALLOC(float, radialb,(size_t)E*4)       // 4 MB  (-> hh1)
  ALLOC(float, hbuf,  (size_t)N*64)       // 4 MB
  ALLOC(float, h2b,   (size_t)N*64)       // 4 MB
  ALLOC(float, aggb,  (size_t)N*64)       // 4 MB
  ALLOC(float, Qb,    (size_t)N*64)       // 4 MB  (-> y2)
  ALLOC(float, xb,    (size_t)N*64)       // 4 MB
  ALLOC(float, tb,    (size_t)N*256)      // 16 MB
  ALLOC(int,   deg,   N)
  ALLOC(int,   rowptr,N+1)
  ALLOC(int,   cursor,N)
  ALLOC(int,   csr,   E)
  ALLOC(float, pooled,G)
  #undef ALLOC
  // tail-phase aliases into loop-dead regions:
  float* featraw = (float*)vbf;   // N*512*4 = 32 MB
  float* featn   = (float*)ebf;   // 32 MB
  float* y1      = exb;           // 4 MB
  float* hh1     = radialb;       // 4 MB
  float* y2      = Qb;            // 4 MB

  auto cdiv = [](int a, int b){ return (a + b - 1)/b; };

  hipMemsetAsync(deg, 0, (size_t)N*sizeof(int), stream);
  hipMemsetAsync(pooled, 0, (size_t)G*sizeof(float), stream);

  k_r<<<cdiv(E,256),256,0,stream>>>(edge_vec, r_arr, E);
  k_rbf<<<E*64/256,256,0,stream>>>(r_arr, rbfb, E);
  k_embed<<<N*64/256,256,0,stream>>>(node_atom, ele, W_embed, xb, N);
  k_edge_embed<<<E*64/256,256,0,stream>>>(edge_src, edge_dst, node_atom, ele, edge_vec, rbfb, W_edge, ebf, E);
  k_count<<<cdiv(E,256),256,0,stream>>>(edge_dst, deg, E);
  k_scan<<<1,1024,0,stream>>>(deg, rowptr, cursor, N);
  k_scatter<<<cdiv(E,256),256,0,stream>>>(edge_dst, cursor, csr, E);

  for(int l=0; l<6; l++){
    k_ln64<<<N/4,256,0,stream>>>(xb, hbuf, N);
    k_gemm64<<<N*64/256,256,0,stream>>>(hbuf, Wq + l*4096, Qb, N);
    k_radial<<<E/4,256,0,stream>>>(rbfb, Wr1 + l*4096, Wr2 + l*256, radialb, E);
    k_kv_logits<<<E/4,256,0,stream>>>(hbuf, ebf, edge_src, edge_dst, Qb, radialb, r_arr,
                                      Wk + l*4096, Wv + l*4096, vbf, exb, E);
    k_agg<<<N/4,256,0,stream>>>(rowptr, csr, exb, vbf, aggb, N);
    k_gemm64_add<<<N*64/256,256,0,stream>>>(aggb, Wo + l*4096, xb, N);
    k_ln64<<<N/4,256,0,stream>>>(xb, h2b, N);
    k_ffn1<<<N*256/256,256,0,stream>>>(h2b, W1 + l*16384, tb, N);
    k_ffn2<<<N*64/256,256,0,stream>>>(tb, W2 + l*16384, xb, N);
  }

  k_feat<<<N*512/256,256,0,stream>>>(xb, W_feat, featraw, N);
  k_ln512<<<N/4,256,0,stream>>>(featraw, featn, N);
  k_head1<<<N*64/256,256,0,stream>>>(featn, hW1, hb1, y1, N);
  k_lnrelu64<<<N/4,256,0,stream>>>(y1, hh1, N);
  k_gemm64_bias<<<N*64/256,256,0,stream>>>(hh1, hW2, hb2, y2, N);
  k_energy<<<N/4,256,0,stream>>>(y2, hW3, hb3, batch, pooled, N);
  k_out<<<cdiv(G,256),256,0,stream>>>(pooled, (float*)d_out, G);
}

// Round 7
// 1287.938 us; speedup vs baseline: 4.6301x; 4.6301x over previous
//
#include <hip/hip_runtime.h>

typedef short s8v __attribute__((ext_vector_type(8)));
typedef float f32x4 __attribute__((ext_vector_type(4)));
typedef unsigned short u16;

__device__ __forceinline__ float bf2f(u16 h){
  union { unsigned u; float f; } v; v.u = ((unsigned)h) << 16; return v.f;
}
__device__ __forceinline__ u16 f2bf(float f){
  union { float f; unsigned u; } v; v.f = f;
  unsigned u = v.u;
  return (u16)((u + 0x7fffu + ((u >> 16) & 1u)) >> 16);
}
#define MFMA(a,b,c) __builtin_amdgcn_mfma_f32_16x16x32_bf16((a),(b),(c),0,0,0)

#define WREDUCE64(s) { s += __shfl_xor(s,1); s += __shfl_xor(s,2); s += __shfl_xor(s,4); \
                       s += __shfl_xor(s,8); s += __shfl_xor(s,16); s += __shfl_xor(s,32); }

// ---------------- transpose f32 -> bf16 (with zero row padding): dst[b][c][rp] = src[b][rp][c] ----------------
__global__ __launch_bounds__(256) void k_transpose(const float* src, u16* dst, int B, int R, int C, int Rpad){
  int idx = blockIdx.x*256 + threadIdx.x;
  int total = B*C*Rpad;
  if(idx >= total) return;
  int b = idx / (C*Rpad);
  int rem = idx - b*C*Rpad;
  int cI = rem / Rpad;
  int rI = rem - cI*Rpad;
  dst[idx] = (rI < R) ? f2bf(src[(size_t)b*R*C + (size_t)rI*C + cI]) : (u16)0;
}

// ---------------- f32 -> bf16 elementwise convert ----------------
__global__ __launch_bounds__(256) void k_convert(const float* src, u16* dst, int n){
  int idx = blockIdx.x*256 + threadIdx.x;
  if(idx < n) dst[idx] = f2bf(src[idx]);
}

// ---------------- per-edge geometry: r, spherical harmonics ----------------
__global__ __launch_bounds__(256) void k_edge_geom(const float* evec, float* r_out, u16* shb, int E){
  int e = blockIdx.x*256 + threadIdx.x;
  if(e >= E) return;
  float vx = evec[(size_t)e*3+0];
  float vy = evec[(size_t)e*3+1];
  float vz = evec[(size_t)e*3+2];
  float r = sqrtf(vx*vx + vy*vy + vz*vz);
  float inv = 1.f/(r + 1e-12f);
  // u = edge_vec[:, [1,2,0]] / r  -> x=vec1, y=vec2, z=vec0
  float x = vy*inv, y = vz*inv, z = vx*inv;
  const float s3 = 1.7320508075688772f, s15 = 3.872983346207417f;
  const float s5h = 1.118033988749895f, s15h = 1.9364916731037085f;
  float sh[9];
  sh[0] = 1.f; sh[1] = s3*x; sh[2] = s3*y; sh[3] = s3*z;
  sh[4] = s15*x*y; sh[5] = s15*y*z; sh[6] = s5h*(3.f*z*z - 1.f);
  sh[7] = s15*x*z; sh[8] = s15h*(x*x - y*y);
  r_out[e] = r;
  #pragma unroll
  for(int i=0;i<9;i++) shb[(size_t)e*16 + i] = f2bf(sh[i]);
  #pragma unroll
  for(int i=9;i<16;i++) shb[(size_t)e*16 + i] = 0;
}

// ---------------- rbf[e][j] = exp(-(r - 10j/63)^2 / (2*w^2)), w=5/64 ----------------
__global__ __launch_bounds__(256) void k_rbf(const float* r_arr, u16* rbfb, int E){
  int tid = blockIdx.x*256 + threadIdx.x;
  if(tid >= E*64) return;
  int e = tid >> 6, j = tid & 63;
  float d = r_arr[e] - (10.f/63.f)*(float)j;
  rbfb[tid] = f2bf(__expf(-81.92f*d*d));
}

// ---------------- x = ele_embed[atom] @ W_embed  (K=32, Nc=64) ----------------
__global__ __launch_bounds__(256) void k_embed(const int* atom, const u16* ele, const u16* Bt, float* x, int M){
  int wave = (blockIdx.x*blockDim.x + threadIdx.x) >> 6;
  int lane = threadIdx.x & 63;
  int row0 = wave*16; if(row0 >= M) return;
  int c = lane & 15, q = lane >> 4;
  int at = atom[row0 + c];
  s8v a = *reinterpret_cast<const s8v*>(ele + (size_t)at*32 + q*8);
  #pragma unroll
  for(int ct=0; ct<4; ct++){
    s8v b = *reinterpret_cast<const s8v*>(Bt + (ct*16+c)*32 + q*8);
    f32x4 acc = {0.f,0.f,0.f,0.f};
    acc = MFMA(a, b, acc);
    #pragma unroll
    for(int r=0;r<4;r++) x[(size_t)(row0+q*4+r)*64 + ct*16 + c] = acc[r];
  }
}

// ---------------- e = [nf_src, nf_dst, sh, rbf] @ W_edge  (K padded 137->160) ----------------
__global__ __launch_bounds__(256) void k_edge_embed(const int* srcI, const int* dstI, const int* atom,
    const u16* ele, const u16* shb, const u16* rbfb, const u16* Bt, u16* ebf, int E){
  int wave = (blockIdx.x*blockDim.x + threadIdx.x) >> 6;
  int lane = threadIdx.x & 63;
  int row0 = wave*16; if(row0 >= E) return;
  int c = lane & 15, q = lane >> 4;
  int erow = row0 + c;
  s8v a[5];
  a[0] = *reinterpret_cast<const s8v*>(ele + (size_t)atom[srcI[erow]]*32 + q*8);
  a[1] = *reinterpret_cast<const s8v*>(ele + (size_t)atom[dstI[erow]]*32 + q*8);
  #pragma unroll
  for(int kc=2; kc<5; kc++){
    #pragma unroll
    for(int j=0;j<8;j++){
      int col = kc*32 + q*8 + j;
      u16 v;
      if(col < 73)       v = shb[(size_t)erow*16 + (col-64)];
      else if(col < 137) v = rbfb[(size_t)erow*64 + (col-73)];
      else               v = 0;
      a[kc][j] = (short)v;
    }
  }
  #pragma unroll
  for(int ct=0; ct<4; ct++){
    f32x4 acc = {0.f,0.f,0.f,0.f};
    #pragma unroll
    for(int kc=0; kc<5; kc++){
      s8v b = *reinterpret_cast<const s8v*>(Bt + (ct*16+c)*160 + kc*32 + q*8);
      acc = MFMA(a[kc], b, acc);
    }
    #pragma unroll
    for(int r_=0;r_<4;r_++) ebf[(size_t)(row0+q*4+r_)*64 + ct*16 + c] = f2bf(acc[r_]);
  }
}

// ---------------- LN over 64 (f32 in, bf16 out), optional relu ----------------
__global__ __launch_bounds__(256) void k_ln64(const float* x, u16* out, int N){
  int wave = (blockIdx.x*blockDim.x + threadIdx.x) >> 6;
  int lane = threadIdx.x & 63;
  if(wave >= N) return;
  float v = x[(size_t)wave*64 + lane];
  float s = v; WREDUCE64(s);
  float m = s*(1.f/64.f);
  float d = v - m;
  float s2 = d*d; WREDUCE64(s2);
  out[(size_t)wave*64 + lane] = f2bf(d * rsqrtf(s2*(1.f/64.f) + 1e-6f));
}
__global__ __launch_bounds__(256) void k_lnrelu64(const float* x, u16* out, int N){
  int wave = (blockIdx.x*blockDim.x + threadIdx.x) >> 6;
  int lane = threadIdx.x & 63;
  if(wave >= N) return;
  float v = x[(size_t)wave*64 + lane];
  float s = v; WREDUCE64(s);
  float m = s*(1.f/64.f);
  float d = v - m;
  float s2 = d*d; WREDUCE64(s2);
  float z = d * rsqrtf(s2*(1.f/64.f) + 1e-6f);
  out[(size_t)wave*64 + lane] = f2bf(fmaxf(z, 0.f));
}

// ---------------- generic M x 64 GEMM (K=64), f32 out ----------------
__global__ __launch_bounds__(256) void k_qgemm(const u16* A, const u16* Bt, float* out, int M){
  int wave = (blockIdx.x*blockDim.x + threadIdx.x) >> 6;
  int lane = threadIdx.x & 63;
  int row0 = wave*16; if(row0 >= M) return;
  int c = lane & 15, q = lane >> 4;
  s8v a0 = *reinterpret_cast<const s8v*>(A + (size_t)(row0+c)*64 + q*8);
  s8v a1 = *reinterpret_cast<const s8v*>(A + (size_t)(row0+c)*64 + 32 + q*8);
  #pragma unroll
  for(int ct=0; ct<4; ct++){
    s8v b0 = *reinterpret_cast<const s8v*>(Bt + (ct*16+c)*64 + q*8);
    s8v b1 = *reinterpret_cast<const s8v*>(Bt + (ct*16+c)*64 + 32 + q*8);
    f32x4 acc = {0.f,0.f,0.f,0.f};
    acc = MFMA(a0, b0, acc);
    acc = MFMA(a1, b1, acc);
    #pragma unroll
    for(int r=0;r<4;r++) out[(size_t)(row0+q*4+r)*64 + ct*16 + c] = acc[r];
  }
}

// ---------------- same but + f32 bias, f32 out (head layer 2 pre-LN) ----------------
__global__ __launch_bounds__(256) void k_gemm64_bias(const u16* A, const u16* Bt, const float* bias, float* out, int M){
  int wave = (blockIdx.x*blockDim.x + threadIdx.x) >> 6;
  int lane = threadIdx.x & 63;
  int row0 = wave*16; if(row0 >= M) return;
  int c = lane & 15, q = lane >> 4;
  s8v a0 = *reinterpret_cast<const s8v*>(A + (size_t)(row0+c)*64 + q*8);
  s8v a1 = *reinterpret_cast<const s8v*>(A + (size_t)(row0+c)*64 + 32 + q*8);
  #pragma unroll
  for(int ct=0; ct<4; ct++){
    s8v b0 = *reinterpret_cast<const s8v*>(Bt + (ct*16+c)*64 + q*8);
    s8v b1 = *reinterpret_cast<const s8v*>(Bt + (ct*16+c)*64 + 32 + q*8);
    f32x4 acc = {0.f,0.f,0.f,0.f};
    acc = MFMA(a0, b0, acc);
    acc = MFMA(a1, b1, acc);
    float bi = bias[ct*16+c];
    #pragma unroll
    for(int r=0;r<4;r++) out[(size_t)(row0+q*4+r)*64 + ct*16 + c] = acc[r] + bi;
  }
}

// ---------------- x += A @ Bt (64x64) ----------------
__global__ __launch_bounds__(256) void k_wo(const u16* A, const u16* Bt, float* x, int M){
  int wave = (blockIdx.x*blockDim.x + threadIdx.x) >> 6;
  int lane = threadIdx.x & 63;
  int row0 = wave*16; if(row0 >= M) return;
  int c = lane & 15, q = lane >> 4;
  s8v a0 = *reinterpret_cast<const s8v*>(A + (size_t)(row0+c)*64 + q*8);
  s8v a1 = *reinterpret_cast<const s8v*>(A + (size_t)(row0+c)*64 + 32 + q*8);
  #pragma unroll
  for(int ct=0; ct<4; ct++){
    s8v b0 = *reinterpret_cast<const s8v*>(Bt + (ct*16+c)*64 + q*8);
    s8v b1 = *reinterpret_cast<const s8v*>(Bt + (ct*16+c)*64 + 32 + q*8);
    f32x4 acc = {0.f,0.f,0.f,0.f};
    acc = MFMA(a0, b0, acc);
    acc = MFMA(a1, b1, acc);
    #pragma unroll
    for(int r=0;r<4;r++){
      size_t idx = (size_t)(row0+q*4+r)*64 + ct*16 + c;
      x[idx] += acc[r];
    }
  }
}

// ---------------- radial = silu(rbf @ Wr1) @ Wr2, fused via LDS; Wr2 is raw f32 ----------------
__global__ __launch_bounds__(256) void k_hid_radial(const u16* rbfb, const u16* Wr1T, const float* Wr2, float* radial, int E){
  __shared__ float lds[4][16*65];
  int widL = threadIdx.x >> 6;
  int wave = (blockIdx.x*256 + threadIdx.x) >> 6;
  int lane = threadIdx.x & 63;
  int row0 = wave*16;
  int c = lane & 15, q = lane >> 4;
  s8v a0 = *reinterpret_cast<const s8v*>(rbfb + (size_t)(row0+c)*64 + q*8);
  s8v a1 = *reinterpret_cast<const s8v*>(rbfb + (size_t)(row0+c)*64 + 32 + q*8);
  #pragma unroll
  for(int ct=0; ct<4; ct++){
    s8v b0 = *reinterpret_cast<const s8v*>(Wr1T + (ct*16+c)*64 + q*8);
    s8v b1 = *reinterpret_cast<const s8v*>(Wr1T + (ct*16+c)*64 + 32 + q*8);
    f32x4 acc = {0.f,0.f,0.f,0.f};
    acc = MFMA(a0, b0, acc);
    acc = MFMA(a1, b1, acc);
    #pragma unroll
    for(int r=0;r<4;r++){
      float y = acc[r];
      lds[widL][(q*4+r)*65 + ct*16 + c] = y / (1.f + __expf(-y));
    }
  }
  __syncthreads();
  int row2 = lane & 15, h = lane >> 4;
  float acc = 0.f;
  #pragma unroll 8
  for(int j=0;j<64;j++)
    acc += lds[widL][row2*65 + j] * Wr2[j*4 + h];
  radial[(size_t)(row0+row2)*4 + h] = acc;
}

// ---------------- k,v = (h[src]+e) @ {Wk,Wv}; logits via LDS; exp ----------------
__global__ __launch_bounds__(256) void k_kv_logits2(const u16* hbf, const u16* ebf, const int* srcI, const int* dstI,
    const float* Qb, const float* radial, const float* r_arr, const u16* WkT, const u16* WvT,
    u16* vbf, float* exb, int E){
  __shared__ float lds[4][16*65];
  int widL = threadIdx.x >> 6;
  int wave = (blockIdx.x*256 + threadIdx.x) >> 6;
  int lane = threadIdx.x & 63;
  int row0 = wave*16;
  int c = lane & 15, q = lane >> 4;
  int sr = srcI[row0 + c];
  s8v a0, a1;
  {
    s8v h0 = *reinterpret_cast<const s8v*>(hbf + (size_t)sr*64 + q*8);
    s8v h1 = *reinterpret_cast<const s8v*>(hbf + (size_t)sr*64 + 32 + q*8);
    s8v e0 = *reinterpret_cast<const s8v*>(ebf + (size_t)(row0+c)*64 + q*8);
    s8v e1 = *reinterpret_cast<const s8v*>(ebf + (size_t)(row0+c)*64 + 32 + q*8);
    #pragma unroll
    for(int j=0;j<8;j++){
      a0[j] = (short)f2bf(bf2f((u16)h0[j]) + bf2f((u16)e0[j]));
      a1[j] = (short)f2bf(bf2f((u16)h1[j]) + bf2f((u16)e1[j]));
    }
  }
  #pragma unroll
  for(int ct=0; ct<4; ct++){
    s8v bk0 = *reinterpret_cast<const s8v*>(WkT + (ct*16+c)*64 + q*8);
    s8v bk1 = *reinterpret_cast<const s8v*>(WkT + (ct*16+c)*64 + 32 + q*8);
    s8v bv0 = *reinterpret_cast<const s8v*>(WvT + (ct*16+c)*64 + q*8);
    s8v bv1 = *reinterpret_cast<const s8v*>(WvT + (ct*16+c)*64 + 32 + q*8);
    f32x4 kacc = {0.f,0.f,0.f,0.f};
    kacc = MFMA(a0, bk0, kacc); kacc = MFMA(a1, bk1, kacc);
    f32x4 vacc = {0.f,0.f,0.f,0.f};
    vacc = MFMA(a0, bv0, vacc); vacc = MFMA(a1, bv1, vacc);
    #pragma unroll
    for(int r=0;r<4;r++){
      vbf[(size_t)(row0+q*4+r)*64 + ct*16 + c] = f2bf(vacc[r]);
      lds[widL][(q*4+r)*65 + ct*16 + c] = kacc[r];
    }
  }
  __syncthreads();
  int row2 = lane & 15, h = lane >> 4;
  int erow = row0 + row2;
  int d = dstI[erow];
  const float* qrow = Qb + (size_t)d*64 + h*16;
  float acc = 0.f;
  #pragma unroll
  for(int dd=0; dd<16; dd++)
    acc += lds[widL][row2*65 + h*16 + dd] * qrow[dd];
  float logit = acc*0.25f + radial[(size_t)erow*4 + h];
  exb[(size_t)erow*4 + h] = (r_arr[erow] < 10.f) ? __expf(logit) : 0.f;
}

// ---------------- CSR build ----------------
__global__ __launch_bounds__(256) void k_count(const int* dstI, int* deg, int E){
  int tid = blockIdx.x*256 + threadIdx.x;
  if(tid < E) atomicAdd(&deg[dstI[tid]], 1);
}
__global__ __launch_bounds__(1024) void k_scan(const int* deg, int* rowptr, int* cursor, int N){
  __shared__ int wsum[17];
  int tid = threadIdx.x;
  int per = (N + 1023) >> 10;
  int base = tid * per;
  int s = 0;
  for(int i=0;i<per;i++){ int idx = base+i; if(idx < N) s += deg[idx]; }
  int lane = tid & 63, wid = tid >> 6;
  int inc = s;
  for(int d=1; d<64; d<<=1){
    int t = __shfl_up(inc, d);
    if(lane >= d) inc += t;
  }
  if(lane == 63) wsum[wid+1] = inc;
  if(tid == 0) wsum[0] = 0;
  __syncthreads();
  if(tid == 0){ for(int w=1; w<=16; w++) wsum[w] += wsum[w-1]; }
  __syncthreads();
  int run = inc - s + wsum[wid];
  for(int i=0;i<per;i++){
    int idx = base + i;
    if(idx < N){ rowptr[idx] = run; cursor[idx] = run; run += deg[idx]; }
  }
  if(tid == 1023) rowptr[N] = wsum[16];
}
__global__ __launch_bounds__(256) void k_scatter(const int* dstI, int* cursor, int* csr, int E){
  int tid = blockIdx.x*256 + threadIdx.x;
  if(tid < E){
    int p = atomicAdd(&cursor[dstI[tid]], 1);
    csr[p] = tid;
  }
}

// ---------------- node-centric softmax-denominator + aggregation ----------------
__global__ __launch_bounds__(256) void k_agg(const int* rowptr, const int* csr, const float* exb, const u16* vbf, u16* aggbf, int N){
  int wave = (blockIdx.x*blockDim.x + threadIdx.x) >> 6;
  int lane = threadIdx.x & 63;
  if(wave >= N) return;
  int s0 = rowptr[wave], s1 = rowptr[wave+1];
  float s[4] = {0.f,0.f,0.f,0.f};
  for(int p = s0 + lane; p < s1; p += 64){
    int e = csr[p];
    float4 ev = *reinterpret_cast<const float4*>(exb + (size_t)e*4);
    s[0] += ev.x; s[1] += ev.y; s[2] += ev.z; s[3] += ev.w;
  }
  #pragma unroll
  for(int i=0;i<4;i++){ WREDUCE64(s[i]); }
  int h = lane >> 4;
  float sumh = (h==0)?s[0]:(h==1)?s[1]:(h==2)?s[2]:s[3];
  float invh = 1.f/(sumh + 1e-9f);
  float acc = 0.f;
  for(int p = s0; p < s1; p++){
    int e = csr[p];
    float exh = exb[(size_t)e*4 + h];
    acc += exh * bf2f(vbf[(size_t)e*64 + lane]);
  }
  aggbf[(size_t)wave*64 + lane] = f2bf(acc * invh);
}

// ---------------- FFN ----------------
__global__ __launch_bounds__(256) void k_ffn1(const u16* A, const u16* Bt, u16* tout, int M){
  int wave = (blockIdx.x*blockDim.x + threadIdx.x) >> 6;
  int lane = threadIdx.x & 63;
  int row0 = wave*16; if(row0 >= M) return;
  int c = lane & 15, q = lane >> 4;
  s8v a0 = *reinterpret_cast<const s8v*>(A + (size_t)(row0+c)*64 + q*8);
  s8v a1 = *reinterpret_cast<const s8v*>(A + (size_t)(row0+c)*64 + 32 + q*8);
  #pragma unroll
  for(int ct=0; ct<16; ct++){
    s8v b0 = *reinterpret_cast<const s8v*>(Bt + (ct*16+c)*64 + q*8);
    s8v b1 = *reinterpret_cast<const s8v*>(Bt + (ct*16+c)*64 + 32 + q*8);
    f32x4 acc = {0.f,0.f,0.f,0.f};
    acc = MFMA(a0, b0, acc);
    acc = MFMA(a1, b1, acc);
    #pragma unroll
    for(int r=0;r<4;r++){
      float y = acc[r];
      tout[(size_t)(row0+q*4+r)*256 + ct*16 + c] = f2bf(y / (1.f + __expf(-y)));
    }
  }
}
__global__ __launch_bounds__(256) void k_ffn2(const u16* T, const u16* Bt, float* x, u16* xbf, int writex, int M){
  int wave = (blockIdx.x*blockDim.x + threadIdx.x) >> 6;
  int lane = threadIdx.x & 63;
  int row0 = wave*16; if(row0 >= M) return;
  int c = lane & 15, q = lane >> 4;
  s8v a[8];
  #pragma unroll
  for(int kc=0; kc<8; kc++)
    a[kc] = *reinterpret_cast<const s8v*>(T + (size_t)(row0+c)*256 + kc*32 + q*8);
  #pragma unroll
  for(int ct=0; ct<4; ct++){
    f32x4 acc = {0.f,0.f,0.f,0.f};
    #pragma unroll
    for(int kc=0; kc<8; kc++){
      s8v b = *reinterpret_cast<const s8v*>(Bt + (ct*16+c)*256 + kc*32 + q*8);
      acc = MFMA(a[kc], b, acc);
    }
    #pragma unroll
    for(int r=0;r<4;r++){
      size_t idx = (size_t)(row0+q*4+r)*64 + ct*16 + c;
      float nx = x[idx] + acc[r];
      x[idx] = nx;
      if(writex) xbf[idx] = f2bf(nx);
    }
  }
}

// ---------------- feat = x @ W_feat (Nc=512, raw f32) ----------------
__global__ __launch_bounds__(256) void k_feat(const u16* A, const u16* Bt, float* out, int M){
  int wave = (blockIdx.x*blockDim.x + threadIdx.x) >> 6;
  int lane = threadIdx.x & 63;
  int row0 = wave*16; if(row0 >= M) return;
  int c = lane & 15, q = lane >> 4;
  s8v a0 = *reinterpret_cast<const s8v*>(A + (size_t)(row0+c)*64 + q*8);
  s8v a1 = *reinterpret_cast<const s8v*>(A + (size_t)(row0+c)*64 + 32 + q*8);
  #pragma unroll
  for(int ct=0; ct<32; ct++){
    s8v b0 = *reinterpret_cast<const s8v*>(Bt + (ct*16+c)*64 + q*8);
    s8v b1 = *reinterpret_cast<const s8v*>(Bt + (ct*16+c)*64 + 32 + q*8);
    f32x4 acc = {0.f,0.f,0.f,0.f};
    acc = MFMA(a0, b0, acc);
    acc = MFMA(a1, b1, acc);
    #pragma unroll
    for(int r=0;r<4;r++) out[(size_t)(row0+q*4+r)*512 + ct*16 + c] = acc[r];
  }
}

// ---------------- LN over 512 ----------------
__global__ __launch_bounds__(256) void k_ln512(const float* fr, u16* out, int N){
  int wave = (blockIdx.x*blockDim.x + threadIdx.x) >> 6;
  int lane = threadIdx.x & 63;
  if(wave >= N) return;
  const float* row = fr + (size_t)wave*512 + lane*8;
  float v[8];
  float4 u0 = *reinterpret_cast<const float4*>(row);
  float4 u1 = *reinterpret_cast<const float4*>(row+4);
  v[0]=u0.x; v[1]=u0.y; v[2]=u0.z; v[3]=u0.w;
  v[4]=u1.x; v[5]=u1.y; v[6]=u1.z; v[7]=u1.w;
  float s = 0.f;
  #pragma unroll
  for(int i=0;i<8;i++) s += v[i];
  WREDUCE64(s);
  float m = s*(1.f/512.f);
  float vv = 0.f;
  #pragma unroll
  for(int i=0;i<8;i++){ float d = v[i]-m; vv += d*d; }
  WREDUCE64(vv);
  float rs = rsqrtf(vv*(1.f/512.f) + 1e-6f);
  s8v o;
  #pragma unroll
  for(int i=0;i<8;i++) o[i] = (short)f2bf((v[i]-m)*rs);
  *reinterpret_cast<s8v*>(out + (size_t)wave*512 + lane*8) = o;
}

// ---------------- head1 GEMM (K=512) + f32 bias, raw f32 out ----------------
__global__ __launch_bounds__(256) void k_head1_gemm(const u16* A, const u16* Bt, const float* hb, float* out, int M){
  int wave = (blockIdx.x*blockDim.x + threadIdx.x) >> 6;
  int lane = threadIdx.x & 63;
  int row0 = wave*16; if(row0 >= M) return;
  int c = lane & 15, q = lane >> 4;
  s8v a[16];
  #pragma unroll
  for(int kc=0; kc<16; kc++)
    a[kc] = *reinterpret_cast<const s8v*>(A + (size_t)(row0+c)*512 + kc*32 + q*8);
  #pragma unroll
  for(int ct=0; ct<4; ct++){
    f32x4 acc = {0.f,0.f,0.f,0.f};
    #pragma unroll
    for(int kc=0; kc<16; kc++){
      s8v b = *reinterpret_cast<const s8v*>(Bt + (size_t)(ct*16+c)*512 + kc*32 + q*8);
      acc = MFMA(a[kc], b, acc);
    }
    float bi = hb[ct*16+c];
    #pragma unroll
    for(int r=0;r<4;r++) out[(size_t)(row0+q*4+r)*64 + ct*16 + c] = acc[r] + bi;
  }
}

// ---------------- per-node: LN(y2)+relu, dot hW3 (f32), pooled atomicAdd ----------------
__global__ __launch_bounds__(256) void k_energy(const float* y2, const float* hW3, const float* hb3,
    const int* batch, float* pooled, int N){
  int wave = (blockIdx.x*blockDim.x + threadIdx.x) >> 6;
  int lane = threadIdx.x & 63;
  if(wave >= N) return;
  float v = y2[(size_t)wave*64 + lane];
  float s = v; WREDUCE64(s);
  float m = s*(1.f/64.f);
  float d = v - m;
  float s2 = d*d; WREDUCE64(s2);
  float z = fmaxf(d * rsqrtf(s2*(1.f/64.f) + 1e-6f), 0.f);
  float e_ = z * hW3[lane];
  WREDUCE64(e_);
  if(lane == 0) atomicAdd(&pooled[batch[wave]], e_ + hb3[0]);
}

// ---------------- output is FLOAT32 (reference output dtype) ----------------
__global__ __launch_bounds__(256) void k_out(const float* pooled, float* out, int G){
  int tid = blockIdx.x*256 + threadIdx.x;
  if(tid < G) out[tid] = pooled[tid] * 0.11785113019775793f; // 1/sqrt(72)
}

extern "C" void kernel_launch(void* const* d_in, const int* in_sizes, int n_in,
                              void* d_out, int out_size, void* d_ws, size_t ws_size,
                              hipStream_t stream){
  const int*   edge_src  = (const int*)d_in[1];
  const int*   edge_dst  = (const int*)d_in[2];
  const float* edge_vec  = (const float*)d_in[3];
  const int*   batch     = (const int*)d_in[4];
  const int*   node_atom = (const int*)d_in[5];
  const float* ele    = (const float*)d_in[6];
  const float* W_embed= (const float*)d_in[7];
  const float* W_edge = (const float*)d_in[8];
  const float* Wq = (const float*)d_in[9];
  const float* Wk = (const float*)d_in[10];
  const float* Wv = (const float*)d_in[11];
  const float* Wr1= (const float*)d_in[12];
  const float* Wr2= (const float*)d_in[13];
  const float* Wo = (const float*)d_in[14];
  const float* W1 = (const float*)d_in[15];
  const float* W2 = (const float*)d_in[16];
  const float* W_feat=(const float*)d_in[17];
  const float* hW1= (const float*)d_in[18];
  const float* hb1= (const float*)d_in[19];
  const float* hW2= (const float*)d_in[20];
  const float* hb2= (const float*)d_in[21];
  const float* hW3= (const float*)d_in[22];
  const float* hb3= (const float*)d_in[23];
  (void)n_in; (void)ws_size;

  const int E = in_sizes[1];
  const int N = in_sizes[4];
  const int G = out_size;

  // ---- workspace layout: peak ~139 MB (proven crash-free in R3) ----
  char* base = (char*)d_ws;
  size_t off = 0;
  #define ALLOC(ty, name, count) ty* name = (ty*)(base + off); off = (off + (size_t)(count)*sizeof(ty) + 255) & ~(size_t)255;
  ALLOC(float, r_arr, E)
  ALLOC(u16,   shb,   (size_t)E*16)
  ALLOC(u16,   rbfb,  (size_t)E*64)
  ALLOC(u16,   ebf,   (size_t)E*64)
  ALLOC(u16,   vbf,   (size_t)E*64)
  ALLOC(float, exb,   (size_t)E*4)
  ALLOC(float, radialb,(size_t)E*4)
  ALLOC(u16,   hbf,   (size_t)N*64)
  ALLOC(u16,   h2bf,  (size_t)N*64)
  ALLOC(u16,   aggbf, (size_t)N*64)
  ALLOC(u16,   xbf,   (size_t)N*64)
  ALLOC(float, Qb,    (size_t)N*64)
  ALLOC(float, xb,    (size_t)N*64)
  ALLOC(u16,   tbf,   (size_t)N*256)
  ALLOC(int,   deg,   N)
  ALLOC(int,   rowptr,N+1)
  ALLOC(int,   cursor,N)
  ALLOC(int,   csr,   E)
  ALLOC(float, pooled,G)
  ALLOC(u16, ele_bf, 120*32)
  ALLOC(u16, WembT, 64*32)
  ALLOC(u16, WedgeT,64*160)
  ALLOC(u16, WqT,  6*64*64)
  ALLOC(u16, WkT,  6*64*64)
  ALLOC(u16, WvT,  6*64*64)
  ALLOC(u16, Wr1T, 6*64*64)
  ALLOC(u16, WoT,  6*64*64)
  ALLOC(u16, W1T,  6*256*64)
  ALLOC(u16, W2T,  6*64*256)
  ALLOC(u16, WfT,  512*64)
  ALLOC(u16, hW1T, 64*512)
  ALLOC(u16, hW2T, 64*64)
  #undef ALLOC
  // tail-phase aliases into loop-dead regions:
  float* featraw = (float*)vbf;    // 32 MB = 32 MB
  u16*   featbf  = rbfb;           // 16 MB <= 32 MB
  float* y1      = exb;            // 4 MB
  u16*   hh1     = (u16*)radialb;  // 2 MB <= 4 MB
  float* y2      = Qb;             // 4 MB

  auto cdiv = [](int a, int b){ return (a + b - 1)/b; };

  k_convert<<<cdiv(120*32,256),256,0,stream>>>(ele, ele_bf, 120*32);
  k_transpose<<<cdiv(64*32,256),256,0,stream>>>(W_embed, WembT, 1, 32, 64, 32);
  k_transpose<<<cdiv(64*160,256),256,0,stream>>>(W_edge, WedgeT, 1, 137, 64, 160);
  k_transpose<<<cdiv(6*64*64,256),256,0,stream>>>(Wq, WqT, 6, 64, 64, 64);
  k_transpose<<<cdiv(6*64*64,256),256,0,stream>>>(Wk, WkT, 6, 64, 64, 64);
  k_transpose<<<cdiv(6*64*64,256),256,0,stream>>>(Wv, WvT, 6, 64, 64, 64);
  k_transpose<<<cdiv(6*64*64,256),256,0,stream>>>(Wr1, Wr1T, 6, 64, 64, 64);
  k_transpose<<<cdiv(6*64*64,256),256,0,stream>>>(Wo, WoT, 6, 64, 64, 64);
  k_transpose<<<cdiv(6*256*64,256),256,0,stream>>>(W1, W1T, 6, 64, 256, 64);
  k_transpose<<<cdiv(6*64*256,256),256,0,stream>>>(W2, W2T, 6, 256, 64, 256);
  k_transpose<<<cdiv(512*64,256),256,0,stream>>>(W_feat, WfT, 1, 64, 512, 64);
  k_transpose<<<cdiv(64*512,256),256,0,stream>>>(hW1, hW1T, 1, 512, 64, 512);
  k_transpose<<<cdiv(64*64,256),256,0,stream>>>(hW2, hW2T, 1, 64, 64, 64);

  hipMemsetAsync(deg, 0, (size_t)N*sizeof(int), stream);
  hipMemsetAsync(pooled, 0, (size_t)G*sizeof(float), stream);

  k_edge_geom<<<cdiv(E,256),256,0,stream>>>(edge_vec, r_arr, shb, E);
  k_rbf<<<cdiv(E*64,256),256,0,stream>>>(r_arr, rbfb, E);
  k_embed<<<N/64, 256, 0, stream>>>(node_atom, ele_bf, WembT, xb, N);
  k_edge_embed<<<E/64, 256, 0, stream>>>(edge_src, edge_dst, node_atom, ele_bf, shb, rbfb, WedgeT, ebf, E);
  k_count<<<cdiv(E,256),256,0,stream>>>(edge_dst, deg, E);
  k_scan<<<1,1024,0,stream>>>(deg, rowptr, cursor, N);
  k_scatter<<<cdiv(E,256),256,0,stream>>>(edge_dst, cursor, csr, E);

  for(int l=0; l<6; l++){
    k_ln64<<<cdiv(N,4),256,0,stream>>>(xb, hbf, N);
    k_qgemm<<<N/64,256,0,stream>>>(hbf, WqT + l*4096, Qb, N);
    k_hid_radial<<<E/64,256,0,stream>>>(rbfb, Wr1T + l*4096, Wr2 + l*256, radialb, E);
    k_kv_logits2<<<E/64,256,0,stream>>>(hbf, ebf, edge_src, edge_dst, Qb, radialb, r_arr,
                                        WkT + l*4096, WvT + l*4096, vbf, exb, E);
    k_agg<<<cdiv(N,4),256,0,stream>>>(rowptr, csr, exb, vbf, aggbf, N);
    k_wo<<<N/64,256,0,stream>>>(aggbf, WoT + l*4096, xb, N);
    k_ln64<<<cdiv(N,4),256,0,stream>>>(xb, h2bf, N);
    k_ffn1<<<N/64,256,0,stream>>>(h2bf, W1T + l*16384, tbf, N);
    k_ffn2<<<N/64,256,0,stream>>>(tbf, W2T + l*16384, xb, xbf, (l==5)?1:0, N);
  }

  k_feat<<<N/64,256,0,stream>>>(xbf, WfT, featraw, N);
  k_ln512<<<cdiv(N,4),256,0,stream>>>(featraw, featbf, N);
  k_head1_gemm<<<N/64,256,0,stream>>>(featbf, hW1T, hb1, y1, N);
  k_lnrelu64<<<cdiv(N,4),256,0,stream>>>(y1, hh1, N);
  k_gemm64_bias<<<N/64,256,0,stream>>>(hh1, hW2T, hb2, y2, N);
  k_energy<<<cdiv(N,4),256,0,stream>>>(y2, hW3, hb3, batch, pooled, N);
  k_out<<<cdiv(G,256),256,0,stream>>>(pooled, (float*)d_out, G);
}

// Round 8
// 1092.693 us; speedup vs baseline: 5.4574x; 1.1787x over previous
//
#include <hip/hip_runtime.h>

typedef short s8v __attribute__((ext_vector_type(8)));
typedef float f32x4 __attribute__((ext_vector_type(4)));
typedef unsigned short u16;

__device__ __forceinline__ float bf2f(u16 h){
  union { unsigned u; float f; } v; v.u = ((unsigned)h) << 16; return v.f;
}
__device__ __forceinline__ u16 f2bf(float f){
  union { float f; unsigned u; } v; v.f = f;
  unsigned u = v.u;
  return (u16)((u + 0x7fffu + ((u >> 16) & 1u)) >> 16);
}
#define MFMA(a,b,c) __builtin_amdgcn_mfma_f32_16x16x32_bf16((a),(b),(c),0,0,0)

#define WREDUCE64(s) { s += __shfl_xor(s,1); s += __shfl_xor(s,2); s += __shfl_xor(s,4); \
                       s += __shfl_xor(s,8); s += __shfl_xor(s,16); s += __shfl_xor(s,32); }
#define QREDUCE16(s) { s += __shfl_xor(s,1); s += __shfl_xor(s,2); s += __shfl_xor(s,4); s += __shfl_xor(s,8); }

// ---------------- transpose f32 -> bf16 (with zero row padding): dst[b][c][rp] = src[b][rp][c] ----------------
__global__ __launch_bounds__(256) void k_transpose(const float* src, u16* dst, int B, int R, int C, int Rpad){
  int idx = blockIdx.x*256 + threadIdx.x;
  int total = B*C*Rpad;
  if(idx >= total) return;
  int b = idx / (C*Rpad);
  int rem = idx - b*C*Rpad;
  int cI = rem / Rpad;
  int rI = rem - cI*Rpad;
  dst[idx] = (rI < R) ? f2bf(src[(size_t)b*R*C + (size_t)rI*C + cI]) : (u16)0;
}

// 5 batched 6x64x64 transposes in one launch (dst buffers contiguous)
__global__ __launch_bounds__(256) void k_transpose5(const float* W0, const float* W1, const float* W2,
    const float* W3, const float* W4, u16* dst){
  int idx = blockIdx.x*256 + threadIdx.x; // 5*6*64*64
  int which = idx / (6*64*64);
  int rem = idx - which*(6*64*64);
  const float* src = (which==0)?W0:(which==1)?W1:(which==2)?W2:(which==3)?W3:W4;
  int b = rem >> 12;
  int r2 = rem & 4095;
  int cI = r2 >> 6, rI = r2 & 63;
  dst[idx] = f2bf(src[b*4096 + rI*64 + cI]);
}

// ---------------- f32 -> bf16 elementwise convert ----------------
__global__ __launch_bounds__(256) void k_convert(const float* src, u16* dst, int n){
  int idx = blockIdx.x*256 + threadIdx.x;
  if(idx < n) dst[idx] = f2bf(src[idx]);
}

// ---------------- per-edge geometry: r, spherical harmonics ----------------
__global__ __launch_bounds__(256) void k_edge_geom(const float* evec, float* r_out, u16* shb, int E){
  int e = blockIdx.x*256 + threadIdx.x;
  if(e >= E) return;
  float vx = evec[(size_t)e*3+0];
  float vy = evec[(size_t)e*3+1];
  float vz = evec[(size_t)e*3+2];
  float r = sqrtf(vx*vx + vy*vy + vz*vz);
  float inv = 1.f/(r + 1e-12f);
  // u = edge_vec[:, [1,2,0]] / r  -> x=vec1, y=vec2, z=vec0
  float x = vy*inv, y = vz*inv, z = vx*inv;
  const float s3 = 1.7320508075688772f, s15 = 3.872983346207417f;
  const float s5h = 1.118033988749895f, s15h = 1.9364916731037085f;
  float sh[9];
  sh[0] = 1.f; sh[1] = s3*x; sh[2] = s3*y; sh[3] = s3*z;
  sh[4] = s15*x*y; sh[5] = s15*y*z; sh[6] = s5h*(3.f*z*z - 1.f);
  sh[7] = s15*x*z; sh[8] = s15h*(x*x - y*y);
  r_out[e] = r;
  #pragma unroll
  for(int i=0;i<9;i++) shb[(size_t)e*16 + i] = f2bf(sh[i]);
  #pragma unroll
  for(int i=9;i<16;i++) shb[(size_t)e*16 + i] = 0;
}

// ---------------- rbf[e][j] = exp(-(r - 10j/63)^2 / (2*w^2)), w=5/64 ----------------
__global__ __launch_bounds__(256) void k_rbf(const float* r_arr, u16* rbfb, int E){
  int tid = blockIdx.x*256 + threadIdx.x;
  if(tid >= E*64) return;
  int e = tid >> 6, j = tid & 63;
  float d = r_arr[e] - (10.f/63.f)*(float)j;
  rbfb[tid] = f2bf(__expf(-81.92f*d*d));
}

// ---------------- x = ele_embed[atom] @ W_embed  (K=32, Nc=64) ----------------
__global__ __launch_bounds__(256) void k_embed(const int* atom, const u16* ele, const u16* Bt, float* x, int M){
  int wave = (blockIdx.x*blockDim.x + threadIdx.x) >> 6;
  int lane = threadIdx.x & 63;
  int row0 = wave*16; if(row0 >= M) return;
  int c = lane & 15, q = lane >> 4;
  int at = atom[row0 + c];
  s8v a = *reinterpret_cast<const s8v*>(ele + (size_t)at*32 + q*8);
  #pragma unroll
  for(int ct=0; ct<4; ct++){
    s8v b = *reinterpret_cast<const s8v*>(Bt + (ct*16+c)*32 + q*8);
    f32x4 acc = {0.f,0.f,0.f,0.f};
    acc = MFMA(a, b, acc);
    #pragma unroll
    for(int r=0;r<4;r++) x[(size_t)(row0+q*4+r)*64 + ct*16 + c] = acc[r];
  }
}

// ---------------- e = [nf_src, nf_dst, sh, rbf] @ W_edge  (K padded 137->160) ----------------
__global__ __launch_bounds__(256) void k_edge_embed(const int* srcI, const int* dstI, const int* atom,
    const u16* ele, const u16* shb, const u16* rbfb, const u16* Bt, u16* ebf, int E){
  int wave = (blockIdx.x*blockDim.x + threadIdx.x) >> 6;
  int lane = threadIdx.x & 63;
  int row0 = wave*16; if(row0 >= E) return;
  int c = lane & 15, q = lane >> 4;
  int erow = row0 + c;
  s8v a[5];
  a[0] = *reinterpret_cast<const s8v*>(ele + (size_t)atom[srcI[erow]]*32 + q*8);
  a[1] = *reinterpret_cast<const s8v*>(ele + (size_t)atom[dstI[erow]]*32 + q*8);
  #pragma unroll
  for(int kc=2; kc<5; kc++){
    #pragma unroll
    for(int j=0;j<8;j++){
      int col = kc*32 + q*8 + j;
      u16 v;
      if(col < 73)       v = shb[(size_t)erow*16 + (col-64)];
      else if(col < 137) v = rbfb[(size_t)erow*64 + (col-73)];
      else               v = 0;
      a[kc][j] = (short)v;
    }
  }
  #pragma unroll
  for(int ct=0; ct<4; ct++){
    f32x4 acc = {0.f,0.f,0.f,0.f};
    #pragma unroll
    for(int kc=0; kc<5; kc++){
      s8v b = *reinterpret_cast<const s8v*>(Bt + (ct*16+c)*160 + kc*32 + q*8);
      acc = MFMA(a[kc], b, acc);
    }
    #pragma unroll
    for(int r_=0;r_<4;r_++) ebf[(size_t)(row0+q*4+r_)*64 + ct*16 + c] = f2bf(acc[r_]);
  }
}

// ---------------- LN over 64 (f32 in, bf16 out) ----------------
__global__ __launch_bounds__(256) void k_ln64(const float* x, u16* out, int N){
  int wave = (blockIdx.x*blockDim.x + threadIdx.x) >> 6;
  int lane = threadIdx.x & 63;
  if(wave >= N) return;
  float v = x[(size_t)wave*64 + lane];
  float s = v; WREDUCE64(s);
  float m = s*(1.f/64.f);
  float d = v - m;
  float s2 = d*d; WREDUCE64(s2);
  out[(size_t)wave*64 + lane] = f2bf(d * rsqrtf(s2*(1.f/64.f) + 1e-6f));
}
__global__ __launch_bounds__(256) void k_lnrelu64(const float* x, u16* out, int N){
  int wave = (blockIdx.x*blockDim.x + threadIdx.x) >> 6;
  int lane = threadIdx.x & 63;
  if(wave >= N) return;
  float v = x[(size_t)wave*64 + lane];
  float s = v; WREDUCE64(s);
  float m = s*(1.f/64.f);
  float d = v - m;
  float s2 = d*d; WREDUCE64(s2);
  float z = d * rsqrtf(s2*(1.f/64.f) + 1e-6f);
  out[(size_t)wave*64 + lane] = f2bf(fmaxf(z, 0.f));
}

// ---------------- generic M x 64 GEMM (K=64), f32 out ----------------
__global__ __launch_bounds__(256) void k_qgemm(const u16* A, const u16* Bt, float* out, int M){
  int wave = (blockIdx.x*blockDim.x + threadIdx.x) >> 6;
  int lane = threadIdx.x & 63;
  int row0 = wave*16; if(row0 >= M) return;
  int c = lane & 15, q = lane >> 4;
  s8v a0 = *reinterpret_cast<const s8v*>(A + (size_t)(row0+c)*64 + q*8);
  s8v a1 = *reinterpret_cast<const s8v*>(A + (size_t)(row0+c)*64 + 32 + q*8);
  #pragma unroll
  for(int ct=0; ct<4; ct++){
    s8v b0 = *reinterpret_cast<const s8v*>(Bt + (ct*16+c)*64 + q*8);
    s8v b1 = *reinterpret_cast<const s8v*>(Bt + (ct*16+c)*64 + 32 + q*8);
    f32x4 acc = {0.f,0.f,0.f,0.f};
    acc = MFMA(a0, b0, acc);
    acc = MFMA(a1, b1, acc);
    #pragma unroll
    for(int r=0;r<4;r++) out[(size_t)(row0+q*4+r)*64 + ct*16 + c] = acc[r];
  }
}

// ---------------- + f32 bias, f32 out (head layer 2 pre-LN) ----------------
__global__ __launch_bounds__(256) void k_gemm64_bias(const u16* A, const u16* Bt, const float* bias, float* out, int M){
  int wave = (blockIdx.x*blockDim.x + threadIdx.x) >> 6;
  int lane = threadIdx.x & 63;
  int row0 = wave*16; if(row0 >= M) return;
  int c = lane & 15, q = lane >> 4;
  s8v a0 = *reinterpret_cast<const s8v*>(A + (size_t)(row0+c)*64 + q*8);
  s8v a1 = *reinterpret_cast<const s8v*>(A + (size_t)(row0+c)*64 + 32 + q*8);
  #pragma unroll
  for(int ct=0; ct<4; ct++){
    s8v b0 = *reinterpret_cast<const s8v*>(Bt + (ct*16+c)*64 + q*8);
    s8v b1 = *reinterpret_cast<const s8v*>(Bt + (ct*16+c)*64 + 32 + q*8);
    f32x4 acc = {0.f,0.f,0.f,0.f};
    acc = MFMA(a0, b0, acc);
    acc = MFMA(a1, b1, acc);
    float bi = bias[ct*16+c];
    #pragma unroll
    for(int r=0;r<4;r++) out[(size_t)(row0+q*4+r)*64 + ct*16 + c] = acc[r] + bi;
  }
}

// ---------------- x += agg @ WoT; h2 = LN(x) fused ----------------
__global__ __launch_bounds__(256) void k_wo_ln(const u16* A, const u16* Bt, float* x, u16* hout, int M){
  int wave = (blockIdx.x*blockDim.x + threadIdx.x) >> 6;
  int lane = threadIdx.x & 63;
  int row0 = wave*16; if(row0 >= M) return;
  int c = lane & 15, q = lane >> 4;
  s8v a0 = *reinterpret_cast<const s8v*>(A + (size_t)(row0+c)*64 + q*8);
  s8v a1 = *reinterpret_cast<const s8v*>(A + (size_t)(row0+c)*64 + 32 + q*8);
  float nx[4][4];
  #pragma unroll
  for(int ct=0; ct<4; ct++){
    s8v b0 = *reinterpret_cast<const s8v*>(Bt + (ct*16+c)*64 + q*8);
    s8v b1 = *reinterpret_cast<const s8v*>(Bt + (ct*16+c)*64 + 32 + q*8);
    f32x4 acc = {0.f,0.f,0.f,0.f};
    acc = MFMA(a0, b0, acc);
    acc = MFMA(a1, b1, acc);
    #pragma unroll
    for(int r=0;r<4;r++){
      size_t idx = (size_t)(row0+q*4+r)*64 + ct*16 + c;
      float t = x[idx] + acc[r];
      x[idx] = t;
      nx[ct][r] = t;
    }
  }
  #pragma unroll
  for(int r=0;r<4;r++){
    float s = nx[0][r]+nx[1][r]+nx[2][r]+nx[3][r];
    QREDUCE16(s);
    float m = s*(1.f/64.f);
    float vv = 0.f;
    #pragma unroll
    for(int ct=0;ct<4;ct++){ float d = nx[ct][r]-m; vv += d*d; }
    QREDUCE16(vv);
    float rs = rsqrtf(vv*(1.f/64.f) + 1e-6f);
    #pragma unroll
    for(int ct=0;ct<4;ct++)
      hout[(size_t)(row0+q*4+r)*64 + ct*16 + c] = f2bf((nx[ct][r]-m)*rs);
  }
}

// ---------------- fused: k,v = (h[src]+e)@{Wk,Wv}; hid=silu(rbf@Wr1); logits+radial+exp ----------------
__global__ __launch_bounds__(256) void k_kvrad(const u16* hbf, const u16* ebf, const u16* rbfb,
    const int* srcI, const int* dstI, const float* Qb, const float* r_arr,
    const u16* WkT, const u16* WvT, const u16* Wr1T, const float* Wr2,
    u16* vbf, float* exb, int E){
  __shared__ float ldsK[4][16*65];
  __shared__ float ldsH[4][16*65];
  int widL = threadIdx.x >> 6;
  int wave = (blockIdx.x*256 + threadIdx.x) >> 6;
  int lane = threadIdx.x & 63;
  int row0 = wave*16;
  int c = lane & 15, q = lane >> 4;
  int sr = srcI[row0 + c];
  s8v a0, a1;
  {
    s8v h0 = *reinterpret_cast<const s8v*>(hbf + (size_t)sr*64 + q*8);
    s8v h1 = *reinterpret_cast<const s8v*>(hbf + (size_t)sr*64 + 32 + q*8);
    s8v e0 = *reinterpret_cast<const s8v*>(ebf + (size_t)(row0+c)*64 + q*8);
    s8v e1 = *reinterpret_cast<const s8v*>(ebf + (size_t)(row0+c)*64 + 32 + q*8);
    #pragma unroll
    for(int j=0;j<8;j++){
      a0[j] = (short)f2bf(bf2f((u16)h0[j]) + bf2f((u16)e0[j]));
      a1[j] = (short)f2bf(bf2f((u16)h1[j]) + bf2f((u16)e1[j]));
    }
  }
  s8v r0 = *reinterpret_cast<const s8v*>(rbfb + (size_t)(row0+c)*64 + q*8);
  s8v r1 = *reinterpret_cast<const s8v*>(rbfb + (size_t)(row0+c)*64 + 32 + q*8);
  #pragma unroll
  for(int ct=0; ct<4; ct++){
    s8v bk0 = *reinterpret_cast<const s8v*>(WkT + (ct*16+c)*64 + q*8);
    s8v bk1 = *reinterpret_cast<const s8v*>(WkT + (ct*16+c)*64 + 32 + q*8);
    s8v bv0 = *reinterpret_cast<const s8v*>(WvT + (ct*16+c)*64 + q*8);
    s8v bv1 = *reinterpret_cast<const s8v*>(WvT + (ct*16+c)*64 + 32 + q*8);
    s8v bw0 = *reinterpret_cast<const s8v*>(Wr1T + (ct*16+c)*64 + q*8);
    s8v bw1 = *reinterpret_cast<const s8v*>(Wr1T + (ct*16+c)*64 + 32 + q*8);
    f32x4 kacc = {0.f,0.f,0.f,0.f};
    kacc = MFMA(a0, bk0, kacc); kacc = MFMA(a1, bk1, kacc);
    f32x4 vacc = {0.f,0.f,0.f,0.f};
    vacc = MFMA(a0, bv0, vacc); vacc = MFMA(a1, bv1, vacc);
    f32x4 hacc = {0.f,0.f,0.f,0.f};
    hacc = MFMA(r0, bw0, hacc); hacc = MFMA(r1, bw1, hacc);
    #pragma unroll
    for(int r=0;r<4;r++){
      vbf[(size_t)(row0+q*4+r)*64 + ct*16 + c] = f2bf(vacc[r]);
      ldsK[widL][(q*4+r)*65 + ct*16 + c] = kacc[r];
      float y = hacc[r];
      ldsH[widL][(q*4+r)*65 + ct*16 + c] = y / (1.f + __expf(-y));
    }
  }
  __syncthreads();
  int row2 = lane & 15, h = lane >> 4;
  int erow = row0 + row2;
  int d = dstI[erow];
  const float* qrow = Qb + (size_t)d*64 + h*16;
  float qk = 0.f;
  #pragma unroll
  for(int dd=0; dd<16; dd++)
    qk += ldsK[widL][row2*65 + h*16 + dd] * qrow[dd];
  float rad = 0.f;
  #pragma unroll 8
  for(int j=0;j<64;j++)
    rad += ldsH[widL][row2*65 + j] * Wr2[j*4 + h];
  float logit = qk*0.25f + rad;
  exb[(size_t)erow*4 + h] = (r_arr[erow] < 10.f) ? __expf(logit) : 0.f;
}

// ---------------- CSR build ----------------
__global__ __launch_bounds__(256) void k_count(const int* dstI, int* deg, int E){
  int tid = blockIdx.x*256 + threadIdx.x;
  if(tid < E) atomicAdd(&deg[dstI[tid]], 1);
}
__global__ __launch_bounds__(1024) void k_scan(const int* deg, int* rowptr, int* cursor, int N){
  __shared__ int wsum[17];
  int tid = threadIdx.x;
  int per = (N + 1023) >> 10;
  int base = tid * per;
  int s = 0;
  for(int i=0;i<per;i++){ int idx = base+i; if(idx < N) s += deg[idx]; }
  int lane = tid & 63, wid = tid >> 6;
  int inc = s;
  for(int d=1; d<64; d<<=1){
    int t = __shfl_up(inc, d);
    if(lane >= d) inc += t;
  }
  if(lane == 63) wsum[wid+1] = inc;
  if(tid == 0) wsum[0] = 0;
  __syncthreads();
  if(tid == 0){ for(int w=1; w<=16; w++) wsum[w] += wsum[w-1]; }
  __syncthreads();
  int run = inc - s + wsum[wid];
  for(int i=0;i<per;i++){
    int idx = base + i;
    if(idx < N){ rowptr[idx] = run; cursor[idx] = run; run += deg[idx]; }
  }
  if(tid == 1023) rowptr[N] = wsum[16];
}
__global__ __launch_bounds__(256) void k_scatter(const int* dstI, int* cursor, int* csr, int E){
  int tid = blockIdx.x*256 + threadIdx.x;
  if(tid < E){
    int p = atomicAdd(&cursor[dstI[tid]], 1);
    csr[p] = tid;
  }
}

// ---------------- softmax-denominator + aggregation, 4-edge-parallel ----------------
__global__ __launch_bounds__(256) void k_agg(const int* rowptr, const int* csr, const float* exb, const u16* vbf, u16* aggbf, int N){
  int wave = (blockIdx.x*256 + threadIdx.x) >> 6;
  int lane = threadIdx.x & 63;
  if(wave >= N) return;
  int s0 = rowptr[wave], s1 = rowptr[wave+1];
  float s[4] = {0.f,0.f,0.f,0.f};
  for(int p = s0 + lane; p < s1; p += 64){
    int e = csr[p];
    float4 ev = *reinterpret_cast<const float4*>(exb + (size_t)e*4);
    s[0] += ev.x; s[1] += ev.y; s[2] += ev.z; s[3] += ev.w;
  }
  #pragma unroll
  for(int i=0;i<4;i++){ WREDUCE64(s[i]); }
  int ep = lane >> 4, cc = lane & 15;
  int hh = cc >> 2;
  float inv = 1.f/(s[hh] + 1e-9f);
  float a0=0.f, a1=0.f, a2=0.f, a3=0.f;
  for(int p = s0 + ep; p < s1; p += 4){
    int e = csr[p];
    ushort4 v4 = *reinterpret_cast<const ushort4*>(vbf + (size_t)e*64 + cc*4);
    float ex = exb[(size_t)e*4 + hh];
    a0 += ex*bf2f(v4.x); a1 += ex*bf2f(v4.y); a2 += ex*bf2f(v4.z); a3 += ex*bf2f(v4.w);
  }
  a0 += __shfl_xor(a0,16); a0 += __shfl_xor(a0,32);
  a1 += __shfl_xor(a1,16); a1 += __shfl_xor(a1,32);
  a2 += __shfl_xor(a2,16); a2 += __shfl_xor(a2,32);
  a3 += __shfl_xor(a3,16); a3 += __shfl_xor(a3,32);
  if(ep == 0){
    ushort4 o;
    o.x = f2bf(a0*inv); o.y = f2bf(a1*inv); o.z = f2bf(a2*inv); o.w = f2bf(a3*inv);
    *reinterpret_cast<ushort4*>(aggbf + (size_t)wave*64 + cc*4) = o;
  }
}

// ---------------- FFN ----------------
__global__ __launch_bounds__(256) void k_ffn1(const u16* A, const u16* Bt, u16* tout, int M){
  int wave = (blockIdx.x*blockDim.x + threadIdx.x) >> 6;
  int lane = threadIdx.x & 63;
  int row0 = wave*16; if(row0 >= M) return;
  int c = lane & 15, q = lane >> 4;
  s8v a0 = *reinterpret_cast<const s8v*>(A + (size_t)(row0+c)*64 + q*8);
  s8v a1 = *reinterpret_cast<const s8v*>(A + (size_t)(row0+c)*64 + 32 + q*8);
  #pragma unroll
  for(int ct=0; ct<16; ct++){
    s8v b0 = *reinterpret_cast<const s8v*>(Bt + (ct*16+c)*64 + q*8);
    s8v b1 = *reinterpret_cast<const s8v*>(Bt + (ct*16+c)*64 + 32 + q*8);
    f32x4 acc = {0.f,0.f,0.f,0.f};
    acc = MFMA(a0, b0, acc);
    acc = MFMA(a1, b1, acc);
    #pragma unroll
    for(int r=0;r<4;r++){
      float y = acc[r];
      tout[(size_t)(row0+q*4+r)*256 + ct*16 + c] = f2bf(y / (1.f + __expf(-y)));
    }
  }
}
// x += T @ W2T; hbf = LN(x); optional xbf = bf16(x)
__global__ __launch_bounds__(256) void k_ffn2_ln(const u16* T, const u16* Bt, float* x, u16* hout, u16* xbf, int writex, int M){
  int wave = (blockIdx.x*blockDim.x + threadIdx.x) >> 6;
  int lane = threadIdx.x & 63;
  int row0 = wave*16; if(row0 >= M) return;
  int c = lane & 15, q = lane >> 4;
  s8v a[8];
  #pragma unroll
  for(int kc=0; kc<8; kc++)
    a[kc] = *reinterpret_cast<const s8v*>(T + (size_t)(row0+c)*256 + kc*32 + q*8);
  float nx[4][4];
  #pragma unroll
  for(int ct=0; ct<4; ct++){
    f32x4 acc = {0.f,0.f,0.f,0.f};
    #pragma unroll
    for(int kc=0; kc<8; kc++){
      s8v b = *reinterpret_cast<const s8v*>(Bt + (ct*16+c)*256 + kc*32 + q*8);
      acc = MFMA(a[kc], b, acc);
    }
    #pragma unroll
    for(int r=0;r<4;r++){
      size_t idx = (size_t)(row0+q*4+r)*64 + ct*16 + c;
      float t = x[idx] + acc[r];
      x[idx] = t;
      nx[ct][r] = t;
      if(writex) xbf[idx] = f2bf(t);
    }
  }
  #pragma unroll
  for(int r=0;r<4;r++){
    float s = nx[0][r]+nx[1][r]+nx[2][r]+nx[3][r];
    QREDUCE16(s);
    float m = s*(1.f/64.f);
    float vv = 0.f;
    #pragma unroll
    for(int ct=0;ct<4;ct++){ float d = nx[ct][r]-m; vv += d*d; }
    QREDUCE16(vv);
    float rs = rsqrtf(vv*(1.f/64.f) + 1e-6f);
    #pragma unroll
    for(int ct=0;ct<4;ct++)
      hout[(size_t)(row0+q*4+r)*64 + ct*16 + c] = f2bf((nx[ct][r]-m)*rs);
  }
}

// ---------------- feat = x @ W_feat (Nc=512, raw f32) ----------------
__global__ __launch_bounds__(256) void k_feat(const u16* A, const u16* Bt, float* out, int M){
  int wave = (blockIdx.x*blockDim.x + threadIdx.x) >> 6;
  int lane = threadIdx.x & 63;
  int row0 = wave*16; if(row0 >= M) return;
  int c = lane & 15, q = lane >> 4;
  s8v a0 = *reinterpret_cast<const s8v*>(A + (size_t)(row0+c)*64 + q*8);
  s8v a1 = *reinterpret_cast<const s8v*>(A + (size_t)(row0+c)*64 + 32 + q*8);
  #pragma unroll
  for(int ct=0; ct<32; ct++){
    s8v b0 = *reinterpret_cast<const s8v*>(Bt + (ct*16+c)*64 + q*8);
    s8v b1 = *reinterpret_cast<const s8v*>(Bt + (ct*16+c)*64 + 32 + q*8);
    f32x4 acc = {0.f,0.f,0.f,0.f};
    acc = MFMA(a0, b0, acc);
    acc = MFMA(a1, b1, acc);
    #pragma unroll
    for(int r=0;r<4;r++) out[(size_t)(row0+q*4+r)*512 + ct*16 + c] = acc[r];
  }
}

// ---------------- LN over 512 ----------------
__global__ __launch_bounds__(256) void k_ln512(const float* fr, u16* out, int N){
  int wave = (blockIdx.x*blockDim.x + threadIdx.x) >> 6;
  int lane = threadIdx.x & 63;
  if(wave >= N) return;
  const float* row = fr + (size_t)wave*512 + lane*8;
  float v[8];
  float4 u0 = *reinterpret_cast<const float4*>(row);
  float4 u1 = *reinterpret_cast<const float4*>(row+4);
  v[0]=u0.x; v[1]=u0.y; v[2]=u0.z; v[3]=u0.w;
  v[4]=u1.x; v[5]=u1.y; v[6]=u1.z; v[7]=u1.w;
  float s = 0.f;
  #pragma unroll
  for(int i=0;i<8;i++) s += v[i];
  WREDUCE64(s);
  float m = s*(1.f/512.f);
  float vv = 0.f;
  #pragma unroll
  for(int i=0;i<8;i++){ float d = v[i]-m; vv += d*d; }
  WREDUCE64(vv);
  float rs = rsqrtf(vv*(1.f/512.f) + 1e-6f);
  s8v o;
  #pragma unroll
  for(int i=0;i<8;i++) o[i] = (short)f2bf((v[i]-m)*rs);
  *reinterpret_cast<s8v*>(out + (size_t)wave*512 + lane*8) = o;
}

// ---------------- head1 GEMM (K=512) + f32 bias, raw f32 out ----------------
__global__ __launch_bounds__(256) void k_head1_gemm(const u16* A, const u16* Bt, const float* hb, float* out, int M){
  int wave = (blockIdx.x*blockDim.x + threadIdx.x) >> 6;
  int lane = threadIdx.x & 63;
  int row0 = wave*16; if(row0 >= M) return;
  int c = lane & 15, q = lane >> 4;
  s8v a[16];
  #pragma unroll
  for(int kc=0; kc<16; kc++)
    a[kc] = *reinterpret_cast<const s8v*>(A + (size_t)(row0+c)*512 + kc*32 + q*8);
  #pragma unroll
  for(int ct=0; ct<4; ct++){
    f32x4 acc = {0.f,0.f,0.f,0.f};
    #pragma unroll
    for(int kc=0; kc<16; kc++){
      s8v b = *reinterpret_cast<const s8v*>(Bt + (size_t)(ct*16+c)*512 + kc*32 + q*8);
      acc = MFMA(a[kc], b, acc);
    }
    float bi = hb[ct*16+c];
    #pragma unroll
    for(int r=0;r<4;r++) out[(size_t)(row0+q*4+r)*64 + ct*16 + c] = acc[r] + bi;
  }
}

// ---------------- per-node: LN(y2)+relu, dot hW3 (f32), pooled atomicAdd ----------------
__global__ __launch_bounds__(256) void k_energy(const float* y2, const float* hW3, const float* hb3,
    const int* batch, float* pooled, int N){
  int wave = (blockIdx.x*blockDim.x + threadIdx.x) >> 6;
  int lane = threadIdx.x & 63;
  if(wave >= N) return;
  float v = y2[(size_t)wave*64 + lane];
  float s = v; WREDUCE64(s);
  float m = s*(1.f/64.f);
  float d = v - m;
  float s2 = d*d; WREDUCE64(s2);
  float z = fmaxf(d * rsqrtf(s2*(1.f/64.f) + 1e-6f), 0.f);
  float e_ = z * hW3[lane];
  WREDUCE64(e_);
  if(lane == 0) atomicAdd(&pooled[batch[wave]], e_ + hb3[0]);
}

// ---------------- output f32 ----------------
__global__ __launch_bounds__(256) void k_out(const float* pooled, float* out, int G){
  int tid = blockIdx.x*256 + threadIdx.x;
  if(tid < G) out[tid] = pooled[tid] * 0.11785113019775793f; // 1/sqrt(72)
}

extern "C" void kernel_launch(void* const* d_in, const int* in_sizes, int n_in,
                              void* d_out, int out_size, void* d_ws, size_t ws_size,
                              hipStream_t stream){
  const int*   edge_src  = (const int*)d_in[1];
  const int*   edge_dst  = (const int*)d_in[2];
  const float* edge_vec  = (const float*)d_in[3];
  const int*   batch     = (const int*)d_in[4];
  const int*   node_atom = (const int*)d_in[5];
  const float* ele    = (const float*)d_in[6];
  const float* W_embed= (const float*)d_in[7];
  const float* W_edge = (const float*)d_in[8];
  const float* Wq = (const float*)d_in[9];
  const float* Wk = (const float*)d_in[10];
  const float* Wv = (const float*)d_in[11];
  const float* Wr1= (const float*)d_in[12];
  const float* Wr2= (const float*)d_in[13];
  const float* Wo = (const float*)d_in[14];
  const float* W1 = (const float*)d_in[15];
  const float* W2 = (const float*)d_in[16];
  const float* W_feat=(const float*)d_in[17];
  const float* hW1= (const float*)d_in[18];
  const float* hb1= (const float*)d_in[19];
  const float* hW2= (const float*)d_in[20];
  const float* hb2= (const float*)d_in[21];
  const float* hW3= (const float*)d_in[22];
  const float* hb3= (const float*)d_in[23];
  (void)n_in; (void)ws_size;

  const int E = in_sizes[1];
  const int N = in_sizes[4];
  const int G = out_size;

  // ---- workspace layout: peak ~139 MB (proven crash-free) ----
  char* base = (char*)d_ws;
  size_t off = 0;
  #define ALLOC(ty, name, count) ty* name = (ty*)(base + off); off = (off + (size_t)(count)*sizeof(ty) + 255) & ~(size_t)255;
  ALLOC(float, r_arr, E)
  ALLOC(u16,   shb,   (size_t)E*16)
  ALLOC(u16,   rbfb,  (size_t)E*64)
  ALLOC(u16,   ebf,   (size_t)E*64)
  ALLOC(u16,   vbf,   (size_t)E*64)
  ALLOC(float, exb,   (size_t)E*4)
  ALLOC(float, radialb,(size_t)E*4)   // loop-unused now; alias region for hh1
  ALLOC(u16,   hbf,   (size_t)N*64)
  ALLOC(u16,   h2bf,  (size_t)N*64)
  ALLOC(u16,   aggbf, (size_t)N*64)
  ALLOC(u16,   xbf,   (size_t)N*64)
  ALLOC(float, Qb,    (size_t)N*64)
  ALLOC(float, xb,    (size_t)N*64)
  ALLOC(u16,   tbf,   (size_t)N*256)
  ALLOC(int,   deg,   N)
  ALLOC(int,   rowptr,N+1)
  ALLOC(int,   cursor,N)
  ALLOC(int,   csr,   E)
  ALLOC(float, pooled,G)
  ALLOC(u16, ele_bf, 120*32)
  ALLOC(u16, WembT, 64*32)
  ALLOC(u16, WedgeT,64*160)
  ALLOC(u16, WqT,  6*64*64)   // WqT..WoT contiguous (each 48 KB, 256-aligned)
  ALLOC(u16, WkT,  6*64*64)
  ALLOC(u16, WvT,  6*64*64)
  ALLOC(u16, Wr1T, 6*64*64)
  ALLOC(u16, WoT,  6*64*64)
  ALLOC(u16, W1T,  6*256*64)
  ALLOC(u16, W2T,  6*64*256)
  ALLOC(u16, WfT,  512*64)
  ALLOC(u16, hW1T, 64*512)
  ALLOC(u16, hW2T, 64*64)
  #undef ALLOC
  // tail-phase aliases into loop-dead regions:
  float* featraw = (float*)vbf;    // 32 MB
  u16*   featbf  = rbfb;           // 16 MB <= 32 MB
  float* y1      = exb;            // 4 MB
  u16*   hh1     = (u16*)radialb;  // 2 MB <= 4 MB
  float* y2      = Qb;             // 4 MB

  auto cdiv = [](int a, int b){ return (a + b - 1)/b; };

  k_convert<<<cdiv(120*32,256),256,0,stream>>>(ele, ele_bf, 120*32);
  k_transpose<<<cdiv(64*32,256),256,0,stream>>>(W_embed, WembT, 1, 32, 64, 32);
  k_transpose<<<cdiv(64*160,256),256,0,stream>>>(W_edge, WedgeT, 1, 137, 64, 160);
  k_transpose5<<<cdiv(5*6*64*64,256),256,0,stream>>>(Wq, Wk, Wv, Wr1, Wo, WqT);
  k_transpose<<<cdiv(6*256*64,256),256,0,stream>>>(W1, W1T, 6, 64, 256, 64);
  k_transpose<<<cdiv(6*64*256,256),256,0,stream>>>(W2, W2T, 6, 256, 64, 256);
  k_transpose<<<cdiv(512*64,256),256,0,stream>>>(W_feat, WfT, 1, 64, 512, 64);
  k_transpose<<<cdiv(64*512,256),256,0,stream>>>(hW1, hW1T, 1, 512, 64, 512);
  k_transpose<<<cdiv(64*64,256),256,0,stream>>>(hW2, hW2T, 1, 64, 64, 64);

  hipMemsetAsync(deg, 0, (size_t)N*sizeof(int), stream);
  hipMemsetAsync(pooled, 0, (size_t)G*sizeof(float), stream);

  k_edge_geom<<<cdiv(E,256),256,0,stream>>>(edge_vec, r_arr, shb, E);
  k_rbf<<<cdiv(E*64,256),256,0,stream>>>(r_arr, rbfb, E);
  k_embed<<<N/64, 256, 0, stream>>>(node_atom, ele_bf, WembT, xb, N);
  k_edge_embed<<<E/64, 256, 0, stream>>>(edge_src, edge_dst, node_atom, ele_bf, shb, rbfb, WedgeT, ebf, E);
  k_count<<<cdiv(E,256),256,0,stream>>>(edge_dst, deg, E);
  k_scan<<<1,1024,0,stream>>>(deg, rowptr, cursor, N);
  k_scatter<<<cdiv(E,256),256,0,stream>>>(edge_dst, cursor, csr, E);

  k_ln64<<<cdiv(N,4),256,0,stream>>>(xb, hbf, N);   // layer-0 input LN
  for(int l=0; l<6; l++){
    k_qgemm<<<N/64,256,0,stream>>>(hbf, WqT + l*4096, Qb, N);
    k_kvrad<<<E/64,256,0,stream>>>(hbf, ebf, rbfb, edge_src, edge_dst, Qb, r_arr,
                                   WkT + l*4096, WvT + l*4096, Wr1T + l*4096, Wr2 + l*256,
                                   vbf, exb, E);
    k_agg<<<cdiv(N,4),256,0,stream>>>(rowptr, csr, exb, vbf, aggbf, N);
    k_wo_ln<<<N/64,256,0,stream>>>(aggbf, WoT + l*4096, xb, h2bf, N);
    k_ffn1<<<N/64,256,0,stream>>>(h2bf, W1T + l*16384, tbf, N);
    k_ffn2_ln<<<N/64,256,0,stream>>>(tbf, W2T + l*16384, xb, hbf, xbf, (l==5)?1:0, N);
  }

  k_feat<<<N/64,256,0,stream>>>(xbf, WfT, featraw, N);
  k_ln512<<<cdiv(N,4),256,0,stream>>>(featraw, featbf, N);
  k_head1_gemm<<<N/64,256,0,stream>>>(featbf, hW1T, hb1, y1, N);
  k_lnrelu64<<<cdiv(N,4),256,0,stream>>>(y1, hh1, N);
  k_gemm64_bias<<<N/64,256,0,stream>>>(hh1, hW2T, hb2, y2, N);
  k_energy<<<cdiv(N,4),256,0,stream>>>(y2, hW3, hb3, batch, pooled, N);
  k_out<<<cdiv(G,256),256,0,stream>>>(pooled, (float*)d_out, G);
}

// Round 9
// 1043.004 us; speedup vs baseline: 5.7174x; 1.0476x over previous
//
#include <hip/hip_runtime.h>

typedef short s8v __attribute__((ext_vector_type(8)));
typedef float f32x4 __attribute__((ext_vector_type(4)));
typedef unsigned short u16;

__device__ __forceinline__ float bf2f(u16 h){
  union { unsigned u; float f; } v; v.u = ((unsigned)h) << 16; return v.f;
}
__device__ __forceinline__ u16 f2bf(float f){
  union { float f; unsigned u; } v; v.f = f;
  unsigned u = v.u;
  return (u16)((u + 0x7fffu + ((u >> 16) & 1u)) >> 16);
}
#define MFMA(a,b,c) __builtin_amdgcn_mfma_f32_16x16x32_bf16((a),(b),(c),0,0,0)

#define WREDUCE64(s) { s += __shfl_xor(s,1); s += __shfl_xor(s,2); s += __shfl_xor(s,4); \
                       s += __shfl_xor(s,8); s += __shfl_xor(s,16); s += __shfl_xor(s,32); }
#define QREDUCE16(s) { s += __shfl_xor(s,1); s += __shfl_xor(s,2); s += __shfl_xor(s,4); s += __shfl_xor(s,8); }

// ---------------- transpose f32 -> bf16 (with zero row padding): dst[b][c][rp] = src[b][rp][c] ----------------
__global__ __launch_bounds__(256) void k_transpose(const float* src, u16* dst, int B, int R, int C, int Rpad){
  int idx = blockIdx.x*256 + threadIdx.x;
  int total = B*C*Rpad;
  if(idx >= total) return;
  int b = idx / (C*Rpad);
  int rem = idx - b*C*Rpad;
  int cI = rem / Rpad;
  int rI = rem - cI*Rpad;
  dst[idx] = (rI < R) ? f2bf(src[(size_t)b*R*C + (size_t)rI*C + cI]) : (u16)0;
}

// 5 batched 6x64x64 transposes in one launch (dst buffers contiguous)
__global__ __launch_bounds__(256) void k_transpose5(const float* W0, const float* W1, const float* W2,
    const float* W3, const float* W4, u16* dst){
  int idx = blockIdx.x*256 + threadIdx.x; // 5*6*64*64
  int which = idx / (6*64*64);
  int rem = idx - which*(6*64*64);
  const float* src = (which==0)?W0:(which==1)?W1:(which==2)?W2:(which==3)?W3:W4;
  int b = rem >> 12;
  int r2 = rem & 4095;
  int cI = r2 >> 6, rI = r2 & 63;
  dst[idx] = f2bf(src[b*4096 + rI*64 + cI]);
}

// ---------------- f32 -> bf16 elementwise convert ----------------
__global__ __launch_bounds__(256) void k_convert(const float* src, u16* dst, int n){
  int idx = blockIdx.x*256 + threadIdx.x;
  if(idx < n) dst[idx] = f2bf(src[idx]);
}

// ---------------- fused per-edge geometry: r, sh, rbf (one wave per edge) ----------------
__global__ __launch_bounds__(256) void k_edge_geom_rbf(const float* evec, float* r_out, u16* shb, u16* rbfb, int E){
  int e = (blockIdx.x*256 + threadIdx.x) >> 6;
  int j = threadIdx.x & 63;
  if(e >= E) return;
  float vx = evec[(size_t)e*3+0];
  float vy = evec[(size_t)e*3+1];
  float vz = evec[(size_t)e*3+2];
  float r = sqrtf(vx*vx + vy*vy + vz*vz);
  float d = r - (10.f/63.f)*(float)j;
  rbfb[(size_t)e*64 + j] = f2bf(__expf(-81.92f*d*d));
  if(j < 16){
    float inv = 1.f/(r + 1e-12f);
    // u = edge_vec[:, [1,2,0]] / r  -> x=vec1, y=vec2, z=vec0
    float x = vy*inv, y = vz*inv, z = vx*inv;
    const float s3 = 1.7320508075688772f, s15 = 3.872983346207417f;
    const float s5h = 1.118033988749895f, s15h = 1.9364916731037085f;
    float sh;
    switch(j){
      case 0: sh = 1.f; break;
      case 1: sh = s3*x; break;
      case 2: sh = s3*y; break;
      case 3: sh = s3*z; break;
      case 4: sh = s15*x*y; break;
      case 5: sh = s15*y*z; break;
      case 6: sh = s5h*(3.f*z*z - 1.f); break;
      case 7: sh = s15*x*z; break;
      case 8: sh = s15h*(x*x - y*y); break;
      default: sh = 0.f; break;
    }
    shb[(size_t)e*16 + j] = f2bf(sh);
    if(j == 0) r_out[e] = r;
  }
}

// ---------------- x = ele_embed[atom] @ W_embed  (K=32, Nc=64) ----------------
__global__ __launch_bounds__(256) void k_embed(const int* atom, const u16* ele, const u16* Bt, float* x, int M){
  int wave = (blockIdx.x*blockDim.x + threadIdx.x) >> 6;
  int lane = threadIdx.x & 63;
  int row0 = wave*16; if(row0 >= M) return;
  int c = lane & 15, q = lane >> 4;
  int at = atom[row0 + c];
  s8v a = *reinterpret_cast<const s8v*>(ele + (size_t)at*32 + q*8);
  #pragma unroll
  for(int ct=0; ct<4; ct++){
    s8v b = *reinterpret_cast<const s8v*>(Bt + (ct*16+c)*32 + q*8);
    f32x4 acc = {0.f,0.f,0.f,0.f};
    acc = MFMA(a, b, acc);
    #pragma unroll
    for(int r=0;r<4;r++) x[(size_t)(row0+q*4+r)*64 + ct*16 + c] = acc[r];
  }
}

// ---------------- e = [nf_src, nf_dst, sh, rbf] @ W_edge  (K padded 137->160) ----------------
__global__ __launch_bounds__(256) void k_edge_embed(const int* srcI, const int* dstI, const int* atom,
    const u16* ele, const u16* shb, const u16* rbfb, const u16* Bt, u16* ebf, int E){
  int wave = (blockIdx.x*blockDim.x + threadIdx.x) >> 6;
  int lane = threadIdx.x & 63;
  int row0 = wave*16; if(row0 >= E) return;
  int c = lane & 15, q = lane >> 4;
  int erow = row0 + c;
  s8v a[5];
  a[0] = *reinterpret_cast<const s8v*>(ele + (size_t)atom[srcI[erow]]*32 + q*8);
  a[1] = *reinterpret_cast<const s8v*>(ele + (size_t)atom[dstI[erow]]*32 + q*8);
  #pragma unroll
  for(int kc=2; kc<5; kc++){
    #pragma unroll
    for(int j=0;j<8;j++){
      int col = kc*32 + q*8 + j;
      u16 v;
      if(col < 73)       v = shb[(size_t)erow*16 + (col-64)];
      else if(col < 137) v = rbfb[(size_t)erow*64 + (col-73)];
      else               v = 0;
      a[kc][j] = (short)v;
    }
  }
  #pragma unroll
  for(int ct=0; ct<4; ct++){
    f32x4 acc = {0.f,0.f,0.f,0.f};
    #pragma unroll
    for(int kc=0; kc<5; kc++){
      s8v b = *reinterpret_cast<const s8v*>(Bt + (ct*16+c)*160 + kc*32 + q*8);
      acc = MFMA(a[kc], b, acc);
    }
    #pragma unroll
    for(int r_=0;r_<4;r_++) ebf[(size_t)(row0+q*4+r_)*64 + ct*16 + c] = f2bf(acc[r_]);
  }
}

// ---------------- LN over 64 (f32 in, bf16 out) ----------------
__global__ __launch_bounds__(256) void k_ln64(const float* x, u16* out, int N){
  int wave = (blockIdx.x*blockDim.x + threadIdx.x) >> 6;
  int lane = threadIdx.x & 63;
  if(wave >= N) return;
  float v = x[(size_t)wave*64 + lane];
  float s = v; WREDUCE64(s);
  float m = s*(1.f/64.f);
  float d = v - m;
  float s2 = d*d; WREDUCE64(s2);
  out[(size_t)wave*64 + lane] = f2bf(d * rsqrtf(s2*(1.f/64.f) + 1e-6f));
}
__global__ __launch_bounds__(256) void k_lnrelu64(const float* x, u16* out, int N){
  int wave = (blockIdx.x*blockDim.x + threadIdx.x) >> 6;
  int lane = threadIdx.x & 63;
  if(wave >= N) return;
  float v = x[(size_t)wave*64 + lane];
  float s = v; WREDUCE64(s);
  float m = s*(1.f/64.f);
  float d = v - m;
  float s2 = d*d; WREDUCE64(s2);
  float z = d * rsqrtf(s2*(1.f/64.f) + 1e-6f);
  out[(size_t)wave*64 + lane] = f2bf(fmaxf(z, 0.f));
}

// ---------------- generic M x 64 GEMM (K=64), f32 out ----------------
__global__ __launch_bounds__(256) void k_qgemm(const u16* A, const u16* Bt, float* out, int M){
  int wave = (blockIdx.x*blockDim.x + threadIdx.x) >> 6;
  int lane = threadIdx.x & 63;
  int row0 = wave*16; if(row0 >= M) return;
  int c = lane & 15, q = lane >> 4;
  s8v a0 = *reinterpret_cast<const s8v*>(A + (size_t)(row0+c)*64 + q*8);
  s8v a1 = *reinterpret_cast<const s8v*>(A + (size_t)(row0+c)*64 + 32 + q*8);
  #pragma unroll
  for(int ct=0; ct<4; ct++){
    s8v b0 = *reinterpret_cast<const s8v*>(Bt + (ct*16+c)*64 + q*8);
    s8v b1 = *reinterpret_cast<const s8v*>(Bt + (ct*16+c)*64 + 32 + q*8);
    f32x4 acc = {0.f,0.f,0.f,0.f};
    acc = MFMA(a0, b0, acc);
    acc = MFMA(a1, b1, acc);
    #pragma unroll
    for(int r=0;r<4;r++) out[(size_t)(row0+q*4+r)*64 + ct*16 + c] = acc[r];
  }
}

// ---------------- + f32 bias, f32 out (head layer 2 pre-LN) ----------------
__global__ __launch_bounds__(256) void k_gemm64_bias(const u16* A, const u16* Bt, const float* bias, float* out, int M){
  int wave = (blockIdx.x*blockDim.x + threadIdx.x) >> 6;
  int lane = threadIdx.x & 63;
  int row0 = wave*16; if(row0 >= M) return;
  int c = lane & 15, q = lane >> 4;
  s8v a0 = *reinterpret_cast<const s8v*>(A + (size_t)(row0+c)*64 + q*8);
  s8v a1 = *reinterpret_cast<const s8v*>(A + (size_t)(row0+c)*64 + 32 + q*8);
  #pragma unroll
  for(int ct=0; ct<4; ct++){
    s8v b0 = *reinterpret_cast<const s8v*>(Bt + (ct*16+c)*64 + q*8);
    s8v b1 = *reinterpret_cast<const s8v*>(Bt + (ct*16+c)*64 + 32 + q*8);
    f32x4 acc = {0.f,0.f,0.f,0.f};
    acc = MFMA(a0, b0, acc);
    acc = MFMA(a1, b1, acc);
    float bi = bias[ct*16+c];
    #pragma unroll
    for(int r=0;r<4;r++) out[(size_t)(row0+q*4+r)*64 + ct*16 + c] = acc[r] + bi;
  }
}

// ---------------- x += agg @ WoT; h2 = LN(x) fused ----------------
__global__ __launch_bounds__(256) void k_wo_ln(const u16* A, const u16* Bt, float* x, u16* hout, int M){
  int wave = (blockIdx.x*blockDim.x + threadIdx.x) >> 6;
  int lane = threadIdx.x & 63;
  int row0 = wave*16; if(row0 >= M) return;
  int c = lane & 15, q = lane >> 4;
  s8v a0 = *reinterpret_cast<const s8v*>(A + (size_t)(row0+c)*64 + q*8);
  s8v a1 = *reinterpret_cast<const s8v*>(A + (size_t)(row0+c)*64 + 32 + q*8);
  float nx[4][4];
  #pragma unroll
  for(int ct=0; ct<4; ct++){
    s8v b0 = *reinterpret_cast<const s8v*>(Bt + (ct*16+c)*64 + q*8);
    s8v b1 = *reinterpret_cast<const s8v*>(Bt + (ct*16+c)*64 + 32 + q*8);
    f32x4 acc = {0.f,0.f,0.f,0.f};
    acc = MFMA(a0, b0, acc);
    acc = MFMA(a1, b1, acc);
    #pragma unroll
    for(int r=0;r<4;r++){
      size_t idx = (size_t)(row0+q*4+r)*64 + ct*16 + c;
      float t = x[idx] + acc[r];
      x[idx] = t;
      nx[ct][r] = t;
    }
  }
  #pragma unroll
  for(int r=0;r<4;r++){
    float s = nx[0][r]+nx[1][r]+nx[2][r]+nx[3][r];
    QREDUCE16(s);
    float m = s*(1.f/64.f);
    float vv = 0.f;
    #pragma unroll
    for(int ct=0;ct<4;ct++){ float d = nx[ct][r]-m; vv += d*d; }
    QREDUCE16(vv);
    float rs = rsqrtf(vv*(1.f/64.f) + 1e-6f);
    #pragma unroll
    for(int ct=0;ct<4;ct++)
      hout[(size_t)(row0+q*4+r)*64 + ct*16 + c] = f2bf((nx[ct][r]-m)*rs);
  }
}

// ---------------- fused: k,v,hid MFMAs; logits+radial via quad-shuffle (no LDS) ----------------
__global__ __launch_bounds__(256) void k_kvrad(const u16* hbf, const u16* ebf, const u16* rbfb,
    const int* srcI, const int* dstI, const float* Qb, const float* r_arr,
    const u16* WkT, const u16* WvT, const u16* Wr1T, const float* Wr2,
    u16* vbf, float* exb, int E){
  int wave = (blockIdx.x*256 + threadIdx.x) >> 6;
  int lane = threadIdx.x & 63;
  int row0 = wave*16;
  int c = lane & 15, q = lane >> 4;
  int sr = srcI[row0 + c];
  s8v a0, a1;
  {
    s8v h0 = *reinterpret_cast<const s8v*>(hbf + (size_t)sr*64 + q*8);
    s8v h1 = *reinterpret_cast<const s8v*>(hbf + (size_t)sr*64 + 32 + q*8);
    s8v e0 = *reinterpret_cast<const s8v*>(ebf + (size_t)(row0+c)*64 + q*8);
    s8v e1 = *reinterpret_cast<const s8v*>(ebf + (size_t)(row0+c)*64 + 32 + q*8);
    #pragma unroll
    for(int j=0;j<8;j++){
      a0[j] = (short)f2bf(bf2f((u16)h0[j]) + bf2f((u16)e0[j]));
      a1[j] = (short)f2bf(bf2f((u16)h1[j]) + bf2f((u16)e1[j]));
    }
  }
  s8v r0 = *reinterpret_cast<const s8v*>(rbfb + (size_t)(row0+c)*64 + q*8);
  s8v r1 = *reinterpret_cast<const s8v*>(rbfb + (size_t)(row0+c)*64 + 32 + q*8);
  int dr[4];
  #pragma unroll
  for(int r=0;r<4;r++) dr[r] = dstI[row0 + q*4 + r];
  const float4* wr2v = reinterpret_cast<const float4*>(Wr2);
  // comb[h][r] accumulates 0.25*qk + radial contributions (linear, reduced together)
  float comb[4][4];
  #pragma unroll
  for(int h=0;h<4;h++)
    #pragma unroll
    for(int r=0;r<4;r++) comb[h][r] = 0.f;
  #pragma unroll
  for(int ct=0; ct<4; ct++){
    s8v bk0 = *reinterpret_cast<const s8v*>(WkT + (ct*16+c)*64 + q*8);
    s8v bk1 = *reinterpret_cast<const s8v*>(WkT + (ct*16+c)*64 + 32 + q*8);
    s8v bv0 = *reinterpret_cast<const s8v*>(WvT + (ct*16+c)*64 + q*8);
    s8v bv1 = *reinterpret_cast<const s8v*>(WvT + (ct*16+c)*64 + 32 + q*8);
    s8v bw0 = *reinterpret_cast<const s8v*>(Wr1T + (ct*16+c)*64 + q*8);
    s8v bw1 = *reinterpret_cast<const s8v*>(Wr1T + (ct*16+c)*64 + 32 + q*8);
    f32x4 kacc = {0.f,0.f,0.f,0.f};
    kacc = MFMA(a0, bk0, kacc); kacc = MFMA(a1, bk1, kacc);
    f32x4 vacc = {0.f,0.f,0.f,0.f};
    vacc = MFMA(a0, bv0, vacc); vacc = MFMA(a1, bv1, vacc);
    f32x4 hacc = {0.f,0.f,0.f,0.f};
    hacc = MFMA(r0, bw0, hacc); hacc = MFMA(r1, bw1, hacc);
    float4 w2 = wr2v[ct*16 + c];
    #pragma unroll
    for(int r=0;r<4;r++){
      vbf[(size_t)(row0+q*4+r)*64 + ct*16 + c] = f2bf(vacc[r]);
      // qk contribution for head ct, row q*4+r:
      comb[ct][r] += 0.25f * kacc[r] * Qb[(size_t)dr[r]*64 + ct*16 + c];
      // radial contribution: col = ct*16+c feeds all 4 heads
      float y = hacc[r];
      float sv = y / (1.f + __expf(-y));
      comb[0][r] += sv * w2.x;
      comb[1][r] += sv * w2.y;
      comb[2][r] += sv * w2.z;
      comb[3][r] += sv * w2.w;
    }
  }
  // reduce over the 16 c-lanes of each quad
  #pragma unroll
  for(int m=1; m<16; m<<=1){
    #pragma unroll
    for(int h=0;h<4;h++)
      #pragma unroll
      for(int r=0;r<4;r++) comb[h][r] += __shfl_xor(comb[h][r], m);
  }
  // lane c in quad handles (r = c>>2, h = c&3)
  int hh = c & 3, rr = c >> 2;
  float logit = comb[0][0];
  #pragma unroll
  for(int h=0;h<4;h++)
    #pragma unroll
    for(int r=0;r<4;r++)
      if(h || r) logit = (hh==h && rr==r) ? comb[h][r] : logit;
  int row = row0 + q*4 + rr;
  exb[(size_t)row0*4 + lane] = (r_arr[row] < 10.f) ? __expf(logit) : 0.f;
}

// ---------------- CSR build ----------------
__global__ __launch_bounds__(256) void k_count(const int* dstI, int* deg, int E){
  int tid = blockIdx.x*256 + threadIdx.x;
  if(tid < E) atomicAdd(&deg[dstI[tid]], 1);
}
__global__ __launch_bounds__(1024) void k_scan(const int* deg, int* rowptr, int* cursor, int N){
  __shared__ int wsum[17];
  int tid = threadIdx.x;
  int per = (N + 1023) >> 10;
  int base = tid * per;
  int s = 0;
  for(int i=0;i<per;i++){ int idx = base+i; if(idx < N) s += deg[idx]; }
  int lane = tid & 63, wid = tid >> 6;
  int inc = s;
  for(int d=1; d<64; d<<=1){
    int t = __shfl_up(inc, d);
    if(lane >= d) inc += t;
  }
  if(lane == 63) wsum[wid+1] = inc;
  if(tid == 0) wsum[0] = 0;
  __syncthreads();
  if(tid == 0){ for(int w=1; w<=16; w++) wsum[w] += wsum[w-1]; }
  __syncthreads();
  int run = inc - s + wsum[wid];
  for(int i=0;i<per;i++){
    int idx = base + i;
    if(idx < N){ rowptr[idx] = run; cursor[idx] = run; run += deg[idx]; }
  }
  if(tid == 1023) rowptr[N] = wsum[16];
}
__global__ __launch_bounds__(256) void k_scatter(const int* dstI, int* cursor, int* csr, int E){
  int tid = blockIdx.x*256 + threadIdx.x;
  if(tid < E){
    int p = atomicAdd(&cursor[dstI[tid]], 1);
    csr[p] = tid;
  }
}

// ---------------- softmax-denominator + aggregation, 4-edge-parallel ----------------
__global__ __launch_bounds__(256) void k_agg(const int* rowptr, const int* csr, const float* exb, const u16* vbf, u16* aggbf, int N){
  int wave = (blockIdx.x*256 + threadIdx.x) >> 6;
  int lane = threadIdx.x & 63;
  if(wave >= N) return;
  int s0 = rowptr[wave], s1 = rowptr[wave+1];
  float s[4] = {0.f,0.f,0.f,0.f};
  for(int p = s0 + lane; p < s1; p += 64){
    int e = csr[p];
    float4 ev = *reinterpret_cast<const float4*>(exb + (size_t)e*4);
    s[0] += ev.x; s[1] += ev.y; s[2] += ev.z; s[3] += ev.w;
  }
  #pragma unroll
  for(int i=0;i<4;i++){ WREDUCE64(s[i]); }
  int ep = lane >> 4, cc = lane & 15;
  int hh = cc >> 2;
  float inv = 1.f/(s[hh] + 1e-9f);
  float a0=0.f, a1=0.f, a2=0.f, a3=0.f;
  for(int p = s0 + ep; p < s1; p += 4){
    int e = csr[p];
    ushort4 v4 = *reinterpret_cast<const ushort4*>(vbf + (size_t)e*64 + cc*4);
    float ex = exb[(size_t)e*4 + hh];
    a0 += ex*bf2f(v4.x); a1 += ex*bf2f(v4.y); a2 += ex*bf2f(v4.z); a3 += ex*bf2f(v4.w);
  }
  a0 += __shfl_xor(a0,16); a0 += __shfl_xor(a0,32);
  a1 += __shfl_xor(a1,16); a1 += __shfl_xor(a1,32);
  a2 += __shfl_xor(a2,16); a2 += __shfl_xor(a2,32);
  a3 += __shfl_xor(a3,16); a3 += __shfl_xor(a3,32);
  if(ep == 0){
    ushort4 o;
    o.x = f2bf(a0*inv); o.y = f2bf(a1*inv); o.z = f2bf(a2*inv); o.w = f2bf(a3*inv);
    *reinterpret_cast<ushort4*>(aggbf + (size_t)wave*64 + cc*4) = o;
  }
}

// ---------------- FFN ----------------
__global__ __launch_bounds__(256) void k_ffn1(const u16* A, const u16* Bt, u16* tout, int M){
  int wave = (blockIdx.x*blockDim.x + threadIdx.x) >> 6;
  int lane = threadIdx.x & 63;
  int row0 = wave*16; if(row0 >= M) return;
  int c = lane & 15, q = lane >> 4;
  s8v a0 = *reinterpret_cast<const s8v*>(A + (size_t)(row0+c)*64 + q*8);
  s8v a1 = *reinterpret_cast<const s8v*>(A + (size_t)(row0+c)*64 + 32 + q*8);
  #pragma unroll
  for(int ct=0; ct<16; ct++){
    s8v b0 = *reinterpret_cast<const s8v*>(Bt + (ct*16+c)*64 + q*8);
    s8v b1 = *reinterpret_cast<const s8v*>(Bt + (ct*16+c)*64 + 32 + q*8);
    f32x4 acc = {0.f,0.f,0.f,0.f};
    acc = MFMA(a0, b0, acc);
    acc = MFMA(a1, b1, acc);
    #pragma unroll
    for(int r=0;r<4;r++){
      float y = acc[r];
      tout[(size_t)(row0+q*4+r)*256 + ct*16 + c] = f2bf(y / (1.f + __expf(-y)));
    }
  }
}
// x += T @ W2T; hbf = LN(x); optional xbf = bf16(x)
__global__ __launch_bounds__(256) void k_ffn2_ln(const u16* T, const u16* Bt, float* x, u16* hout, u16* xbf, int writex, int M){
  int wave = (blockIdx.x*blockDim.x + threadIdx.x) >> 6;
  int lane = threadIdx.x & 63;
  int row0 = wave*16; if(row0 >= M) return;
  int c = lane & 15, q = lane >> 4;
  s8v a[8];
  #pragma unroll
  for(int kc=0; kc<8; kc++)
    a[kc] = *reinterpret_cast<const s8v*>(T + (size_t)(row0+c)*256 + kc*32 + q*8);
  float nx[4][4];
  #pragma unroll
  for(int ct=0; ct<4; ct++){
    f32x4 acc = {0.f,0.f,0.f,0.f};
    #pragma unroll
    for(int kc=0; kc<8; kc++){
      s8v b = *reinterpret_cast<const s8v*>(Bt + (ct*16+c)*256 + kc*32 + q*8);
      acc = MFMA(a[kc], b, acc);
    }
    #pragma unroll
    for(int r=0;r<4;r++){
      size_t idx = (size_t)(row0+q*4+r)*64 + ct*16 + c;
      float t = x[idx] + acc[r];
      x[idx] = t;
      nx[ct][r] = t;
      if(writex) xbf[idx] = f2bf(t);
    }
  }
  #pragma unroll
  for(int r=0;r<4;r++){
    float s = nx[0][r]+nx[1][r]+nx[2][r]+nx[3][r];
    QREDUCE16(s);
    float m = s*(1.f/64.f);
    float vv = 0.f;
    #pragma unroll
    for(int ct=0;ct<4;ct++){ float d = nx[ct][r]-m; vv += d*d; }
    QREDUCE16(vv);
    float rs = rsqrtf(vv*(1.f/64.f) + 1e-6f);
    #pragma unroll
    for(int ct=0;ct<4;ct++)
      hout[(size_t)(row0+q*4+r)*64 + ct*16 + c] = f2bf((nx[ct][r]-m)*rs);
  }
}

// ---------------- feat = x @ W_feat (Nc=512, raw f32) ----------------
__global__ __launch_bounds__(256) void k_feat(const u16* A, const u16* Bt, float* out, int M){
  int wave = (blockIdx.x*blockDim.x + threadIdx.x) >> 6;
  int lane = threadIdx.x & 63;
  int row0 = wave*16; if(row0 >= M) return;
  int c = lane & 15, q = lane >> 4;
  s8v a0 = *reinterpret_cast<const s8v*>(A + (size_t)(row0+c)*64 + q*8);
  s8v a1 = *reinterpret_cast<const s8v*>(A + (size_t)(row0+c)*64 + 32 + q*8);
  #pragma unroll
  for(int ct=0; ct<32; ct++){
    s8v b0 = *reinterpret_cast<const s8v*>(Bt + (ct*16+c)*64 + q*8);
    s8v b1 = *reinterpret_cast<const s8v*>(Bt + (ct*16+c)*64 + 32 + q*8);
    f32x4 acc = {0.f,0.f,0.f,0.f};
    acc = MFMA(a0, b0, acc);
    acc = MFMA(a1, b1, acc);
    #pragma unroll
    for(int r=0;r<4;r++) out[(size_t)(row0+q*4+r)*512 + ct*16 + c] = acc[r];
  }
}

// ---------------- LN over 512 ----------------
__global__ __launch_bounds__(256) void k_ln512(const float* fr, u16* out, int N){
  int wave = (blockIdx.x*blockDim.x + threadIdx.x) >> 6;
  int lane = threadIdx.x & 63;
  if(wave >= N) return;
  const float* row = fr + (size_t)wave*512 + lane*8;
  float v[8];
  float4 u0 = *reinterpret_cast<const float4*>(row);
  float4 u1 = *reinterpret_cast<const float4*>(row+4);
  v[0]=u0.x; v[1]=u0.y; v[2]=u0.z; v[3]=u0.w;
  v[4]=u1.x; v[5]=u1.y; v[6]=u1.z; v[7]=u1.w;
  float s = 0.f;
  #pragma unroll
  for(int i=0;i<8;i++) s += v[i];
  WREDUCE64(s);
  float m = s*(1.f/512.f);
  float vv = 0.f;
  #pragma unroll
  for(int i=0;i<8;i++){ float d = v[i]-m; vv += d*d; }
  WREDUCE64(vv);
  float rs = rsqrtf(vv*(1.f/512.f) + 1e-6f);
  s8v o;
  #pragma unroll
  for(int i=0;i<8;i++) o[i] = (short)f2bf((v[i]-m)*rs);
  *reinterpret_cast<s8v*>(out + (size_t)wave*512 + lane*8) = o;
}

// ---------------- head1 GEMM (K=512) + f32 bias, raw f32 out ----------------
__global__ __launch_bounds__(256) void k_head1_gemm(const u16* A, const u16* Bt, const float* hb, float* out, int M){
  int wave = (blockIdx.x*blockDim.x + threadIdx.x) >> 6;
  int lane = threadIdx.x & 63;
  int row0 = wave*16; if(row0 >= M) return;
  int c = lane & 15, q = lane >> 4;
  s8v a[16];
  #pragma unroll
  for(int kc=0; kc<16; kc++)
    a[kc] = *reinterpret_cast<const s8v*>(A + (size_t)(row0+c)*512 + kc*32 + q*8);
  #pragma unroll
  for(int ct=0; ct<4; ct++){
    f32x4 acc = {0.f,0.f,0.f,0.f};
    #pragma unroll
    for(int kc=0; kc<16; kc++){
      s8v b = *reinterpret_cast<const s8v*>(Bt + (size_t)(ct*16+c)*512 + kc*32 + q*8);
      acc = MFMA(a[kc], b, acc);
    }
    float bi = hb[ct*16+c];
    #pragma unroll
    for(int r=0;r<4;r++) out[(size_t)(row0+q*4+r)*64 + ct*16 + c] = acc[r] + bi;
  }
}

// ---------------- per-node: LN(y2)+relu, dot hW3 (f32), pooled atomicAdd ----------------
__global__ __launch_bounds__(256) void k_energy(const float* y2, const float* hW3, const float* hb3,
    const int* batch, float* pooled, int N){
  int wave = (blockIdx.x*blockDim.x + threadIdx.x) >> 6;
  int lane = threadIdx.x & 63;
  if(wave >= N) return;
  float v = y2[(size_t)wave*64 + lane];
  float s = v; WREDUCE64(s);
  float m = s*(1.f/64.f);
  float d = v - m;
  float s2 = d*d; WREDUCE64(s2);
  float z = fmaxf(d * rsqrtf(s2*(1.f/64.f) + 1e-6f), 0.f);
  float e_ = z * hW3[lane];
  WREDUCE64(e_);
  if(lane == 0) atomicAdd(&pooled[batch[wave]], e_ + hb3[0]);
}

// ---------------- output f32 ----------------
__global__ __launch_bounds__(256) void k_out(const float* pooled, float* out, int G){
  int tid = blockIdx.x*256 + threadIdx.x;
  if(tid < G) out[tid] = pooled[tid] * 0.11785113019775793f; // 1/sqrt(72)
}

extern "C" void kernel_launch(void* const* d_in, const int* in_sizes, int n_in,
                              void* d_out, int out_size, void* d_ws, size_t ws_size,
                              hipStream_t stream){
  const int*   edge_src  = (const int*)d_in[1];
  const int*   edge_dst  = (const int*)d_in[2];
  const float* edge_vec  = (const float*)d_in[3];
  const int*   batch     = (const int*)d_in[4];
  const int*   node_atom = (const int*)d_in[5];
  const float* ele    = (const float*)d_in[6];
  const float* W_embed= (const float*)d_in[7];
  const float* W_edge = (const float*)d_in[8];
  const float* Wq = (const float*)d_in[9];
  const float* Wk = (const float*)d_in[10];
  const float* Wv = (const float*)d_in[11];
  const float* Wr1= (const float*)d_in[12];
  const float* Wr2= (const float*)d_in[13];
  const float* Wo = (const float*)d_in[14];
  const float* W1 = (const float*)d_in[15];
  const float* W2 = (const float*)d_in[16];
  const float* W_feat=(const float*)d_in[17];
  const float* hW1= (const float*)d_in[18];
  const float* hb1= (const float*)d_in[19];
  const float* hW2= (const float*)d_in[20];
  const float* hb2= (const float*)d_in[21];
  const float* hW3= (const float*)d_in[22];
  const float* hb3= (const float*)d_in[23];
  (void)n_in; (void)ws_size;

  const int E = in_sizes[1];
  const int N = in_sizes[4];
  const int G = out_size;

  // ---- workspace layout: peak ~139 MB (proven crash-free) ----
  char* base = (char*)d_ws;
  size_t off = 0;
  #define ALLOC(ty, name, count) ty* name = (ty*)(base + off); off = (off + (size_t)(count)*sizeof(ty) + 255) & ~(size_t)255;
  ALLOC(float, r_arr, E)
  ALLOC(u16,   shb,   (size_t)E*16)
  ALLOC(u16,   rbfb,  (size_t)E*64)
  ALLOC(u16,   ebf,   (size_t)E*64)
  ALLOC(u16,   vbf,   (size_t)E*64)
  ALLOC(float, exb,   (size_t)E*4)
  ALLOC(float, radialb,(size_t)E*4)   // loop-unused; alias region for hh1
  ALLOC(u16,   hbf,   (size_t)N*64)
  ALLOC(u16,   h2bf,  (size_t)N*64)
  ALLOC(u16,   aggbf, (size_t)N*64)
  ALLOC(u16,   xbf,   (size_t)N*64)
  ALLOC(float, Qb,    (size_t)N*64)
  ALLOC(float, xb,    (size_t)N*64)
  ALLOC(u16,   tbf,   (size_t)N*256)
  ALLOC(int,   deg,   N)
  ALLOC(int,   rowptr,N+1)
  ALLOC(int,   cursor,N)
  ALLOC(int,   csr,   E)
  ALLOC(float, pooled,G)
  ALLOC(u16, ele_bf, 120*32)
  ALLOC(u16, WembT, 64*32)
  ALLOC(u16, WedgeT,64*160)
  ALLOC(u16, WqT,  6*64*64)   // WqT..WoT contiguous
  ALLOC(u16, WkT,  6*64*64)
  ALLOC(u16, WvT,  6*64*64)
  ALLOC(u16, Wr1T, 6*64*64)
  ALLOC(u16, WoT,  6*64*64)
  ALLOC(u16, W1T,  6*256*64)
  ALLOC(u16, W2T,  6*64*256)
  ALLOC(u16, WfT,  512*64)
  ALLOC(u16, hW1T, 64*512)
  ALLOC(u16, hW2T, 64*64)
  #undef ALLOC
  // tail-phase aliases into loop-dead regions:
  float* featraw = (float*)vbf;    // 32 MB
  u16*   featbf  = rbfb;           // 16 MB <= 32 MB
  float* y1      = exb;            // 4 MB
  u16*   hh1     = (u16*)radialb;  // 2 MB <= 4 MB
  float* y2      = Qb;             // 4 MB

  auto cdiv = [](int a, int b){ return (a + b - 1)/b; };

  k_convert<<<cdiv(120*32,256),256,0,stream>>>(ele, ele_bf, 120*32);
  k_transpose<<<cdiv(64*32,256),256,0,stream>>>(W_embed, WembT, 1, 32, 64, 32);
  k_transpose<<<cdiv(64*160,256),256,0,stream>>>(W_edge, WedgeT, 1, 137, 64, 160);
  k_transpose5<<<cdiv(5*6*64*64,256),256,0,stream>>>(Wq, Wk, Wv, Wr1, Wo, WqT);
  k_transpose<<<cdiv(6*256*64,256),256,0,stream>>>(W1, W1T, 6, 64, 256, 64);
  k_transpose<<<cdiv(6*64*256,256),256,0,stream>>>(W2, W2T, 6, 256, 64, 256);
  k_transpose<<<cdiv(512*64,256),256,0,stream>>>(W_feat, WfT, 1, 64, 512, 64);
  k_transpose<<<cdiv(64*512,256),256,0,stream>>>(hW1, hW1T, 1, 512, 64, 512);
  k_transpose<<<cdiv(64*64,256),256,0,stream>>>(hW2, hW2T, 1, 64, 64, 64);

  hipMemsetAsync(deg, 0, (size_t)N*sizeof(int), stream);
  hipMemsetAsync(pooled, 0, (size_t)G*sizeof(float), stream);

  k_edge_geom_rbf<<<cdiv(E,4),256,0,stream>>>(edge_vec, r_arr, shb, rbfb, E);
  k_embed<<<N/64, 256, 0, stream>>>(node_atom, ele_bf, WembT, xb, N);
  k_edge_embed<<<E/64, 256, 0, stream>>>(edge_src, edge_dst, node_atom, ele_bf, shb, rbfb, WedgeT, ebf, E);
  k_count<<<cdiv(E,256),256,0,stream>>>(edge_dst, deg, E);
  k_scan<<<1,1024,0,stream>>>(deg, rowptr, cursor, N);
  k_scatter<<<cdiv(E,256),256,0,stream>>>(edge_dst, cursor, csr, E);

  k_ln64<<<cdiv(N,4),256,0,stream>>>(xb, hbf, N);   // layer-0 input LN
  for(int l=0; l<6; l++){
    k_qgemm<<<N/64,256,0,stream>>>(hbf, WqT + l*4096, Qb, N);
    k_kvrad<<<E/64,256,0,stream>>>(hbf, ebf, rbfb, edge_src, edge_dst, Qb, r_arr,
                                   WkT + l*4096, WvT + l*4096, Wr1T + l*4096, Wr2 + l*256,
                                   vbf, exb, E);
    k_agg<<<cdiv(N,4),256,0,stream>>>(rowptr, csr, exb, vbf, aggbf, N);
    k_wo_ln<<<N/64,256,0,stream>>>(aggbf, WoT + l*4096, xb, h2bf, N);
    k_ffn1<<<N/64,256,0,stream>>>(h2bf, W1T + l*16384, tbf, N);
    k_ffn2_ln<<<N/64,256,0,stream>>>(tbf, W2T + l*16384, xb, hbf, xbf, (l==5)?1:0, N);
  }

  k_feat<<<N/64,256,0,stream>>>(xbf, WfT, featraw, N);
  k_ln512<<<cdiv(N,4),256,0,stream>>>(featraw, featbf, N);
  k_head1_gemm<<<N/64,256,0,stream>>>(featbf, hW1T, hb1, y1, N);
  k_lnrelu64<<<cdiv(N,4),256,0,stream>>>(y1, hh1, N);
  k_gemm64_bias<<<N/64,256,0,stream>>>(hh1, hW2T, hb2, y2, N);
  k_energy<<<cdiv(N,4),256,0,stream>>>(y2, hW3, hb3, batch, pooled, N);
  k_out<<<cdiv(G,256),256,0,stream>>>(pooled, (float*)d_out, G);
}

// Round 10
// 1016.422 us; speedup vs baseline: 5.8669x; 1.0262x over previous
//
#include <hip/hip_runtime.h>

typedef short s8v __attribute__((ext_vector_type(8)));
typedef float f32x4 __attribute__((ext_vector_type(4)));
typedef unsigned short u16;

__device__ __forceinline__ float bf2f(u16 h){
  union { unsigned u; float f; } v; v.u = ((unsigned)h) << 16; return v.f;
}
__device__ __forceinline__ u16 f2bf(float f){
  union { float f; unsigned u; } v; v.f = f;
  unsigned u = v.u;
  return (u16)((u + 0x7fffu + ((u >> 16) & 1u)) >> 16);
}
#define MFMA(a,b,c) __builtin_amdgcn_mfma_f32_16x16x32_bf16((a),(b),(c),0,0,0)

#define WREDUCE64(s) { s += __shfl_xor(s,1); s += __shfl_xor(s,2); s += __shfl_xor(s,4); \
                       s += __shfl_xor(s,8); s += __shfl_xor(s,16); s += __shfl_xor(s,32); }
#define QREDUCE16(s) { s += __shfl_xor(s,1); s += __shfl_xor(s,2); s += __shfl_xor(s,4); s += __shfl_xor(s,8); }

// ---------------- transpose f32 -> bf16 (with zero row padding): dst[b][c][rp] = src[b][rp][c] ----------------
__global__ __launch_bounds__(256) void k_transpose(const float* src, u16* dst, int B, int R, int C, int Rpad){
  int idx = blockIdx.x*256 + threadIdx.x;
  int total = B*C*Rpad;
  if(idx >= total) return;
  int b = idx / (C*Rpad);
  int rem = idx - b*C*Rpad;
  int cI = rem / Rpad;
  int rI = rem - cI*Rpad;
  dst[idx] = (rI < R) ? f2bf(src[(size_t)b*R*C + (size_t)rI*C + cI]) : (u16)0;
}

// 5 batched 6x64x64 transposes in one launch (dst buffers contiguous)
__global__ __launch_bounds__(256) void k_transpose5(const float* W0, const float* W1, const float* W2,
    const float* W3, const float* W4, u16* dst){
  int idx = blockIdx.x*256 + threadIdx.x; // 5*6*64*64
  int which = idx / (6*64*64);
  int rem = idx - which*(6*64*64);
  const float* src = (which==0)?W0:(which==1)?W1:(which==2)?W2:(which==3)?W3:W4;
  int b = rem >> 12;
  int r2 = rem & 4095;
  int cI = r2 >> 6, rI = r2 & 63;
  dst[idx] = f2bf(src[b*4096 + rI*64 + cI]);
}

// ---------------- f32 -> bf16 elementwise convert ----------------
__global__ __launch_bounds__(256) void k_convert(const float* src, u16* dst, int n){
  int idx = blockIdx.x*256 + threadIdx.x;
  if(idx < n) dst[idx] = f2bf(src[idx]);
}

// ---------------- per-edge geometry: r, spherical harmonics ----------------
__global__ __launch_bounds__(256) void k_edge_geom(const float* evec, float* r_out, u16* shb, int E){
  int e = blockIdx.x*256 + threadIdx.x;
  if(e >= E) return;
  float vx = evec[(size_t)e*3+0];
  float vy = evec[(size_t)e*3+1];
  float vz = evec[(size_t)e*3+2];
  float r = sqrtf(vx*vx + vy*vy + vz*vz);
  float inv = 1.f/(r + 1e-12f);
  // u = edge_vec[:, [1,2,0]] / r  -> x=vec1, y=vec2, z=vec0
  float x = vy*inv, y = vz*inv, z = vx*inv;
  const float s3 = 1.7320508075688772f, s15 = 3.872983346207417f;
  const float s5h = 1.118033988749895f, s15h = 1.9364916731037085f;
  float sh[9];
  sh[0] = 1.f; sh[1] = s3*x; sh[2] = s3*y; sh[3] = s3*z;
  sh[4] = s15*x*y; sh[5] = s15*y*z; sh[6] = s5h*(3.f*z*z - 1.f);
  sh[7] = s15*x*z; sh[8] = s15h*(x*x - y*y);
  r_out[e] = r;
  #pragma unroll
  for(int i=0;i<9;i++) shb[(size_t)e*16 + i] = f2bf(sh[i]);
  #pragma unroll
  for(int i=9;i<16;i++) shb[(size_t)e*16 + i] = 0;
}

// ---------------- x = ele_embed[atom] @ W_embed  (K=32, Nc=64) ----------------
__global__ __launch_bounds__(256) void k_embed(const int* atom, const u16* ele, const u16* Bt, float* x, int M){
  int wave = (blockIdx.x*blockDim.x + threadIdx.x) >> 6;
  int lane = threadIdx.x & 63;
  int row0 = wave*16; if(row0 >= M) return;
  int c = lane & 15, q = lane >> 4;
  int at = atom[row0 + c];
  s8v a = *reinterpret_cast<const s8v*>(ele + (size_t)at*32 + q*8);
  #pragma unroll
  for(int ct=0; ct<4; ct++){
    s8v b = *reinterpret_cast<const s8v*>(Bt + (ct*16+c)*32 + q*8);
    f32x4 acc = {0.f,0.f,0.f,0.f};
    acc = MFMA(a, b, acc);
    #pragma unroll
    for(int r=0;r<4;r++) x[(size_t)(row0+q*4+r)*64 + ct*16 + c] = acc[r];
  }
}

// ---------------- e = [nf_src, nf_dst, sh, rbf(on-the-fly)] @ W_edge  (K padded 137->160) ----------------
__global__ __launch_bounds__(256) void k_edge_embed(const int* srcI, const int* dstI, const int* atom,
    const u16* ele, const u16* shb, const float* r_arr, const u16* Bt, u16* ebf, int E){
  int wave = (blockIdx.x*blockDim.x + threadIdx.x) >> 6;
  int lane = threadIdx.x & 63;
  int row0 = wave*16; if(row0 >= E) return;
  int c = lane & 15, q = lane >> 4;
  int erow = row0 + c;
  float re = r_arr[erow];
  s8v a[5];
  a[0] = *reinterpret_cast<const s8v*>(ele + (size_t)atom[srcI[erow]]*32 + q*8);
  a[1] = *reinterpret_cast<const s8v*>(ele + (size_t)atom[dstI[erow]]*32 + q*8);
  #pragma unroll
  for(int kc=2; kc<5; kc++){
    #pragma unroll
    for(int j=0;j<8;j++){
      int col = kc*32 + q*8 + j;
      u16 v;
      if(col < 73)       v = shb[(size_t)erow*16 + (col-64)];
      else if(col < 137){
        float d = re - (10.f/63.f)*(float)(col-73);
        v = f2bf(__expf(-81.92f*d*d));
      }
      else               v = 0;
      a[kc][j] = (short)v;
    }
  }
  #pragma unroll
  for(int ct=0; ct<4; ct++){
    f32x4 acc = {0.f,0.f,0.f,0.f};
    #pragma unroll
    for(int kc=0; kc<5; kc++){
      s8v b = *reinterpret_cast<const s8v*>(Bt + (ct*16+c)*160 + kc*32 + q*8);
      acc = MFMA(a[kc], b, acc);
    }
    #pragma unroll
    for(int r_=0;r_<4;r_++) ebf[(size_t)(row0+q*4+r_)*64 + ct*16 + c] = f2bf(acc[r_]);
  }
}

// ---------------- LN over 64 (f32 in, bf16 out) ----------------
__global__ __launch_bounds__(256) void k_ln64(const float* x, u16* out, int N){
  int wave = (blockIdx.x*blockDim.x + threadIdx.x) >> 6;
  int lane = threadIdx.x & 63;
  if(wave >= N) return;
  float v = x[(size_t)wave*64 + lane];
  float s = v; WREDUCE64(s);
  float m = s*(1.f/64.f);
  float d = v - m;
  float s2 = d*d; WREDUCE64(s2);
  out[(size_t)wave*64 + lane] = f2bf(d * rsqrtf(s2*(1.f/64.f) + 1e-6f));
}
__global__ __launch_bounds__(256) void k_lnrelu64(const float* x, u16* out, int N){
  int wave = (blockIdx.x*blockDim.x + threadIdx.x) >> 6;
  int lane = threadIdx.x & 63;
  if(wave >= N) return;
  float v = x[(size_t)wave*64 + lane];
  float s = v; WREDUCE64(s);
  float m = s*(1.f/64.f);
  float d = v - m;
  float s2 = d*d; WREDUCE64(s2);
  float z = d * rsqrtf(s2*(1.f/64.f) + 1e-6f);
  out[(size_t)wave*64 + lane] = f2bf(fmaxf(z, 0.f));
}

// ---------------- generic M x 64 GEMM (K=64), f32 out ----------------
__global__ __launch_bounds__(256) void k_qgemm(const u16* A, const u16* Bt, float* out, int M){
  int wave = (blockIdx.x*blockDim.x + threadIdx.x) >> 6;
  int lane = threadIdx.x & 63;
  int row0 = wave*16; if(row0 >= M) return;
  int c = lane & 15, q = lane >> 4;
  s8v a0 = *reinterpret_cast<const s8v*>(A + (size_t)(row0+c)*64 + q*8);
  s8v a1 = *reinterpret_cast<const s8v*>(A + (size_t)(row0+c)*64 + 32 + q*8);
  #pragma unroll
  for(int ct=0; ct<4; ct++){
    s8v b0 = *reinterpret_cast<const s8v*>(Bt + (ct*16+c)*64 + q*8);
    s8v b1 = *reinterpret_cast<const s8v*>(Bt + (ct*16+c)*64 + 32 + q*8);
    f32x4 acc = {0.f,0.f,0.f,0.f};
    acc = MFMA(a0, b0, acc);
    acc = MFMA(a1, b1, acc);
    #pragma unroll
    for(int r=0;r<4;r++) out[(size_t)(row0+q*4+r)*64 + ct*16 + c] = acc[r];
  }
}

// ---------------- + f32 bias, f32 out (head layer 2 pre-LN) ----------------
__global__ __launch_bounds__(256) void k_gemm64_bias(const u16* A, const u16* Bt, const float* bias, float* out, int M){
  int wave = (blockIdx.x*blockDim.x + threadIdx.x) >> 6;
  int lane = threadIdx.x & 63;
  int row0 = wave*16; if(row0 >= M) return;
  int c = lane & 15, q = lane >> 4;
  s8v a0 = *reinterpret_cast<const s8v*>(A + (size_t)(row0+c)*64 + q*8);
  s8v a1 = *reinterpret_cast<const s8v*>(A + (size_t)(row0+c)*64 + 32 + q*8);
  #pragma unroll
  for(int ct=0; ct<4; ct++){
    s8v b0 = *reinterpret_cast<const s8v*>(Bt + (ct*16+c)*64 + q*8);
    s8v b1 = *reinterpret_cast<const s8v*>(Bt + (ct*16+c)*64 + 32 + q*8);
    f32x4 acc = {0.f,0.f,0.f,0.f};
    acc = MFMA(a0, b0, acc);
    acc = MFMA(a1, b1, acc);
    float bi = bias[ct*16+c];
    #pragma unroll
    for(int r=0;r<4;r++) out[(size_t)(row0+q*4+r)*64 + ct*16 + c] = acc[r] + bi;
  }
}

// ---------------- x += agg @ WoT; h2 = LN(x) fused ----------------
__global__ __launch_bounds__(256) void k_wo_ln(const u16* A, const u16* Bt, float* x, u16* hout, int M){
  int wave = (blockIdx.x*blockDim.x + threadIdx.x) >> 6;
  int lane = threadIdx.x & 63;
  int row0 = wave*16; if(row0 >= M) return;
  int c = lane & 15, q = lane >> 4;
  s8v a0 = *reinterpret_cast<const s8v*>(A + (size_t)(row0+c)*64 + q*8);
  s8v a1 = *reinterpret_cast<const s8v*>(A + (size_t)(row0+c)*64 + 32 + q*8);
  float nx[4][4];
  #pragma unroll
  for(int ct=0; ct<4; ct++){
    s8v b0 = *reinterpret_cast<const s8v*>(Bt + (ct*16+c)*64 + q*8);
    s8v b1 = *reinterpret_cast<const s8v*>(Bt + (ct*16+c)*64 + 32 + q*8);
    f32x4 acc = {0.f,0.f,0.f,0.f};
    acc = MFMA(a0, b0, acc);
    acc = MFMA(a1, b1, acc);
    #pragma unroll
    for(int r=0;r<4;r++){
      size_t idx = (size_t)(row0+q*4+r)*64 + ct*16 + c;
      float t = x[idx] + acc[r];
      x[idx] = t;
      nx[ct][r] = t;
    }
  }
  #pragma unroll
  for(int r=0;r<4;r++){
    float s = nx[0][r]+nx[1][r]+nx[2][r]+nx[3][r];
    QREDUCE16(s);
    float m = s*(1.f/64.f);
    float vv = 0.f;
    #pragma unroll
    for(int ct=0;ct<4;ct++){ float d = nx[ct][r]-m; vv += d*d; }
    QREDUCE16(vv);
    float rs = rsqrtf(vv*(1.f/64.f) + 1e-6f);
    #pragma unroll
    for(int ct=0;ct<4;ct++)
      hout[(size_t)(row0+q*4+r)*64 + ct*16 + c] = f2bf((nx[ct][r]-m)*rs);
  }
}

// ---------------- fused: k,v,hid MFMAs; rbf on-the-fly; logits via quad-shuffle ----------------
// vbf stored tile-swizzled: vbf[row0*64 + (r*4+ct)*64 + q*16 + c]  (128B-coalesced writes)
__global__ __launch_bounds__(256) void k_kvrad(const u16* hbf, const u16* ebf,
    const int* srcI, const int* dstI, const float* Qb, const float* r_arr,
    const u16* WkT, const u16* WvT, const u16* Wr1T, const float* Wr2,
    u16* vbf, float* exb, int E){
  int wave = (blockIdx.x*256 + threadIdx.x) >> 6;
  int lane = threadIdx.x & 63;
  int row0 = wave*16;
  int c = lane & 15, q = lane >> 4;
  int sr = srcI[row0 + c];
  s8v a0, a1;
  {
    s8v h0 = *reinterpret_cast<const s8v*>(hbf + (size_t)sr*64 + q*8);
    s8v h1 = *reinterpret_cast<const s8v*>(hbf + (size_t)sr*64 + 32 + q*8);
    s8v e0 = *reinterpret_cast<const s8v*>(ebf + (size_t)(row0+c)*64 + q*8);
    s8v e1 = *reinterpret_cast<const s8v*>(ebf + (size_t)(row0+c)*64 + 32 + q*8);
    #pragma unroll
    for(int j=0;j<8;j++){
      a0[j] = (short)f2bf(bf2f((u16)h0[j]) + bf2f((u16)e0[j]));
      a1[j] = (short)f2bf(bf2f((u16)h1[j]) + bf2f((u16)e1[j]));
    }
  }
  // rbf fragments on the fly from r (saves 32MB read per dispatch)
  float re = r_arr[row0 + c];
  s8v r0, r1;
  #pragma unroll
  for(int j=0;j<8;j++){
    float d0 = re - (10.f/63.f)*(float)(q*8+j);
    float d1 = re - (10.f/63.f)*(float)(32+q*8+j);
    r0[j] = (short)f2bf(__expf(-81.92f*d0*d0));
    r1[j] = (short)f2bf(__expf(-81.92f*d1*d1));
  }
  int dr[4];
  #pragma unroll
  for(int r=0;r<4;r++) dr[r] = dstI[row0 + q*4 + r];
  const float4* wr2v = reinterpret_cast<const float4*>(Wr2);
  float comb[4][4];
  #pragma unroll
  for(int h=0;h<4;h++)
    #pragma unroll
    for(int r=0;r<4;r++) comb[h][r] = 0.f;
  #pragma unroll
  for(int ct=0; ct<4; ct++){
    s8v bk0 = *reinterpret_cast<const s8v*>(WkT + (ct*16+c)*64 + q*8);
    s8v bk1 = *reinterpret_cast<const s8v*>(WkT + (ct*16+c)*64 + 32 + q*8);
    s8v bv0 = *reinterpret_cast<const s8v*>(WvT + (ct*16+c)*64 + q*8);
    s8v bv1 = *reinterpret_cast<const s8v*>(WvT + (ct*16+c)*64 + 32 + q*8);
    s8v bw0 = *reinterpret_cast<const s8v*>(Wr1T + (ct*16+c)*64 + q*8);
    s8v bw1 = *reinterpret_cast<const s8v*>(Wr1T + (ct*16+c)*64 + 32 + q*8);
    f32x4 kacc = {0.f,0.f,0.f,0.f};
    kacc = MFMA(a0, bk0, kacc); kacc = MFMA(a1, bk1, kacc);
    f32x4 vacc = {0.f,0.f,0.f,0.f};
    vacc = MFMA(a0, bv0, vacc); vacc = MFMA(a1, bv1, vacc);
    f32x4 hacc = {0.f,0.f,0.f,0.f};
    hacc = MFMA(r0, bw0, hacc); hacc = MFMA(r1, bw1, hacc);
    float4 w2 = wr2v[ct*16 + c];
    #pragma unroll
    for(int r=0;r<4;r++){
      // tile-swizzled, 128B-coalesced store: offset = (r*4+ct)*64 + lane
      vbf[(size_t)row0*64 + (r*4+ct)*64 + q*16 + c] = f2bf(vacc[r]);
      comb[ct][r] += 0.25f * kacc[r] * Qb[(size_t)dr[r]*64 + ct*16 + c];
      float y = hacc[r];
      float sv = y / (1.f + __expf(-y));
      comb[0][r] += sv * w2.x;
      comb[1][r] += sv * w2.y;
      comb[2][r] += sv * w2.z;
      comb[3][r] += sv * w2.w;
    }
  }
  #pragma unroll
  for(int m=1; m<16; m<<=1){
    #pragma unroll
    for(int h=0;h<4;h++)
      #pragma unroll
      for(int r=0;r<4;r++) comb[h][r] += __shfl_xor(comb[h][r], m);
  }
  int hh = c & 3, rr = c >> 2;
  float logit = comb[0][0];
  #pragma unroll
  for(int h=0;h<4;h++)
    #pragma unroll
    for(int r=0;r<4;r++)
      if(h || r) logit = (hh==h && rr==r) ? comb[h][r] : logit;
  int row = row0 + q*4 + rr;
  exb[(size_t)row0*4 + lane] = (r_arr[row] < 10.f) ? __expf(logit) : 0.f;
}

// ---------------- CSR build ----------------
__global__ __launch_bounds__(256) void k_count(const int* dstI, int* deg, int E){
  int tid = blockIdx.x*256 + threadIdx.x;
  if(tid < E) atomicAdd(&deg[dstI[tid]], 1);
}
__global__ __launch_bounds__(1024) void k_scan(const int* deg, int* rowptr, int* cursor, int N){
  __shared__ int wsum[17];
  int tid = threadIdx.x;
  int per = (N + 1023) >> 10;
  int base = tid * per;
  int s = 0;
  for(int i=0;i<per;i++){ int idx = base+i; if(idx < N) s += deg[idx]; }
  int lane = tid & 63, wid = tid >> 6;
  int inc = s;
  for(int d=1; d<64; d<<=1){
    int t = __shfl_up(inc, d);
    if(lane >= d) inc += t;
  }
  if(lane == 63) wsum[wid+1] = inc;
  if(tid == 0) wsum[0] = 0;
  __syncthreads();
  if(tid == 0){ for(int w=1; w<=16; w++) wsum[w] += wsum[w-1]; }
  __syncthreads();
  int run = inc - s + wsum[wid];
  for(int i=0;i<per;i++){
    int idx = base + i;
    if(idx < N){ rowptr[idx] = run; cursor[idx] = run; run += deg[idx]; }
  }
  if(tid == 1023) rowptr[N] = wsum[16];
}
__global__ __launch_bounds__(256) void k_scatter(const int* dstI, int* cursor, int* csr, int E){
  int tid = blockIdx.x*256 + threadIdx.x;
  if(tid < E){
    int p = atomicAdd(&cursor[dstI[tid]], 1);
    csr[p] = tid;
  }
}

// ---------------- softmax-denominator + aggregation, 4-edge-parallel, swizzled v reads ----------------
__global__ __launch_bounds__(256) void k_agg(const int* rowptr, const int* csr, const float* exb, const u16* vbf, u16* aggbf, int N){
  int wave = (blockIdx.x*256 + threadIdx.x) >> 6;
  int lane = threadIdx.x & 63;
  if(wave >= N) return;
  int s0 = rowptr[wave], s1 = rowptr[wave+1];
  float s[4] = {0.f,0.f,0.f,0.f};
  for(int p = s0 + lane; p < s1; p += 64){
    int e = csr[p];
    float4 ev = *reinterpret_cast<const float4*>(exb + (size_t)e*4);
    s[0] += ev.x; s[1] += ev.y; s[2] += ev.z; s[3] += ev.w;
  }
  #pragma unroll
  for(int i=0;i<4;i++){ WREDUCE64(s[i]); }
  int ep = lane >> 4, cc = lane & 15;
  int hh = cc >> 2;
  // swizzle constants for cols 4cc..4cc+3: ct = cc>>2, c = (cc&3)*4
  int swz = (hh)*64 + (cc&3)*4;   // (ct)*64 + cbase; add (r4*4)*64 + q2*16 per edge
  float inv = 1.f/(s[hh] + 1e-9f);
  float a0=0.f, a1=0.f, a2=0.f, a3=0.f;
  for(int p = s0 + ep; p < s1; p += 4){
    int e = csr[p];
    int t = e & 15;
    size_t base = (size_t)(e & ~15)*64 + (size_t)((t&3)*256) + (size_t)((t>>2)*16) + swz;
    ushort4 v4 = *reinterpret_cast<const ushort4*>(vbf + base);
    float ex = exb[(size_t)e*4 + hh];
    a0 += ex*bf2f(v4.x); a1 += ex*bf2f(v4.y); a2 += ex*bf2f(v4.z); a3 += ex*bf2f(v4.w);
  }
  a0 += __shfl_xor(a0,16); a0 += __shfl_xor(a0,32);
  a1 += __shfl_xor(a1,16); a1 += __shfl_xor(a1,32);
  a2 += __shfl_xor(a2,16); a2 += __shfl_xor(a2,32);
  a3 += __shfl_xor(a3,16); a3 += __shfl_xor(a3,32);
  if(ep == 0){
    ushort4 o;
    o.x = f2bf(a0*inv); o.y = f2bf(a1*inv); o.z = f2bf(a2*inv); o.w = f2bf(a3*inv);
    *reinterpret_cast<ushort4*>(aggbf + (size_t)wave*64 + cc*4) = o;
  }
}

// ---------------- FFN ----------------
__global__ __launch_bounds__(256) void k_ffn1(const u16* A, const u16* Bt, u16* tout, int M){
  int wave = (blockIdx.x*blockDim.x + threadIdx.x) >> 6;
  int lane = threadIdx.x & 63;
  int row0 = wave*16; if(row0 >= M) return;
  int c = lane & 15, q = lane >> 4;
  s8v a0 = *reinterpret_cast<const s8v*>(A + (size_t)(row0+c)*64 + q*8);
  s8v a1 = *reinterpret_cast<const s8v*>(A + (size_t)(row0+c)*64 + 32 + q*8);
  #pragma unroll
  for(int ct=0; ct<16; ct++){
    s8v b0 = *reinterpret_cast<const s8v*>(Bt + (ct*16+c)*64 + q*8);
    s8v b1 = *reinterpret_cast<const s8v*>(Bt + (ct*16+c)*64 + 32 + q*8);
    f32x4 acc = {0.f,0.f,0.f,0.f};
    acc = MFMA(a0, b0, acc);
    acc = MFMA(a1, b1, acc);
    #pragma unroll
    for(int r=0;r<4;r++){
      float y = acc[r];
      tout[(size_t)(row0+q*4+r)*256 + ct*16 + c] = f2bf(y / (1.f + __expf(-y)));
    }
  }
}
// x += T @ W2T; hbf = LN(x); optional xbf = bf16(x)
__global__ __launch_bounds__(256) void k_ffn2_ln(const u16* T, const u16* Bt, float* x, u16* hout, u16* xbf, int writex, int M){
  int wave = (blockIdx.x*blockDim.x + threadIdx.x) >> 6;
  int lane = threadIdx.x & 63;
  int row0 = wave*16; if(row0 >= M) return;
  int c = lane & 15, q = lane >> 4;
  s8v a[8];
  #pragma unroll
  for(int kc=0; kc<8; kc++)
    a[kc] = *reinterpret_cast<const s8v*>(T + (size_t)(row0+c)*256 + kc*32 + q*8);
  float nx[4][4];
  #pragma unroll
  for(int ct=0; ct<4; ct++){
    f32x4 acc = {0.f,0.f,0.f,0.f};
    #pragma unroll
    for(int kc=0; kc<8; kc++){
      s8v b = *reinterpret_cast<const s8v*>(Bt + (ct*16+c)*256 + kc*32 + q*8);
      acc = MFMA(a[kc], b, acc);
    }
    #pragma unroll
    for(int r=0;r<4;r++){
      size_t idx = (size_t)(row0+q*4+r)*64 + ct*16 + c;
      float t = x[idx] + acc[r];
      x[idx] = t;
      nx[ct][r] = t;
      if(writex) xbf[idx] = f2bf(t);
    }
  }
  #pragma unroll
  for(int r=0;r<4;r++){
    float s = nx[0][r]+nx[1][r]+nx[2][r]+nx[3][r];
    QREDUCE16(s);
    float m = s*(1.f/64.f);
    float vv = 0.f;
    #pragma unroll
    for(int ct=0;ct<4;ct++){ float d = nx[ct][r]-m; vv += d*d; }
    QREDUCE16(vv);
    float rs = rsqrtf(vv*(1.f/64.f) + 1e-6f);
    #pragma unroll
    for(int ct=0;ct<4;ct++)
      hout[(size_t)(row0+q*4+r)*64 + ct*16 + c] = f2bf((nx[ct][r]-m)*rs);
  }
}

// ---------------- feat = x @ W_feat (Nc=512, raw f32) ----------------
__global__ __launch_bounds__(256) void k_feat(const u16* A, const u16* Bt, float* out, int M){
  int wave = (blockIdx.x*blockDim.x + threadIdx.x) >> 6;
  int lane = threadIdx.x & 63;
  int row0 = wave*16; if(row0 >= M) return;
  int c = lane & 15, q = lane >> 4;
  s8v a0 = *reinterpret_cast<const s8v*>(A + (size_t)(row0+c)*64 + q*8);
  s8v a1 = *reinterpret_cast<const s8v*>(A + (size_t)(row0+c)*64 + 32 + q*8);
  #pragma unroll
  for(int ct=0; ct<32; ct++){
    s8v b0 = *reinterpret_cast<const s8v*>(Bt + (ct*16+c)*64 + q*8);
    s8v b1 = *reinterpret_cast<const s8v*>(Bt + (ct*16+c)*64 + 32 + q*8);
    f32x4 acc = {0.f,0.f,0.f,0.f};
    acc = MFMA(a0, b0, acc);
    acc = MFMA(a1, b1, acc);
    #pragma unroll
    for(int r=0;r<4;r++) out[(size_t)(row0+q*4+r)*512 + ct*16 + c] = acc[r];
  }
}

// ---------------- LN over 512 ----------------
__global__ __launch_bounds__(256) void k_ln512(const float* fr, u16* out, int N){
  int wave = (blockIdx.x*blockDim.x + threadIdx.x) >> 6;
  int lane = threadIdx.x & 63;
  if(wave >= N) return;
  const float* row = fr + (size_t)wave*512 + lane*8;
  float v[8];
  float4 u0 = *reinterpret_cast<const float4*>(row);
  float4 u1 = *reinterpret_cast<const float4*>(row+4);
  v[0]=u0.x; v[1]=u0.y; v[2]=u0.z; v[3]=u0.w;
  v[4]=u1.x; v[5]=u1.y; v[6]=u1.z; v[7]=u1.w;
  float s = 0.f;
  #pragma unroll
  for(int i=0;i<8;i++) s += v[i];
  WREDUCE64(s);
  float m = s*(1.f/512.f);
  float vv = 0.f;
  #pragma unroll
  for(int i=0;i<8;i++){ float d = v[i]-m; vv += d*d; }
  WREDUCE64(vv);
  float rs = rsqrtf(vv*(1.f/512.f) + 1e-6f);
  s8v o;
  #pragma unroll
  for(int i=0;i<8;i++) o[i] = (short)f2bf((v[i]-m)*rs);
  *reinterpret_cast<s8v*>(out + (size_t)wave*512 + lane*8) = o;
}

// ---------------- head1 GEMM (K=512) + f32 bias, raw f32 out ----------------
__global__ __launch_bounds__(256) void k_head1_gemm(const u16* A, const u16* Bt, const float* hb, float* out, int M){
  int wave = (blockIdx.x*blockDim.x + threadIdx.x) >> 6;
  int lane = threadIdx.x & 63;
  int row0 = wave*16; if(row0 >= M) return;
  int c = lane & 15, q = lane >> 4;
  s8v a[16];
  #pragma unroll
  for(int kc=0; kc<16; kc++)
    a[kc] = *reinterpret_cast<const s8v*>(A + (size_t)(row0+c)*512 + kc*32 + q*8);
  #pragma unroll
  for(int ct=0; ct<4; ct++){
    f32x4 acc = {0.f,0.f,0.f,0.f};
    #pragma unroll
    for(int kc=0; kc<16; kc++){
      s8v b = *reinterpret_cast<const s8v*>(Bt + (size_t)(ct*16+c)*512 + kc*32 + q*8);
      acc = MFMA(a[kc], b, acc);
    }
    float bi = hb[ct*16+c];
    #pragma unroll
    for(int r=0;r<4;r++) out[(size_t)(row0+q*4+r)*64 + ct*16 + c] = acc[r] + bi;
  }
}

// ---------------- per-node: LN(y2)+relu, dot hW3 (f32), pooled atomicAdd ----------------
__global__ __launch_bounds__(256) void k_energy(const float* y2, const float* hW3, const float* hb3,
    const int* batch, float* pooled, int N){
  int wave = (blockIdx.x*blockDim.x + threadIdx.x) >> 6;
  int lane = threadIdx.x & 63;
  if(wave >= N) return;
  float v = y2[(size_t)wave*64 + lane];
  float s = v; WREDUCE64(s);
  float m = s*(1.f/64.f);
  float d = v - m;
  float s2 = d*d; WREDUCE64(s2);
  float z = fmaxf(d * rsqrtf(s2*(1.f/64.f) + 1e-6f), 0.f);
  float e_ = z * hW3[lane];
  WREDUCE64(e_);
  if(lane == 0) atomicAdd(&pooled[batch[wave]], e_ + hb3[0]);
}

// ---------------- output f32 ----------------
__global__ __launch_bounds__(256) void k_out(const float* pooled, float* out, int G){
  int tid = blockIdx.x*256 + threadIdx.x;
  if(tid < G) out[tid] = pooled[tid] * 0.11785113019775793f; // 1/sqrt(72)
}

extern "C" void kernel_launch(void* const* d_in, const int* in_sizes, int n_in,
                              void* d_out, int out_size, void* d_ws, size_t ws_size,
                              hipStream_t stream){
  const int*   edge_src  = (const int*)d_in[1];
  const int*   edge_dst  = (const int*)d_in[2];
  const float* edge_vec  = (const float*)d_in[3];
  const int*   batch     = (const int*)d_in[4];
  const int*   node_atom = (const int*)d_in[5];
  const float* ele    = (const float*)d_in[6];
  const float* W_embed= (const float*)d_in[7];
  const float* W_edge = (const float*)d_in[8];
  const float* Wq = (const float*)d_in[9];
  const float* Wk = (const float*)d_in[10];
  const float* Wv = (const float*)d_in[11];
  const float* Wr1= (const float*)d_in[12];
  const float* Wr2= (const float*)d_in[13];
  const float* Wo = (const float*)d_in[14];
  const float* W1 = (const float*)d_in[15];
  const float* W2 = (const float*)d_in[16];
  const float* W_feat=(const float*)d_in[17];
  const float* hW1= (const float*)d_in[18];
  const float* hb1= (const float*)d_in[19];
  const float* hW2= (const float*)d_in[20];
  const float* hb2= (const float*)d_in[21];
  const float* hW3= (const float*)d_in[22];
  const float* hb3= (const float*)d_in[23];
  (void)n_in; (void)ws_size;

  const int E = in_sizes[1];
  const int N = in_sizes[4];
  const int G = out_size;

  // ---- workspace layout: peak ~107 MB ----
  char* base = (char*)d_ws;
  size_t off = 0;
  #define ALLOC(ty, name, count) ty* name = (ty*)(base + off); off = (off + (size_t)(count)*sizeof(ty) + 255) & ~(size_t)255;
  ALLOC(float, r_arr, E)
  ALLOC(u16,   shb,   (size_t)E*16)
  ALLOC(u16,   ebf,   (size_t)E*64)
  ALLOC(u16,   vbf,   (size_t)E*64)
  ALLOC(float, exb,   (size_t)E*4)
  ALLOC(float, radialb,(size_t)E*4)   // loop-unused; alias region for hh1
  ALLOC(u16,   hbf,   (size_t)N*64)
  ALLOC(u16,   h2bf,  (size_t)N*64)
  ALLOC(u16,   aggbf, (size_t)N*64)
  ALLOC(u16,   xbf,   (size_t)N*64)
  ALLOC(float, Qb,    (size_t)N*64)
  ALLOC(float, xb,    (size_t)N*64)
  ALLOC(u16,   tbf,   (size_t)N*256)
  ALLOC(int,   deg,   N)
  ALLOC(int,   rowptr,N+1)
  ALLOC(int,   cursor,N)
  ALLOC(int,   csr,   E)
  ALLOC(float, pooled,G)
  ALLOC(u16, ele_bf, 120*32)
  ALLOC(u16, WembT, 64*32)
  ALLOC(u16, WedgeT,64*160)
  ALLOC(u16, WqT,  6*64*64)   // WqT..WoT contiguous
  ALLOC(u16, WkT,  6*64*64)
  ALLOC(u16, WvT,  6*64*64)
  ALLOC(u16, Wr1T, 6*64*64)
  ALLOC(u16, WoT,  6*64*64)
  ALLOC(u16, W1T,  6*256*64)
  ALLOC(u16, W2T,  6*64*256)
  ALLOC(u16, WfT,  512*64)
  ALLOC(u16, hW1T, 64*512)
  ALLOC(u16, hW2T, 64*64)
  #undef ALLOC
  // tail-phase aliases into loop-dead regions:
  float* featraw = (float*)vbf;    // 32 MB
  u16*   featbf  = ebf;            // 16 MB <= 32 MB
  float* y1      = exb;            // 4 MB
  u16*   hh1     = (u16*)radialb;  // 2 MB <= 4 MB
  float* y2      = Qb;             // 4 MB

  auto cdiv = [](int a, int b){ return (a + b - 1)/b; };

  k_convert<<<cdiv(120*32,256),256,0,stream>>>(ele, ele_bf, 120*32);
  k_transpose<<<cdiv(64*32,256),256,0,stream>>>(W_embed, WembT, 1, 32, 64, 32);
  k_transpose<<<cdiv(64*160,256),256,0,stream>>>(W_edge, WedgeT, 1, 137, 64, 160);
  k_transpose5<<<cdiv(5*6*64*64,256),256,0,stream>>>(Wq, Wk, Wv, Wr1, Wo, WqT);
  k_transpose<<<cdiv(6*256*64,256),256,0,stream>>>(W1, W1T, 6, 64, 256, 64);
  k_transpose<<<cdiv(6*64*256,256),256,0,stream>>>(W2, W2T, 6, 256, 64, 256);
  k_transpose<<<cdiv(512*64,256),256,0,stream>>>(W_feat, WfT, 1, 64, 512, 64);
  k_transpose<<<cdiv(64*512,256),256,0,stream>>>(hW1, hW1T, 1, 512, 64, 512);
  k_transpose<<<cdiv(64*64,256),256,0,stream>>>(hW2, hW2T, 1, 64, 64, 64);

  hipMemsetAsync(deg, 0, (size_t)N*sizeof(int), stream);
  hipMemsetAsync(pooled, 0, (size_t)G*sizeof(float), stream);

  k_edge_geom<<<cdiv(E,256),256,0,stream>>>(edge_vec, r_arr, shb, E);
  k_embed<<<N/64, 256, 0, stream>>>(node_atom, ele_bf, WembT, xb, N);
  k_edge_embed<<<E/64, 256, 0, stream>>>(edge_src, edge_dst, node_atom, ele_bf, shb, r_arr, WedgeT, ebf, E);
  k_count<<<cdiv(E,256),256,0,stream>>>(edge_dst, deg, E);
  k_scan<<<1,1024,0,stream>>>(deg, rowptr, cursor, N);
  k_scatter<<<cdiv(E,256),256,0,stream>>>(edge_dst, cursor, csr, E);

  k_ln64<<<cdiv(N,4),256,0,stream>>>(xb, hbf, N);   // layer-0 input LN
  for(int l=0; l<6; l++){
    k_qgemm<<<N/64,256,0,stream>>>(hbf, WqT + l*4096, Qb, N);
    k_kvrad<<<E/64,256,0,stream>>>(hbf, ebf, edge_src, edge_dst, Qb, r_arr,
                                   WkT + l*4096, WvT + l*4096, Wr1T + l*4096, Wr2 + l*256,
                                   vbf, exb, E);
    k_agg<<<cdiv(N,4),256,0,stream>>>(rowptr, csr, exb, vbf, aggbf, N);
    k_wo_ln<<<N/64,256,0,stream>>>(aggbf, WoT + l*4096, xb, h2bf, N);
    k_ffn1<<<N/64,256,0,stream>>>(h2bf, W1T + l*16384, tbf, N);
    k_ffn2_ln<<<N/64,256,0,stream>>>(tbf, W2T + l*16384, xb, hbf, xbf, (l==5)?1:0, N);
  }

  k_feat<<<N/64,256,0,stream>>>(xbf, WfT, featraw, N);
  k_ln512<<<cdiv(N,4),256,0,stream>>>(featraw, featbf, N);
  k_head1_gemm<<<N/64,256,0,stream>>>(featbf, hW1T, hb1, y1, N);
  k_lnrelu64<<<cdiv(N,4),256,0,stream>>>(y1, hh1, N);
  k_gemm64_bias<<<N/64,256,0,stream>>>(hh1, hW2T, hb2, y2, N);
  k_energy<<<cdiv(N,4),256,0,stream>>>(y2, hW3, hb3, batch, pooled, N);
  k_out<<<cdiv(G,256),256,0,stream>>>(pooled, (float*)d_out, G);
}

// Round 11
// 914.401 us; speedup vs baseline: 6.5215x; 1.1116x over previous
//
#include <hip/hip_runtime.h>

typedef short s8v __attribute__((ext_vector_type(8)));
typedef float f32x4 __attribute__((ext_vector_type(4)));
typedef unsigned short u16;

__device__ __forceinline__ float bf2f(u16 h){
  union { unsigned u; float f; } v; v.u = ((unsigned)h) << 16; return v.f;
}
__device__ __forceinline__ u16 f2bf(float f){
  union { float f; unsigned u; } v; v.f = f;
  unsigned u = v.u;
  return (u16)((u + 0x7fffu + ((u >> 16) & 1u)) >> 16);
}
#define MFMA(a,b,c) __builtin_amdgcn_mfma_f32_16x16x32_bf16((a),(b),(c),0,0,0)

#define WREDUCE64(s) { s += __shfl_xor(s,1); s += __shfl_xor(s,2); s += __shfl_xor(s,4); \
                       s += __shfl_xor(s,8); s += __shfl_xor(s,16); s += __shfl_xor(s,32); }
#define QREDUCE16(s) { s += __shfl_xor(s,1); s += __shfl_xor(s,2); s += __shfl_xor(s,4); s += __shfl_xor(s,8); }

// ---------------- transpose f32 -> bf16 (zero row padding): dst[b][c][rp] = src[b][rp][c] ----------------
__global__ __launch_bounds__(256) void k_transpose(const float* src, u16* dst, int B, int R, int C, int Rpad){
  int idx = blockIdx.x*256 + threadIdx.x;
  int total = B*C*Rpad;
  if(idx >= total) return;
  int b = idx / (C*Rpad);
  int rem = idx - b*C*Rpad;
  int cI = rem / Rpad;
  int rI = rem - cI*Rpad;
  dst[idx] = (rI < R) ? f2bf(src[(size_t)b*R*C + (size_t)rI*C + cI]) : (u16)0;
}

// 5 batched 6x64x64 transposes in one launch (dst buffers contiguous)
__global__ __launch_bounds__(256) void k_transpose5(const float* W0, const float* W1, const float* W2,
    const float* W3, const float* W4, u16* dst){
  int idx = blockIdx.x*256 + threadIdx.x; // 5*6*64*64
  int which = idx / (6*64*64);
  int rem = idx - which*(6*64*64);
  const float* src = (which==0)?W0:(which==1)?W1:(which==2)?W2:(which==3)?W3:W4;
  int b = rem >> 12;
  int r2 = rem & 4095;
  int cI = r2 >> 6, rI = r2 & 63;
  dst[idx] = f2bf(src[b*4096 + rI*64 + cI]);
}

// ---------------- f32 -> bf16 elementwise convert ----------------
__global__ __launch_bounds__(256) void k_convert(const float* src, u16* dst, int n){
  int idx = blockIdx.x*256 + threadIdx.x;
  if(idx < n) dst[idx] = f2bf(src[idx]);
}

// ---------------- e = [nf_src, nf_dst, sh(inline), rbf(inline)] @ W_edge (K 137->160); writes r_arr ----------------
__global__ __launch_bounds__(256) void k_edge_embed(const int* srcI, const int* dstI, const int* atom,
    const u16* ele, const float* evec, const u16* Bt, u16* ebf, float* r_arr, int E){
  int wave = (blockIdx.x*blockDim.x + threadIdx.x) >> 6;
  int lane = threadIdx.x & 63;
  int row0 = wave*16; if(row0 >= E) return;
  int c = lane & 15, q = lane >> 4;
  int erow = row0 + c;
  float vx = evec[(size_t)erow*3+0];
  float vy = evec[(size_t)erow*3+1];
  float vz = evec[(size_t)erow*3+2];
  float r = sqrtf(vx*vx + vy*vy + vz*vz);
  if(q == 0) r_arr[erow] = r;
  float inv = 1.f/(r + 1e-12f);
  // u = edge_vec[:, [1,2,0]] / r -> x=v1, y=v2, z=v0
  float x = vy*inv, y = vz*inv, z = vx*inv;
  const float s3 = 1.7320508075688772f, s15 = 3.872983346207417f;
  const float s5h = 1.118033988749895f, s15h = 1.9364916731037085f;
  float sh[9];
  sh[0] = 1.f; sh[1] = s3*x; sh[2] = s3*y; sh[3] = s3*z;
  sh[4] = s15*x*y; sh[5] = s15*y*z; sh[6] = s5h*(3.f*z*z - 1.f);
  sh[7] = s15*x*z; sh[8] = s15h*(x*x - y*y);
  s8v a[5];
  a[0] = *reinterpret_cast<const s8v*>(ele + (size_t)atom[srcI[erow]]*32 + q*8);
  a[1] = *reinterpret_cast<const s8v*>(ele + (size_t)atom[dstI[erow]]*32 + q*8);
  // kc=2: cols 64..95 (sh for col<73, else rbf)
  #pragma unroll
  for(int j=0;j<8;j++){
    int col = 64 + q*8 + j;
    u16 v;
    if(q == 0)            v = f2bf(sh[j]);       // constant index
    else if(col < 73)     v = f2bf(sh[8]);       // only q==1, j==0
    else { float d = r - (10.f/63.f)*(float)(col-73); v = f2bf(__expf(-81.92f*d*d)); }
    a[2][j] = (short)v;
  }
  // kc=3: cols 96..127 -> rbf(23+q*8+j)
  #pragma unroll
  for(int j=0;j<8;j++){
    float d = r - (10.f/63.f)*(float)(23 + q*8 + j);
    a[3][j] = (short)f2bf(__expf(-81.92f*d*d));
  }
  // kc=4: cols 128..159 -> rbf while col<137 else 0
  #pragma unroll
  for(int j=0;j<8;j++){
    int col = 128 + q*8 + j;
    u16 v = 0;
    if(col < 137){ float d = r - (10.f/63.f)*(float)(col-73); v = f2bf(__expf(-81.92f*d*d)); }
    a[4][j] = (short)v;
  }
  #pragma unroll
  for(int ct=0; ct<4; ct++){
    f32x4 acc = {0.f,0.f,0.f,0.f};
    #pragma unroll
    for(int kc=0; kc<5; kc++){
      s8v b = *reinterpret_cast<const s8v*>(Bt + (ct*16+c)*160 + kc*32 + q*8);
      acc = MFMA(a[kc], b, acc);
    }
    #pragma unroll
    for(int r_=0;r_<4;r_++) ebf[(size_t)(row0+q*4+r_)*64 + ct*16 + c] = f2bf(acc[r_]);
  }
}

// ---------------- pre: x = ele[atom]@Wemb; h0 = LN(x); Q0 = h0@Wq0 (Qt layout) ----------------
__global__ __launch_bounds__(256) void k_pre(const int* atom, const u16* ele, const u16* WembT,
    const u16* WqT0, float* xb, u16* hbf, float* Qt, int M){
  __shared__ u16 ldsH[4][16*72];
  int widL = threadIdx.x >> 6;
  int wave = (blockIdx.x*256 + threadIdx.x) >> 6;
  int lane = threadIdx.x & 63;
  int row0 = wave*16; if(row0 >= M) return;
  int c = lane & 15, q = lane >> 4;
  u16* LH = ldsH[widL];
  int at = atom[row0 + c];
  s8v a = *reinterpret_cast<const s8v*>(ele + (size_t)at*32 + q*8);
  float nx[4][4];
  #pragma unroll
  for(int ct=0; ct<4; ct++){
    s8v b = *reinterpret_cast<const s8v*>(WembT + (ct*16+c)*32 + q*8);
    f32x4 acc = {0.f,0.f,0.f,0.f};
    acc = MFMA(a, b, acc);
    #pragma unroll
    for(int r=0;r<4;r++){
      xb[(size_t)(row0+q*4+r)*64 + ct*16 + c] = acc[r];
      nx[ct][r] = acc[r];
    }
  }
  #pragma unroll
  for(int r=0;r<4;r++){
    float s = nx[0][r]+nx[1][r]+nx[2][r]+nx[3][r];
    QREDUCE16(s);
    float m = s*(1.f/64.f);
    float vv = 0.f;
    #pragma unroll
    for(int ct=0;ct<4;ct++){ float d = nx[ct][r]-m; vv += d*d; }
    QREDUCE16(vv);
    float rs = rsqrtf(vv*(1.f/64.f) + 1e-6f);
    #pragma unroll
    for(int ct=0;ct<4;ct++){
      u16 hb = f2bf((nx[ct][r]-m)*rs);
      hbf[(size_t)(row0+q*4+r)*64 + ct*16 + c] = hb;
      LH[(q*4+r)*72 + ct*16 + c] = hb;
    }
  }
  s8v h0 = *reinterpret_cast<const s8v*>(LH + c*72 + q*8);
  s8v h1 = *reinterpret_cast<const s8v*>(LH + c*72 + 32 + q*8);
  #pragma unroll
  for(int ct=0; ct<4; ct++){
    s8v b0 = *reinterpret_cast<const s8v*>(WqT0 + (ct*16+c)*64 + q*8);
    s8v b1 = *reinterpret_cast<const s8v*>(WqT0 + (ct*16+c)*64 + 32 + q*8);
    f32x4 acc = {0.f,0.f,0.f,0.f};
    acc = MFMA(h0, b0, acc);
    acc = MFMA(h1, b1, acc);
    #pragma unroll
    for(int r=0;r<4;r++) Qt[(size_t)(row0+q*4+r)*64 + c*4 + ct] = acc[r];
  }
}

// ---------------- fused: k,v,hid MFMAs; rbf on-the-fly; logits via quad-shuffle ----------------
// vbf tile-swizzled: vbf[row0*64 + (r*4+ct)*64 + q*16 + c];  Qt[node*64 + c*4 + ct]
__global__ __launch_bounds__(256) void k_kvrad(const u16* hbf, const u16* ebf,
    const int* srcI, const int* dstI, const float* Qt, const float* r_arr,
    const u16* WkT, const u16* WvT, const u16* Wr1T, const float* Wr2,
    u16* vbf, float* exb, int E){
  int wave = (blockIdx.x*256 + threadIdx.x) >> 6;
  int lane = threadIdx.x & 63;
  int row0 = wave*16;
  int c = lane & 15, q = lane >> 4;
  int sr = srcI[row0 + c];
  s8v a0, a1;
  {
    s8v h0 = *reinterpret_cast<const s8v*>(hbf + (size_t)sr*64 + q*8);
    s8v h1 = *reinterpret_cast<const s8v*>(hbf + (size_t)sr*64 + 32 + q*8);
    s8v e0 = *reinterpret_cast<const s8v*>(ebf + (size_t)(row0+c)*64 + q*8);
    s8v e1 = *reinterpret_cast<const s8v*>(ebf + (size_t)(row0+c)*64 + 32 + q*8);
    #pragma unroll
    for(int j=0;j<8;j++){
      a0[j] = (short)f2bf(bf2f((u16)h0[j]) + bf2f((u16)e0[j]));
      a1[j] = (short)f2bf(bf2f((u16)h1[j]) + bf2f((u16)e1[j]));
    }
  }
  float re = r_arr[row0 + c];
  s8v r0, r1;
  #pragma unroll
  for(int j=0;j<8;j++){
    float d0 = re - (10.f/63.f)*(float)(q*8+j);
    float d1 = re - (10.f/63.f)*(float)(32+q*8+j);
    r0[j] = (short)f2bf(__expf(-81.92f*d0*d0));
    r1[j] = (short)f2bf(__expf(-81.92f*d1*d1));
  }
  const float4* QtV = reinterpret_cast<const float4*>(Qt);
  float4 qv[4];
  #pragma unroll
  for(int r=0;r<4;r++){
    int dr = dstI[row0 + q*4 + r];
    qv[r] = QtV[(size_t)dr*16 + c];
  }
  const float4* wr2v = reinterpret_cast<const float4*>(Wr2);
  float comb[4][4];
  #pragma unroll
  for(int h=0;h<4;h++)
    #pragma unroll
    for(int r=0;r<4;r++) comb[h][r] = 0.f;
  #pragma unroll
  for(int ct=0; ct<4; ct++){
    s8v bk0 = *reinterpret_cast<const s8v*>(WkT + (ct*16+c)*64 + q*8);
    s8v bk1 = *reinterpret_cast<const s8v*>(WkT + (ct*16+c)*64 + 32 + q*8);
    s8v bv0 = *reinterpret_cast<const s8v*>(WvT + (ct*16+c)*64 + q*8);
    s8v bv1 = *reinterpret_cast<const s8v*>(WvT + (ct*16+c)*64 + 32 + q*8);
    s8v bw0 = *reinterpret_cast<const s8v*>(Wr1T + (ct*16+c)*64 + q*8);
    s8v bw1 = *reinterpret_cast<const s8v*>(Wr1T + (ct*16+c)*64 + 32 + q*8);
    f32x4 kacc = {0.f,0.f,0.f,0.f};
    kacc = MFMA(a0, bk0, kacc); kacc = MFMA(a1, bk1, kacc);
    f32x4 vacc = {0.f,0.f,0.f,0.f};
    vacc = MFMA(a0, bv0, vacc); vacc = MFMA(a1, bv1, vacc);
    f32x4 hacc = {0.f,0.f,0.f,0.f};
    hacc = MFMA(r0, bw0, hacc); hacc = MFMA(r1, bw1, hacc);
    float4 w2 = wr2v[ct*16 + c];
    #pragma unroll
    for(int r=0;r<4;r++){
      vbf[(size_t)row0*64 + (r*4+ct)*64 + q*16 + c] = f2bf(vacc[r]);
      float qc = (ct==0)?qv[r].x:(ct==1)?qv[r].y:(ct==2)?qv[r].z:qv[r].w;
      comb[ct][r] += 0.25f * kacc[r] * qc;
      float y = hacc[r];
      float sv = y / (1.f + __expf(-y));
      comb[0][r] += sv * w2.x;
      comb[1][r] += sv * w2.y;
      comb[2][r] += sv * w2.z;
      comb[3][r] += sv * w2.w;
    }
  }
  #pragma unroll
  for(int m=1; m<16; m<<=1){
    #pragma unroll
    for(int h=0;h<4;h++)
      #pragma unroll
      for(int r=0;r<4;r++) comb[h][r] += __shfl_xor(comb[h][r], m);
  }
  int hh = c & 3, rr = c >> 2;
  float logit = comb[0][0];
  #pragma unroll
  for(int h=0;h<4;h++)
    #pragma unroll
    for(int r=0;r<4;r++)
      if(h || r) logit = (hh==h && rr==r) ? comb[h][r] : logit;
  int row = row0 + q*4 + rr;
  exb[(size_t)row0*4 + lane] = (r_arr[row] < 10.f) ? __expf(logit) : 0.f;
}

// ---------------- CSR build ----------------
__global__ __launch_bounds__(256) void k_count(const int* dstI, int* deg, int E){
  int tid = blockIdx.x*256 + threadIdx.x;
  if(tid < E) atomicAdd(&deg[dstI[tid]], 1);
}
__global__ __launch_bounds__(1024) void k_scan(const int* deg, int* rowptr, int* cursor, int N){
  __shared__ int wsum[17];
  int tid = threadIdx.x;
  int per = (N + 1023) >> 10;
  int base = tid * per;
  int s = 0;
  for(int i=0;i<per;i++){ int idx = base+i; if(idx < N) s += deg[idx]; }
  int lane = tid & 63, wid = tid >> 6;
  int inc = s;
  for(int d=1; d<64; d<<=1){
    int t = __shfl_up(inc, d);
    if(lane >= d) inc += t;
  }
  if(lane == 63) wsum[wid+1] = inc;
  if(tid == 0) wsum[0] = 0;
  __syncthreads();
  if(tid == 0){ for(int w=1; w<=16; w++) wsum[w] += wsum[w-1]; }
  __syncthreads();
  int run = inc - s + wsum[wid];
  for(int i=0;i<per;i++){
    int idx = base + i;
    if(idx < N){ rowptr[idx] = run; cursor[idx] = run; run += deg[idx]; }
  }
  if(tid == 1023) rowptr[N] = wsum[16];
}
__global__ __launch_bounds__(256) void k_scatter(const int* dstI, int* cursor, int* csr, int E){
  int tid = blockIdx.x*256 + threadIdx.x;
  if(tid < E){
    int p = atomicAdd(&cursor[dstI[tid]], 1);
    csr[p] = tid;
  }
}

// ---------------- softmax-denominator + aggregation, 4-edge-parallel, swizzled v reads ----------------
__global__ __launch_bounds__(256) void k_agg(const int* rowptr, const int* csr, const float* exb, const u16* vbf, u16* aggbf, int N){
  int wave = (blockIdx.x*256 + threadIdx.x) >> 6;
  int lane = threadIdx.x & 63;
  if(wave >= N) return;
  int s0 = rowptr[wave], s1 = rowptr[wave+1];
  float s[4] = {0.f,0.f,0.f,0.f};
  for(int p = s0 + lane; p < s1; p += 64){
    int e = csr[p];
    float4 ev = *reinterpret_cast<const float4*>(exb + (size_t)e*4);
    s[0] += ev.x; s[1] += ev.y; s[2] += ev.z; s[3] += ev.w;
  }
  #pragma unroll
  for(int i=0;i<4;i++){ WREDUCE64(s[i]); }
  int ep = lane >> 4, cc = lane & 15;
  int hh = cc >> 2;
  int swz = hh*64 + (cc&3)*4;
  float inv = 1.f/(s[hh] + 1e-9f);
  float a0=0.f, a1=0.f, a2=0.f, a3=0.f;
  for(int p = s0 + ep; p < s1; p += 4){
    int e = csr[p];
    int t = e & 15;
    size_t base = (size_t)(e & ~15)*64 + (size_t)((t&3)*256) + (size_t)((t>>2)*16) + swz;
    ushort4 v4 = *reinterpret_cast<const ushort4*>(vbf + base);
    float ex = exb[(size_t)e*4 + hh];
    a0 += ex*bf2f(v4.x); a1 += ex*bf2f(v4.y); a2 += ex*bf2f(v4.z); a3 += ex*bf2f(v4.w);
  }
  a0 += __shfl_xor(a0,16); a0 += __shfl_xor(a0,32);
  a1 += __shfl_xor(a1,16); a1 += __shfl_xor(a1,32);
  a2 += __shfl_xor(a2,16); a2 += __shfl_xor(a2,32);
  a3 += __shfl_xor(a3,16); a3 += __shfl_xor(a3,32);
  if(ep == 0){
    ushort4 o;
    o.x = f2bf(a0*inv); o.y = f2bf(a1*inv); o.z = f2bf(a2*inv); o.w = f2bf(a3*inv);
    *reinterpret_cast<ushort4*>(aggbf + (size_t)wave*64 + cc*4) = o;
  }
}

// ---------------- MEGA: x+=agg@Wo; LN; FFN1; FFN2+residual; LN->hbf; Q_next->Qt ----------------
__global__ __launch_bounds__(256) void k_mega(const u16* aggbf, const u16* WoT, float* x,
    const u16* W1T, const u16* W2T, const u16* WqTn, float* Qt, u16* hbf, u16* xbf,
    int writex, int haveQ, int M){
  __shared__ u16 ldsH[4][16*72];
  __shared__ u16 ldsT[4][16*264];
  int widL = threadIdx.x >> 6;
  int wave = (blockIdx.x*256 + threadIdx.x) >> 6;
  int lane = threadIdx.x & 63;
  int row0 = wave*16; if(row0 >= M) return;
  int c = lane & 15, q = lane >> 4;
  u16* LH = ldsH[widL];
  u16* LT = ldsT[widL];

  // Phase A: x += agg @ Wo; h2 = LN(x) -> LDS
  {
    s8v a0 = *reinterpret_cast<const s8v*>(aggbf + (size_t)(row0+c)*64 + q*8);
    s8v a1 = *reinterpret_cast<const s8v*>(aggbf + (size_t)(row0+c)*64 + 32 + q*8);
    float nx[4][4];
    #pragma unroll
    for(int ct=0; ct<4; ct++){
      s8v b0 = *reinterpret_cast<const s8v*>(WoT + (ct*16+c)*64 + q*8);
      s8v b1 = *reinterpret_cast<const s8v*>(WoT + (ct*16+c)*64 + 32 + q*8);
      f32x4 acc = {0.f,0.f,0.f,0.f};
      acc = MFMA(a0, b0, acc);
      acc = MFMA(a1, b1, acc);
      #pragma unroll
      for(int r=0;r<4;r++){
        size_t idx = (size_t)(row0+q*4+r)*64 + ct*16 + c;
        float t = x[idx] + acc[r];
        x[idx] = t;
        nx[ct][r] = t;
      }
    }
    #pragma unroll
    for(int r=0;r<4;r++){
      float s = nx[0][r]+nx[1][r]+nx[2][r]+nx[3][r];
      QREDUCE16(s);
      float m = s*(1.f/64.f);
      float vv = 0.f;
      #pragma unroll
      for(int ct=0;ct<4;ct++){ float d = nx[ct][r]-m; vv += d*d; }
      QREDUCE16(vv);
      float rs = rsqrtf(vv*(1.f/64.f) + 1e-6f);
      #pragma unroll
      for(int ct=0;ct<4;ct++)
        LH[(q*4+r)*72 + ct*16 + c] = f2bf((nx[ct][r]-m)*rs);
    }
  }
  // Phase B/C: t = silu(h2 @ W1) -> LDS
  {
    s8v h0 = *reinterpret_cast<const s8v*>(LH + c*72 + q*8);
    s8v h1 = *reinterpret_cast<const s8v*>(LH + c*72 + 32 + q*8);
    #pragma unroll
    for(int ct=0; ct<16; ct++){
      s8v b0 = *reinterpret_cast<const s8v*>(W1T + (ct*16+c)*64 + q*8);
      s8v b1 = *reinterpret_cast<const s8v*>(W1T + (ct*16+c)*64 + 32 + q*8);
      f32x4 acc = {0.f,0.f,0.f,0.f};
      acc = MFMA(h0, b0, acc);
      acc = MFMA(h1, b1, acc);
      #pragma unroll
      for(int r=0;r<4;r++){
        float y = acc[r];
        LT[(q*4+r)*264 + ct*16 + c] = f2bf(y / (1.f + __expf(-y)));
      }
    }
  }
  // Phase D: x += t @ W2; h = LN(x) -> hbf + LDS
  {
    s8v a[8];
    #pragma unroll
    for(int kc=0; kc<8; kc++)
      a[kc] = *reinterpret_cast<const s8v*>(LT + c*264 + kc*32 + q*8);
    float nx[4][4];
    #pragma unroll
    for(int ct=0; ct<4; ct++){
      f32x4 acc = {0.f,0.f,0.f,0.f};
      #pragma unroll
      for(int kc=0; kc<8; kc++){
        s8v b = *reinterpret_cast<const s8v*>(W2T + (ct*16+c)*256 + kc*32 + q*8);
        acc = MFMA(a[kc], b, acc);
      }
      #pragma unroll
      for(int r=0;r<4;r++){
        size_t idx = (size_t)(row0+q*4+r)*64 + ct*16 + c;
        float t = x[idx] + acc[r];
        x[idx] = t;
        nx[ct][r] = t;
        if(writex) xbf[idx] = f2bf(t);
      }
    }
    #pragma unroll
    for(int r=0;r<4;r++){
      float s = nx[0][r]+nx[1][r]+nx[2][r]+nx[3][r];
      QREDUCE16(s);
      float m = s*(1.f/64.f);
      float vv = 0.f;
      #pragma unroll
      for(int ct=0;ct<4;ct++){ float d = nx[ct][r]-m; vv += d*d; }
      QREDUCE16(vv);
      float rs = rsqrtf(vv*(1.f/64.f) + 1e-6f);
      #pragma unroll
      for(int ct=0;ct<4;ct++){
        u16 hb = f2bf((nx[ct][r]-m)*rs);
        hbf[(size_t)(row0+q*4+r)*64 + ct*16 + c] = hb;
        LH[(q*4+r)*72 + ct*16 + c] = hb;
      }
    }
  }
  // Phase E: Q_next = h @ WqTn -> Qt (node-transposed)
  if(haveQ){
    s8v h0 = *reinterpret_cast<const s8v*>(LH + c*72 + q*8);
    s8v h1 = *reinterpret_cast<const s8v*>(LH + c*72 + 32 + q*8);
    #pragma unroll
    for(int ct=0; ct<4; ct++){
      s8v b0 = *reinterpret_cast<const s8v*>(WqTn + (ct*16+c)*64 + q*8);
      s8v b1 = *reinterpret_cast<const s8v*>(WqTn + (ct*16+c)*64 + 32 + q*8);
      f32x4 acc = {0.f,0.f,0.f,0.f};
      acc = MFMA(h0, b0, acc);
      acc = MFMA(h1, b1, acc);
      #pragma unroll
      for(int r=0;r<4;r++) Qt[(size_t)(row0+q*4+r)*64 + c*4 + ct] = acc[r];
    }
  }
}

// ---------------- feat = x @ W_feat with in-register LN over 512 -> featbf ----------------
__global__ __launch_bounds__(256) void k_feat_ln(const u16* A, const u16* Bt, u16* out, int M){
  int wave = (blockIdx.x*256 + threadIdx.x) >> 6;
  int lane = threadIdx.x & 63;
  int row0 = wave*16; if(row0 >= M) return;
  int c = lane & 15, q = lane >> 4;
  s8v a0 = *reinterpret_cast<const s8v*>(A + (size_t)(row0+c)*64 + q*8);
  s8v a1 = *reinterpret_cast<const s8v*>(A + (size_t)(row0+c)*64 + 32 + q*8);
  float fa[32][4];
  #pragma unroll
  for(int ct=0; ct<32; ct++){
    s8v b0 = *reinterpret_cast<const s8v*>(Bt + (ct*16+c)*64 + q*8);
    s8v b1 = *reinterpret_cast<const s8v*>(Bt + (ct*16+c)*64 + 32 + q*8);
    f32x4 acc = {0.f,0.f,0.f,0.f};
    acc = MFMA(a0, b0, acc);
    acc = MFMA(a1, b1, acc);
    #pragma unroll
    for(int r=0;r<4;r++) fa[ct][r] = acc[r];
  }
  #pragma unroll
  for(int r=0;r<4;r++){
    float s = 0.f;
    #pragma unroll
    for(int ct=0;ct<32;ct++) s += fa[ct][r];
    QREDUCE16(s);
    float m = s*(1.f/512.f);
    float vv = 0.f;
    #pragma unroll
    for(int ct=0;ct<32;ct++){ float d = fa[ct][r]-m; vv += d*d; }
    QREDUCE16(vv);
    float rs = rsqrtf(vv*(1.f/512.f) + 1e-6f);
    #pragma unroll
    for(int ct=0;ct<32;ct++)
      out[(size_t)(row0+q*4+r)*512 + ct*16 + c] = f2bf((fa[ct][r]-m)*rs);
  }
}

// ---------------- head1 (K=512) + bias + LN + relu -> hh1 ----------------
__global__ __launch_bounds__(256) void k_head1_ln(const u16* A, const u16* Bt, const float* hb, u16* out, int M){
  int wave = (blockIdx.x*256 + threadIdx.x) >> 6;
  int lane = threadIdx.x & 63;
  int row0 = wave*16; if(row0 >= M) return;
  int c = lane & 15, q = lane >> 4;
  s8v a[16];
  #pragma unroll
  for(int kc=0; kc<16; kc++)
    a[kc] = *reinterpret_cast<const s8v*>(A + (size_t)(row0+c)*512 + kc*32 + q*8);
  float y[4][4];
  #pragma unroll
  for(int ct=0; ct<4; ct++){
    f32x4 acc = {0.f,0.f,0.f,0.f};
    #pragma unroll
    for(int kc=0; kc<16; kc++){
      s8v b = *reinterpret_cast<const s8v*>(Bt + (size_t)(ct*16+c)*512 + kc*32 + q*8);
      acc = MFMA(a[kc], b, acc);
    }
    float bi = hb[ct*16+c];
    #pragma unroll
    for(int r=0;r<4;r++) y[ct][r] = acc[r] + bi;
  }
  #pragma unroll
  for(int r=0;r<4;r++){
    float s = y[0][r]+y[1][r]+y[2][r]+y[3][r];
    QREDUCE16(s);
    float m = s*(1.f/64.f);
    float vv = 0.f;
    #pragma unroll
    for(int ct=0;ct<4;ct++){ float d = y[ct][r]-m; vv += d*d; }
    QREDUCE16(vv);
    float rs = rsqrtf(vv*(1.f/64.f) + 1e-6f);
    #pragma unroll
    for(int ct=0;ct<4;ct++)
      out[(size_t)(row0+q*4+r)*64 + ct*16 + c] = f2bf(fmaxf((y[ct][r]-m)*rs, 0.f));
  }
}

// ---------------- head2 + bias + LN + relu + dot(hW3) + pooled atomicAdd ----------------
__global__ __launch_bounds__(256) void k_head2_energy(const u16* A, const u16* Bt, const float* hb,
    const float* hW3, const float* hb3, const int* batch, float* pooled, int M){
  int wave = (blockIdx.x*256 + threadIdx.x) >> 6;
  int lane = threadIdx.x & 63;
  int row0 = wave*16; if(row0 >= M) return;
  int c = lane & 15, q = lane >> 4;
  s8v a0 = *reinterpret_cast<const s8v*>(A + (size_t)(row0+c)*64 + q*8);
  s8v a1 = *reinterpret_cast<const s8v*>(A + (size_t)(row0+c)*64 + 32 + q*8);
  float y[4][4];
  #pragma unroll
  for(int ct=0; ct<4; ct++){
    s8v b0 = *reinterpret_cast<const s8v*>(Bt + (ct*16+c)*64 + q*8);
    s8v b1 = *reinterpret_cast<const s8v*>(Bt + (ct*16+c)*64 + 32 + q*8);
    f32x4 acc = {0.f,0.f,0.f,0.f};
    acc = MFMA(a0, b0, acc);
    acc = MFMA(a1, b1, acc);
    float bi = hb[ct*16+c];
    #pragma unroll
    for(int r=0;r<4;r++) y[ct][r] = acc[r] + bi;
  }
  float w3[4];
  #pragma unroll
  for(int ct=0;ct<4;ct++) w3[ct] = hW3[ct*16+c];
  float ep[4];
  #pragma unroll
  for(int r=0;r<4;r++){
    float s = y[0][r]+y[1][r]+y[2][r]+y[3][r];
    QREDUCE16(s);
    float m = s*(1.f/64.f);
    float vv = 0.f;
    #pragma unroll
    for(int ct=0;ct<4;ct++){ float d = y[ct][r]-m; vv += d*d; }
    QREDUCE16(vv);
    float rs = rsqrtf(vv*(1.f/64.f) + 1e-6f);
    float e = 0.f;
    #pragma unroll
    for(int ct=0;ct<4;ct++) e += fmaxf((y[ct][r]-m)*rs, 0.f) * w3[ct];
    QREDUCE16(e);
    ep[r] = e;
  }
  if(c < 4){
    float ev = (c==0)?ep[0]:(c==1)?ep[1]:(c==2)?ep[2]:ep[3];
    int row = row0 + q*4 + c;
    atomicAdd(&pooled[batch[row]], ev + hb3[0]);
  }
}

// ---------------- output f32 ----------------
__global__ __launch_bounds__(256) void k_out(const float* pooled, float* out, int G){
  int tid = blockIdx.x*256 + threadIdx.x;
  if(tid < G) out[tid] = pooled[tid] * 0.11785113019775793f; // 1/sqrt(72)
}

extern "C" void kernel_launch(void* const* d_in, const int* in_sizes, int n_in,
                              void* d_out, int out_size, void* d_ws, size_t ws_size,
                              hipStream_t stream){
  const int*   edge_src  = (const int*)d_in[1];
  const int*   edge_dst  = (const int*)d_in[2];
  const float* edge_vec  = (const float*)d_in[3];
  const int*   batch     = (const int*)d_in[4];
  const int*   node_atom = (const int*)d_in[5];
  const float* ele    = (const float*)d_in[6];
  const float* W_embed= (const float*)d_in[7];
  const float* W_edge = (const float*)d_in[8];
  const float* Wq = (const float*)d_in[9];
  const float* Wk = (const float*)d_in[10];
  const float* Wv = (const float*)d_in[11];
  const float* Wr1= (const float*)d_in[12];
  const float* Wr2= (const float*)d_in[13];
  const float* Wo = (const float*)d_in[14];
  const float* W1 = (const float*)d_in[15];
  const float* W2 = (const float*)d_in[16];
  const float* W_feat=(const float*)d_in[17];
  const float* hW1= (const float*)d_in[18];
  const float* hb1= (const float*)d_in[19];
  const float* hW2= (const float*)d_in[20];
  const float* hb2= (const float*)d_in[21];
  const float* hW3= (const float*)d_in[22];
  const float* hb3= (const float*)d_in[23];
  (void)n_in; (void)ws_size;

  const int E = in_sizes[1];
  const int N = in_sizes[4];
  const int G = out_size;

  // ---- workspace layout: peak ~85 MB ----
  char* base = (char*)d_ws;
  size_t off = 0;
  #define ALLOC(ty, name, count) ty* name = (ty*)(base + off); off = (off + (size_t)(count)*sizeof(ty) + 255) & ~(size_t)255;
  ALLOC(float, r_arr, E)
  ALLOC(u16,   ebf,   (size_t)E*64)
  ALLOC(u16,   vbf,   (size_t)E*64)
  ALLOC(float, exb,   (size_t)E*4)
  ALLOC(u16,   hbf,   (size_t)N*64)
  ALLOC(u16,   aggbf, (size_t)N*64)
  ALLOC(u16,   xbf,   (size_t)N*64)
  ALLOC(float, Qt,    (size_t)N*64)
  ALLOC(float, xb,    (size_t)N*64)
  ALLOC(int,   deg,   N)
  ALLOC(int,   rowptr,N+1)
  ALLOC(int,   cursor,N)
  ALLOC(int,   csr,   E)
  ALLOC(float, pooled,G)
  ALLOC(u16, ele_bf, 120*32)
  ALLOC(u16, WembT, 64*32)
  ALLOC(u16, WedgeT,64*160)
  ALLOC(u16, WqT,  6*64*64)   // WqT..WoT contiguous for transpose5
  ALLOC(u16, WkT,  6*64*64)
  ALLOC(u16, WvT,  6*64*64)
  ALLOC(u16, Wr1T, 6*64*64)
  ALLOC(u16, WoT,  6*64*64)
  ALLOC(u16, W1T,  6*256*64)
  ALLOC(u16, W2T,  6*64*256)
  ALLOC(u16, WfT,  512*64)
  ALLOC(u16, hW1T, 64*512)
  ALLOC(u16, hW2T, 64*64)
  #undef ALLOC
  // tail aliases into loop-dead regions:
  u16* featbf = ebf;          // 16 MB <= 32 MB
  u16* hh1    = (u16*)exb;    // 2 MB <= 4 MB

  auto cdiv = [](int a, int b){ return (a + b - 1)/b; };

  k_convert<<<cdiv(120*32,256),256,0,stream>>>(ele, ele_bf, 120*32);
  k_transpose<<<cdiv(64*32,256),256,0,stream>>>(W_embed, WembT, 1, 32, 64, 32);
  k_transpose<<<cdiv(64*160,256),256,0,stream>>>(W_edge, WedgeT, 1, 137, 64, 160);
  k_transpose5<<<cdiv(5*6*64*64,256),256,0,stream>>>(Wq, Wk, Wv, Wr1, Wo, WqT);
  k_transpose<<<cdiv(6*256*64,256),256,0,stream>>>(W1, W1T, 6, 64, 256, 64);
  k_transpose<<<cdiv(6*64*256,256),256,0,stream>>>(W2, W2T, 6, 256, 64, 256);
  k_transpose<<<cdiv(512*64,256),256,0,stream>>>(W_feat, WfT, 1, 64, 512, 64);
  k_transpose<<<cdiv(64*512,256),256,0,stream>>>(hW1, hW1T, 1, 512, 64, 512);
  k_transpose<<<cdiv(64*64,256),256,0,stream>>>(hW2, hW2T, 1, 64, 64, 64);

  hipMemsetAsync(deg, 0, (size_t)N*sizeof(int), stream);
  hipMemsetAsync(pooled, 0, (size_t)G*sizeof(float), stream);

  k_edge_embed<<<E/64, 256, 0, stream>>>(edge_src, edge_dst, node_atom, ele_bf, edge_vec, WedgeT, ebf, r_arr, E);
  k_count<<<cdiv(E,256),256,0,stream>>>(edge_dst, deg, E);
  k_scan<<<1,1024,0,stream>>>(deg, rowptr, cursor, N);
  k_scatter<<<cdiv(E,256),256,0,stream>>>(edge_dst, cursor, csr, E);
  k_pre<<<N/64,256,0,stream>>>(node_atom, ele_bf, WembT, WqT, xb, hbf, Qt, N);

  for(int l=0; l<6; l++){
    k_kvrad<<<E/64,256,0,stream>>>(hbf, ebf, edge_src, edge_dst, Qt, r_arr,
                                   WkT + l*4096, WvT + l*4096, Wr1T + l*4096, Wr2 + l*256,
                                   vbf, exb, E);
    k_agg<<<cdiv(N,4),256,0,stream>>>(rowptr, csr, exb, vbf, aggbf, N);
    k_mega<<<N/64,256,0,stream>>>(aggbf, WoT + l*4096, xb,
                                  W1T + l*16384, W2T + l*16384,
                                  WqT + ((l<5)?(l+1):0)*4096, Qt, hbf, xbf,
                                  (l==5)?1:0, (l<5)?1:0, N);
  }

  k_feat_ln<<<N/64,256,0,stream>>>(xbf, WfT, featbf, N);
  k_head1_ln<<<N/64,256,0,stream>>>(featbf, hW1T, hb1, hh1, N);
  k_head2_energy<<<N/64,256,0,stream>>>(hh1, hW2T, hb2, hW3, hb3, batch, pooled, N);
  k_out<<<cdiv(G,256),256,0,stream>>>(pooled, (float*)d_out, G);
}

// Round 12
// 823.609 us; speedup vs baseline: 7.2404x; 1.1102x over previous
//
#include <hip/hip_runtime.h>

typedef short s8v __attribute__((ext_vector_type(8)));
typedef float f32x4 __attribute__((ext_vector_type(4)));
typedef unsigned short u16;

__device__ __forceinline__ float bf2f(u16 h){
  union { unsigned u; float f; } v; v.u = ((unsigned)h) << 16; return v.f;
}
__device__ __forceinline__ u16 f2bf(float f){
  union { float f; unsigned u; } v; v.f = f;
  unsigned u = v.u;
  return (u16)((u + 0x7fffu + ((u >> 16) & 1u)) >> 16);
}
#define MFMA(a,b,c) __builtin_amdgcn_mfma_f32_16x16x32_bf16((a),(b),(c),0,0,0)

#define WREDUCE64(s) { s += __shfl_xor(s,1); s += __shfl_xor(s,2); s += __shfl_xor(s,4); \
                       s += __shfl_xor(s,8); s += __shfl_xor(s,16); s += __shfl_xor(s,32); }
#define QREDUCE16(s) { s += __shfl_xor(s,1); s += __shfl_xor(s,2); s += __shfl_xor(s,4); s += __shfl_xor(s,8); }

// ---------------- transpose f32 -> bf16 (zero row padding): dst[b][c][rp] = src[b][rp][c] ----------------
__global__ __launch_bounds__(256) void k_transpose(const float* src, u16* dst, int B, int R, int C, int Rpad){
  int idx = blockIdx.x*256 + threadIdx.x;
  int total = B*C*Rpad;
  if(idx >= total) return;
  int b = idx / (C*Rpad);
  int rem = idx - b*C*Rpad;
  int cI = rem / Rpad;
  int rI = rem - cI*Rpad;
  dst[idx] = (rI < R) ? f2bf(src[(size_t)b*R*C + (size_t)rI*C + cI]) : (u16)0;
}

// 5 batched 6x64x64 transposes in one launch (dst buffers contiguous)
__global__ __launch_bounds__(256) void k_transpose5(const float* W0, const float* W1, const float* W2,
    const float* W3, const float* W4, u16* dst){
  int idx = blockIdx.x*256 + threadIdx.x; // 5*6*64*64
  int which = idx / (6*64*64);
  int rem = idx - which*(6*64*64);
  const float* src = (which==0)?W0:(which==1)?W1:(which==2)?W2:(which==3)?W3:W4;
  int b = rem >> 12;
  int r2 = rem & 4095;
  int cI = r2 >> 6, rI = r2 & 63;
  dst[idx] = f2bf(src[b*4096 + rI*64 + cI]);
}

// ---------------- f32 -> bf16 elementwise convert ----------------
__global__ __launch_bounds__(256) void k_convert(const float* src, u16* dst, int n){
  int idx = blockIdx.x*256 + threadIdx.x;
  if(idx < n) dst[idx] = f2bf(src[idx]);
}

// ---------------- CSR build (runs BEFORE edge_embed now) ----------------
__global__ __launch_bounds__(256) void k_count(const int* dstI, int* deg, int E){
  int tid = blockIdx.x*256 + threadIdx.x;
  if(tid < E) atomicAdd(&deg[dstI[tid]], 1);
}
__global__ __launch_bounds__(1024) void k_scan(const int* deg, int* rowptr, int* cursor, int N){
  __shared__ int wsum[17];
  int tid = threadIdx.x;
  int per = (N + 1023) >> 10;
  int base = tid * per;
  int s = 0;
  for(int i=0;i<per;i++){ int idx = base+i; if(idx < N) s += deg[idx]; }
  int lane = tid & 63, wid = tid >> 6;
  int inc = s;
  for(int d=1; d<64; d<<=1){
    int t = __shfl_up(inc, d);
    if(lane >= d) inc += t;
  }
  if(lane == 63) wsum[wid+1] = inc;
  if(tid == 0) wsum[0] = 0;
  __syncthreads();
  if(tid == 0){ for(int w=1; w<=16; w++) wsum[w] += wsum[w-1]; }
  __syncthreads();
  int run = inc - s + wsum[wid];
  for(int i=0;i<per;i++){
    int idx = base + i;
    if(idx < N){ rowptr[idx] = run; cursor[idx] = run; run += deg[idx]; }
  }
  if(tid == 1023) rowptr[N] = wsum[16];
}
__global__ __launch_bounds__(256) void k_scatter(const int* dstI, int* cursor, int* csr, int E){
  int tid = blockIdx.x*256 + threadIdx.x;
  if(tid < E){
    int p = atomicAdd(&cursor[dstI[tid]], 1);
    csr[p] = tid;
  }
}

// ---------------- e = [nf_src, nf_dst, sh, rbf] @ W_edge in CSR-PERMUTED order ----------------
// output row p corresponds to source edge csr[p]; also emits permuted src2/dst2/r2
__global__ __launch_bounds__(256) void k_edge_embed(const int* csr, const int* srcI, const int* dstI,
    const int* atom, const u16* ele, const float* evec, const u16* Bt,
    u16* ebf, float* r2, int* src2, int* dst2, int E){
  int wave = (blockIdx.x*blockDim.x + threadIdx.x) >> 6;
  int lane = threadIdx.x & 63;
  int row0 = wave*16; if(row0 >= E) return;
  int c = lane & 15, q = lane >> 4;
  int p = row0 + c;
  int e = csr[p];
  int sn = srcI[e], dn = dstI[e];
  float vx = evec[(size_t)e*3+0];
  float vy = evec[(size_t)e*3+1];
  float vz = evec[(size_t)e*3+2];
  float r = sqrtf(vx*vx + vy*vy + vz*vz);
  if(q == 0){ r2[p] = r; src2[p] = sn; dst2[p] = dn; }
  float inv = 1.f/(r + 1e-12f);
  // u = edge_vec[:, [1,2,0]] / r -> x=v1, y=v2, z=v0
  float x = vy*inv, y = vz*inv, z = vx*inv;
  const float s3 = 1.7320508075688772f, s15 = 3.872983346207417f;
  const float s5h = 1.118033988749895f, s15h = 1.9364916731037085f;
  float sh[9];
  sh[0] = 1.f; sh[1] = s3*x; sh[2] = s3*y; sh[3] = s3*z;
  sh[4] = s15*x*y; sh[5] = s15*y*z; sh[6] = s5h*(3.f*z*z - 1.f);
  sh[7] = s15*x*z; sh[8] = s15h*(x*x - y*y);
  s8v a[5];
  a[0] = *reinterpret_cast<const s8v*>(ele + (size_t)atom[sn]*32 + q*8);
  a[1] = *reinterpret_cast<const s8v*>(ele + (size_t)atom[dn]*32 + q*8);
  // kc=2: cols 64..95 (sh for col<73, else rbf)
  #pragma unroll
  for(int j=0;j<8;j++){
    int col = 64 + q*8 + j;
    u16 v;
    if(q == 0)            v = f2bf(sh[j]);
    else if(col < 73)     v = f2bf(sh[8]);
    else { float d = r - (10.f/63.f)*(float)(col-73); v = f2bf(__expf(-81.92f*d*d)); }
    a[2][j] = (short)v;
  }
  // kc=3: cols 96..127 -> rbf(23+q*8+j)
  #pragma unroll
  for(int j=0;j<8;j++){
    float d = r - (10.f/63.f)*(float)(23 + q*8 + j);
    a[3][j] = (short)f2bf(__expf(-81.92f*d*d));
  }
  // kc=4: cols 128..159 -> rbf while col<137 else 0
  #pragma unroll
  for(int j=0;j<8;j++){
    int col = 128 + q*8 + j;
    u16 v = 0;
    if(col < 137){ float d = r - (10.f/63.f)*(float)(col-73); v = f2bf(__expf(-81.92f*d*d)); }
    a[4][j] = (short)v;
  }
  #pragma unroll
  for(int ct=0; ct<4; ct++){
    f32x4 acc = {0.f,0.f,0.f,0.f};
    #pragma unroll
    for(int kc=0; kc<5; kc++){
      s8v b = *reinterpret_cast<const s8v*>(Bt + (ct*16+c)*160 + kc*32 + q*8);
      acc = MFMA(a[kc], b, acc);
    }
    #pragma unroll
    for(int r_=0;r_<4;r_++) ebf[(size_t)(row0+q*4+r_)*64 + ct*16 + c] = f2bf(acc[r_]);
  }
}

// ---------------- pre: x = ele[atom]@Wemb; h0 = LN(x); Q0 = h0@Wq0 (Qt layout) ----------------
__global__ __launch_bounds__(256) void k_pre(const int* atom, const u16* ele, const u16* WembT,
    const u16* WqT0, float* xb, u16* hbf, float* Qt, int M){
  __shared__ u16 ldsH[4][16*72];
  int widL = threadIdx.x >> 6;
  int wave = (blockIdx.x*256 + threadIdx.x) >> 6;
  int lane = threadIdx.x & 63;
  int row0 = wave*16; if(row0 >= M) return;
  int c = lane & 15, q = lane >> 4;
  u16* LH = ldsH[widL];
  int at = atom[row0 + c];
  s8v a = *reinterpret_cast<const s8v*>(ele + (size_t)at*32 + q*8);
  float nx[4][4];
  #pragma unroll
  for(int ct=0; ct<4; ct++){
    s8v b = *reinterpret_cast<const s8v*>(WembT + (ct*16+c)*32 + q*8);
    f32x4 acc = {0.f,0.f,0.f,0.f};
    acc = MFMA(a, b, acc);
    #pragma unroll
    for(int r=0;r<4;r++){
      xb[(size_t)(row0+q*4+r)*64 + ct*16 + c] = acc[r];
      nx[ct][r] = acc[r];
    }
  }
  #pragma unroll
  for(int r=0;r<4;r++){
    float s = nx[0][r]+nx[1][r]+nx[2][r]+nx[3][r];
    QREDUCE16(s);
    float m = s*(1.f/64.f);
    float vv = 0.f;
    #pragma unroll
    for(int ct=0;ct<4;ct++){ float d = nx[ct][r]-m; vv += d*d; }
    QREDUCE16(vv);
    float rs = rsqrtf(vv*(1.f/64.f) + 1e-6f);
    #pragma unroll
    for(int ct=0;ct<4;ct++){
      u16 hb = f2bf((nx[ct][r]-m)*rs);
      hbf[(size_t)(row0+q*4+r)*64 + ct*16 + c] = hb;
      LH[(q*4+r)*72 + ct*16 + c] = hb;
    }
  }
  s8v h0 = *reinterpret_cast<const s8v*>(LH + c*72 + q*8);
  s8v h1 = *reinterpret_cast<const s8v*>(LH + c*72 + 32 + q*8);
  #pragma unroll
  for(int ct=0; ct<4; ct++){
    s8v b0 = *reinterpret_cast<const s8v*>(WqT0 + (ct*16+c)*64 + q*8);
    s8v b1 = *reinterpret_cast<const s8v*>(WqT0 + (ct*16+c)*64 + 32 + q*8);
    f32x4 acc = {0.f,0.f,0.f,0.f};
    acc = MFMA(h0, b0, acc);
    acc = MFMA(h1, b1, acc);
    #pragma unroll
    for(int r=0;r<4;r++) Qt[(size_t)(row0+q*4+r)*64 + c*4 + ct] = acc[r];
  }
}

// ---------------- fused: k,v,hid MFMAs; rbf on-the-fly; logits via quad-shuffle ----------------
// edges in CSR order; vbf tile-swizzled; Qt[node*64 + c*4 + ct]
__global__ __launch_bounds__(256) void k_kvrad(const u16* hbf, const u16* ebf,
    const int* src2, const int* dst2, const float* Qt, const float* r2,
    const u16* WkT, const u16* WvT, const u16* Wr1T, const float* Wr2,
    u16* vbf, float* exb, int E){
  int wave = (blockIdx.x*256 + threadIdx.x) >> 6;
  int lane = threadIdx.x & 63;
  int row0 = wave*16;
  int c = lane & 15, q = lane >> 4;
  int sr = src2[row0 + c];
  s8v a0, a1;
  {
    s8v h0 = *reinterpret_cast<const s8v*>(hbf + (size_t)sr*64 + q*8);
    s8v h1 = *reinterpret_cast<const s8v*>(hbf + (size_t)sr*64 + 32 + q*8);
    s8v e0 = *reinterpret_cast<const s8v*>(ebf + (size_t)(row0+c)*64 + q*8);
    s8v e1 = *reinterpret_cast<const s8v*>(ebf + (size_t)(row0+c)*64 + 32 + q*8);
    #pragma unroll
    for(int j=0;j<8;j++){
      a0[j] = (short)f2bf(bf2f((u16)h0[j]) + bf2f((u16)e0[j]));
      a1[j] = (short)f2bf(bf2f((u16)h1[j]) + bf2f((u16)e1[j]));
    }
  }
  float re = r2[row0 + c];
  s8v r0, r1;
  #pragma unroll
  for(int j=0;j<8;j++){
    float d0 = re - (10.f/63.f)*(float)(q*8+j);
    float d1 = re - (10.f/63.f)*(float)(32+q*8+j);
    r0[j] = (short)f2bf(__expf(-81.92f*d0*d0));
    r1[j] = (short)f2bf(__expf(-81.92f*d1*d1));
  }
  const float4* QtV = reinterpret_cast<const float4*>(Qt);
  float4 qv[4];
  #pragma unroll
  for(int r=0;r<4;r++){
    int dr = dst2[row0 + q*4 + r];
    qv[r] = QtV[(size_t)dr*16 + c];
  }
  const float4* wr2v = reinterpret_cast<const float4*>(Wr2);
  float comb[4][4];
  #pragma unroll
  for(int h=0;h<4;h++)
    #pragma unroll
    for(int r=0;r<4;r++) comb[h][r] = 0.f;
  #pragma unroll
  for(int ct=0; ct<4; ct++){
    s8v bk0 = *reinterpret_cast<const s8v*>(WkT + (ct*16+c)*64 + q*8);
    s8v bk1 = *reinterpret_cast<const s8v*>(WkT + (ct*16+c)*64 + 32 + q*8);
    s8v bv0 = *reinterpret_cast<const s8v*>(WvT + (ct*16+c)*64 + q*8);
    s8v bv1 = *reinterpret_cast<const s8v*>(WvT + (ct*16+c)*64 + 32 + q*8);
    s8v bw0 = *reinterpret_cast<const s8v*>(Wr1T + (ct*16+c)*64 + q*8);
    s8v bw1 = *reinterpret_cast<const s8v*>(Wr1T + (ct*16+c)*64 + 32 + q*8);
    f32x4 kacc = {0.f,0.f,0.f,0.f};
    kacc = MFMA(a0, bk0, kacc); kacc = MFMA(a1, bk1, kacc);
    f32x4 vacc = {0.f,0.f,0.f,0.f};
    vacc = MFMA(a0, bv0, vacc); vacc = MFMA(a1, bv1, vacc);
    f32x4 hacc = {0.f,0.f,0.f,0.f};
    hacc = MFMA(r0, bw0, hacc); hacc = MFMA(r1, bw1, hacc);
    float4 w2 = wr2v[ct*16 + c];
    #pragma unroll
    for(int r=0;r<4;r++){
      vbf[(size_t)row0*64 + (r*4+ct)*64 + q*16 + c] = f2bf(vacc[r]);
      float qc = (ct==0)?qv[r].x:(ct==1)?qv[r].y:(ct==2)?qv[r].z:qv[r].w;
      comb[ct][r] += 0.25f * kacc[r] * qc;
      float y = hacc[r];
      float sv = y / (1.f + __expf(-y));
      comb[0][r] += sv * w2.x;
      comb[1][r] += sv * w2.y;
      comb[2][r] += sv * w2.z;
      comb[3][r] += sv * w2.w;
    }
  }
  #pragma unroll
  for(int m=1; m<16; m<<=1){
    #pragma unroll
    for(int h=0;h<4;h++)
      #pragma unroll
      for(int r=0;r<4;r++) comb[h][r] += __shfl_xor(comb[h][r], m);
  }
  int hh = c & 3, rr = c >> 2;
  float logit = comb[0][0];
  #pragma unroll
  for(int h=0;h<4;h++)
    #pragma unroll
    for(int r=0;r<4;r++)
      if(h || r) logit = (hh==h && rr==r) ? comb[h][r] : logit;
  int row = row0 + q*4 + rr;
  exb[(size_t)row0*4 + lane] = (r2[row] < 10.f) ? __expf(logit) : 0.f;
}

// ---------------- softmax-denominator + aggregation; edges contiguous per node ----------------
__global__ __launch_bounds__(256) void k_agg(const int* rowptr, const float* exb, const u16* vbf, u16* aggbf, int N){
  int wave = (blockIdx.x*256 + threadIdx.x) >> 6;
  int lane = threadIdx.x & 63;
  if(wave >= N) return;
  int s0 = rowptr[wave], s1 = rowptr[wave+1];
  float s[4] = {0.f,0.f,0.f,0.f};
  for(int p = s0 + lane; p < s1; p += 64){
    float4 ev = *reinterpret_cast<const float4*>(exb + (size_t)p*4);
    s[0] += ev.x; s[1] += ev.y; s[2] += ev.z; s[3] += ev.w;
  }
  #pragma unroll
  for(int i=0;i<4;i++){ WREDUCE64(s[i]); }
  int ep = lane >> 4, cc = lane & 15;
  int hh = cc >> 2;
  int swz = hh*64 + (cc&3)*4;
  float inv = 1.f/(s[hh] + 1e-9f);
  float a0=0.f, a1=0.f, a2=0.f, a3=0.f;
  for(int p = s0 + ep; p < s1; p += 4){
    int t = p & 15;
    size_t base = (size_t)(p & ~15)*64 + (size_t)((t&3)*256) + (size_t)((t>>2)*16) + swz;
    ushort4 v4 = *reinterpret_cast<const ushort4*>(vbf + base);
    float ex = exb[(size_t)p*4 + hh];
    a0 += ex*bf2f(v4.x); a1 += ex*bf2f(v4.y); a2 += ex*bf2f(v4.z); a3 += ex*bf2f(v4.w);
  }
  a0 += __shfl_xor(a0,16); a0 += __shfl_xor(a0,32);
  a1 += __shfl_xor(a1,16); a1 += __shfl_xor(a1,32);
  a2 += __shfl_xor(a2,16); a2 += __shfl_xor(a2,32);
  a3 += __shfl_xor(a3,16); a3 += __shfl_xor(a3,32);
  if(ep == 0){
    ushort4 o;
    o.x = f2bf(a0*inv); o.y = f2bf(a1*inv); o.z = f2bf(a2*inv); o.w = f2bf(a3*inv);
    *reinterpret_cast<ushort4*>(aggbf + (size_t)wave*64 + cc*4) = o;
  }
}

// ---------------- MEGA: x+=agg@Wo; LN; FFN1; FFN2+residual; LN->hbf; Q_next->Qt ----------------
__global__ __launch_bounds__(256) void k_mega(const u16* aggbf, const u16* WoT, float* x,
    const u16* W1T, const u16* W2T, const u16* WqTn, float* Qt, u16* hbf, u16* xbf,
    int writex, int haveQ, int M){
  __shared__ u16 ldsH[4][16*72];
  __shared__ u16 ldsT[4][16*264];
  int widL = threadIdx.x >> 6;
  int wave = (blockIdx.x*256 + threadIdx.x) >> 6;
  int lane = threadIdx.x & 63;
  int row0 = wave*16; if(row0 >= M) return;
  int c = lane & 15, q = lane >> 4;
  u16* LH = ldsH[widL];
  u16* LT = ldsT[widL];

  // Phase A: x += agg @ Wo; h2 = LN(x) -> LDS
  {
    s8v a0 = *reinterpret_cast<const s8v*>(aggbf + (size_t)(row0+c)*64 + q*8);
    s8v a1 = *reinterpret_cast<const s8v*>(aggbf + (size_t)(row0+c)*64 + 32 + q*8);
    float nx[4][4];
    #pragma unroll
    for(int ct=0; ct<4; ct++){
      s8v b0 = *reinterpret_cast<const s8v*>(WoT + (ct*16+c)*64 + q*8);
      s8v b1 = *reinterpret_cast<const s8v*>(WoT + (ct*16+c)*64 + 32 + q*8);
      f32x4 acc = {0.f,0.f,0.f,0.f};
      acc = MFMA(a0, b0, acc);
      acc = MFMA(a1, b1, acc);
      #pragma unroll
      for(int r=0;r<4;r++){
        size_t idx = (size_t)(row0+q*4+r)*64 + ct*16 + c;
        float t = x[idx] + acc[r];
        x[idx] = t;
        nx[ct][r] = t;
      }
    }
    #pragma unroll
    for(int r=0;r<4;r++){
      float s = nx[0][r]+nx[1][r]+nx[2][r]+nx[3][r];
      QREDUCE16(s);
      float m = s*(1.f/64.f);
      float vv = 0.f;
      #pragma unroll
      for(int ct=0;ct<4;ct++){ float d = nx[ct][r]-m; vv += d*d; }
      QREDUCE16(vv);
      float rs = rsqrtf(vv*(1.f/64.f) + 1e-6f);
      #pragma unroll
      for(int ct=0;ct<4;ct++)
        LH[(q*4+r)*72 + ct*16 + c] = f2bf((nx[ct][r]-m)*rs);
    }
  }
  // Phase B/C: t = silu(h2 @ W1) -> LDS
  {
    s8v h0 = *reinterpret_cast<const s8v*>(LH + c*72 + q*8);
    s8v h1 = *reinterpret_cast<const s8v*>(LH + c*72 + 32 + q*8);
    #pragma unroll
    for(int ct=0; ct<16; ct++){
      s8v b0 = *reinterpret_cast<const s8v*>(W1T + (ct*16+c)*64 + q*8);
      s8v b1 = *reinterpret_cast<const s8v*>(W1T + (ct*16+c)*64 + 32 + q*8);
      f32x4 acc = {0.f,0.f,0.f,0.f};
      acc = MFMA(h0, b0, acc);
      acc = MFMA(h1, b1, acc);
      #pragma unroll
      for(int r=0;r<4;r++){
        float y = acc[r];
        LT[(q*4+r)*264 + ct*16 + c] = f2bf(y / (1.f + __expf(-y)));
      }
    }
  }
  // Phase D: x += t @ W2; h = LN(x) -> hbf + LDS
  {
    s8v a[8];
    #pragma unroll
    for(int kc=0; kc<8; kc++)
      a[kc] = *reinterpret_cast<const s8v*>(LT + c*264 + kc*32 + q*8);
    float nx[4][4];
    #pragma unroll
    for(int ct=0; ct<4; ct++){
      f32x4 acc = {0.f,0.f,0.f,0.f};
      #pragma unroll
      for(int kc=0; kc<8; kc++){
        s8v b = *reinterpret_cast<const s8v*>(W2T + (ct*16+c)*256 + kc*32 + q*8);
        acc = MFMA(a[kc], b, acc);
      }
      #pragma unroll
      for(int r=0;r<4;r++){
        size_t idx = (size_t)(row0+q*4+r)*64 + ct*16 + c;
        float t = x[idx] + acc[r];
        x[idx] = t;
        nx[ct][r] = t;
        if(writex) xbf[idx] = f2bf(t);
      }
    }
    #pragma unroll
    for(int r=0;r<4;r++){
      float s = nx[0][r]+nx[1][r]+nx[2][r]+nx[3][r];
      QREDUCE16(s);
      float m = s*(1.f/64.f);
      float vv = 0.f;
      #pragma unroll
      for(int ct=0;ct<4;ct++){ float d = nx[ct][r]-m; vv += d*d; }
      QREDUCE16(vv);
      float rs = rsqrtf(vv*(1.f/64.f) + 1e-6f);
      #pragma unroll
      for(int ct=0;ct<4;ct++){
        u16 hb = f2bf((nx[ct][r]-m)*rs);
        hbf[(size_t)(row0+q*4+r)*64 + ct*16 + c] = hb;
        LH[(q*4+r)*72 + ct*16 + c] = hb;
      }
    }
  }
  // Phase E: Q_next = h @ WqTn -> Qt (node-transposed)
  if(haveQ){
    s8v h0 = *reinterpret_cast<const s8v*>(LH + c*72 + q*8);
    s8v h1 = *reinterpret_cast<const s8v*>(LH + c*72 + 32 + q*8);
    #pragma unroll
    for(int ct=0; ct<4; ct++){
      s8v b0 = *reinterpret_cast<const s8v*>(WqTn + (ct*16+c)*64 + q*8);
      s8v b1 = *reinterpret_cast<const s8v*>(WqTn + (ct*16+c)*64 + 32 + q*8);
      f32x4 acc = {0.f,0.f,0.f,0.f};
      acc = MFMA(h0, b0, acc);
      acc = MFMA(h1, b1, acc);
      #pragma unroll
      for(int r=0;r<4;r++) Qt[(size_t)(row0+q*4+r)*64 + c*4 + ct] = acc[r];
    }
  }
}

// ---------------- feat = x @ W_feat with in-register LN over 512 -> featbf ----------------
__global__ __launch_bounds__(256) void k_feat_ln(const u16* A, const u16* Bt, u16* out, int M){
  int wave = (blockIdx.x*256 + threadIdx.x) >> 6;
  int lane = threadIdx.x & 63;
  int row0 = wave*16; if(row0 >= M) return;
  int c = lane & 15, q = lane >> 4;
  s8v a0 = *reinterpret_cast<const s8v*>(A + (size_t)(row0+c)*64 + q*8);
  s8v a1 = *reinterpret_cast<const s8v*>(A + (size_t)(row0+c)*64 + 32 + q*8);
  float fa[32][4];
  #pragma unroll
  for(int ct=0; ct<32; ct++){
    s8v b0 = *reinterpret_cast<const s8v*>(Bt + (ct*16+c)*64 + q*8);
    s8v b1 = *reinterpret_cast<const s8v*>(Bt + (ct*16+c)*64 + 32 + q*8);
    f32x4 acc = {0.f,0.f,0.f,0.f};
    acc = MFMA(a0, b0, acc);
    acc = MFMA(a1, b1, acc);
    #pragma unroll
    for(int r=0;r<4;r++) fa[ct][r] = acc[r];
  }
  #pragma unroll
  for(int r=0;r<4;r++){
    float s = 0.f;
    #pragma unroll
    for(int ct=0;ct<32;ct++) s += fa[ct][r];
    QREDUCE16(s);
    float m = s*(1.f/512.f);
    float vv = 0.f;
    #pragma unroll
    for(int ct=0;ct<32;ct++){ float d = fa[ct][r]-m; vv += d*d; }
    QREDUCE16(vv);
    float rs = rsqrtf(vv*(1.f/512.f) + 1e-6f);
    #pragma unroll
    for(int ct=0;ct<32;ct++)
      out[(size_t)(row0+q*4+r)*512 + ct*16 + c] = f2bf((fa[ct][r]-m)*rs);
  }
}

// ---------------- head1 (K=512) + bias + LN + relu -> hh1 ----------------
__global__ __launch_bounds__(256) void k_head1_ln(const u16* A, const u16* Bt, const float* hb, u16* out, int M){
  int wave = (blockIdx.x*256 + threadIdx.x) >> 6;
  int lane = threadIdx.x & 63;
  int row0 = wave*16; if(row0 >= M) return;
  int c = lane & 15, q = lane >> 4;
  s8v a[16];
  #pragma unroll
  for(int kc=0; kc<16; kc++)
    a[kc] = *reinterpret_cast<const s8v*>(A + (size_t)(row0+c)*512 + kc*32 + q*8);
  float y[4][4];
  #pragma unroll
  for(int ct=0; ct<4; ct++){
    f32x4 acc = {0.f,0.f,0.f,0.f};
    #pragma unroll
    for(int kc=0; kc<16; kc++){
      s8v b = *reinterpret_cast<const s8v*>(Bt + (size_t)(ct*16+c)*512 + kc*32 + q*8);
      acc = MFMA(a[kc], b, acc);
    }
    float bi = hb[ct*16+c];
    #pragma unroll
    for(int r=0;r<4;r++) y[ct][r] = acc[r] + bi;
  }
  #pragma unroll
  for(int r=0;r<4;r++){
    float s = y[0][r]+y[1][r]+y[2][r]+y[3][r];
    QREDUCE16(s);
    float m = s*(1.f/64.f);
    float vv = 0.f;
    #pragma unroll
    for(int ct=0;ct<4;ct++){ float d = y[ct][r]-m; vv += d*d; }
    QREDUCE16(vv);
    float rs = rsqrtf(vv*(1.f/64.f) + 1e-6f);
    #pragma unroll
    for(int ct=0;ct<4;ct++)
      out[(size_t)(row0+q*4+r)*64 + ct*16 + c] = f2bf(fmaxf((y[ct][r]-m)*rs, 0.f));
  }
}

// ---------------- head2 + bias + LN + relu + dot(hW3) + pooled atomicAdd ----------------
__global__ __launch_bounds__(256) void k_head2_energy(const u16* A, const u16* Bt, const float* hb,
    const float* hW3, const float* hb3, const int* batch, float* pooled, int M){
  int wave = (blockIdx.x*256 + threadIdx.x) >> 6;
  int lane = threadIdx.x & 63;
  int row0 = wave*16; if(row0 >= M) return;
  int c = lane & 15, q = lane >> 4;
  s8v a0 = *reinterpret_cast<const s8v*>(A + (size_t)(row0+c)*64 + q*8);
  s8v a1 = *reinterpret_cast<const s8v*>(A + (size_t)(row0+c)*64 + 32 + q*8);
  float y[4][4];
  #pragma unroll
  for(int ct=0; ct<4; ct++){
    s8v b0 = *reinterpret_cast<const s8v*>(Bt + (ct*16+c)*64 + q*8);
    s8v b1 = *reinterpret_cast<const s8v*>(Bt + (ct*16+c)*64 + 32 + q*8);
    f32x4 acc = {0.f,0.f,0.f,0.f};
    acc = MFMA(a0, b0, acc);
    acc = MFMA(a1, b1, acc);
    float bi = hb[ct*16+c];
    #pragma unroll
    for(int r=0;r<4;r++) y[ct][r] = acc[r] + bi;
  }
  float w3[4];
  #pragma unroll
  for(int ct=0;ct<4;ct++) w3[ct] = hW3[ct*16+c];
  float ep[4];
  #pragma unroll
  for(int r=0;r<4;r++){
    float s = y[0][r]+y[1][r]+y[2][r]+y[3][r];
    QREDUCE16(s);
    float m = s*(1.f/64.f);
    float vv = 0.f;
    #pragma unroll
    for(int ct=0;ct<4;ct++){ float d = y[ct][r]-m; vv += d*d; }
    QREDUCE16(vv);
    float rs = rsqrtf(vv*(1.f/64.f) + 1e-6f);
    float e = 0.f;
    #pragma unroll
    for(int ct=0;ct<4;ct++) e += fmaxf((y[ct][r]-m)*rs, 0.f) * w3[ct];
    QREDUCE16(e);
    ep[r] = e;
  }
  if(c < 4){
    float ev = (c==0)?ep[0]:(c==1)?ep[1]:(c==2)?ep[2]:ep[3];
    int row = row0 + q*4 + c;
    atomicAdd(&pooled[batch[row]], ev + hb3[0]);
  }
}

// ---------------- output f32 ----------------
__global__ __launch_bounds__(256) void k_out(const float* pooled, float* out, int G){
  int tid = blockIdx.x*256 + threadIdx.x;
  if(tid < G) out[tid] = pooled[tid] * 0.11785113019775793f; // 1/sqrt(72)
}

extern "C" void kernel_launch(void* const* d_in, const int* in_sizes, int n_in,
                              void* d_out, int out_size, void* d_ws, size_t ws_size,
                              hipStream_t stream){
  const int*   edge_src  = (const int*)d_in[1];
  const int*   edge_dst  = (const int*)d_in[2];
  const float* edge_vec  = (const float*)d_in[3];
  const int*   batch     = (const int*)d_in[4];
  const int*   node_atom = (const int*)d_in[5];
  const float* ele    = (const float*)d_in[6];
  const float* W_embed= (const float*)d_in[7];
  const float* W_edge = (const float*)d_in[8];
  const float* Wq = (const float*)d_in[9];
  const float* Wk = (const float*)d_in[10];
  const float* Wv = (const float*)d_in[11];
  const float* Wr1= (const float*)d_in[12];
  const float* Wr2= (const float*)d_in[13];
  const float* Wo = (const float*)d_in[14];
  const float* W1 = (const float*)d_in[15];
  const float* W2 = (const float*)d_in[16];
  const float* W_feat=(const float*)d_in[17];
  const float* hW1= (const float*)d_in[18];
  const float* hb1= (const float*)d_in[19];
  const float* hW2= (const float*)d_in[20];
  const float* hb2= (const float*)d_in[21];
  const float* hW3= (const float*)d_in[22];
  const float* hb3= (const float*)d_in[23];
  (void)n_in; (void)ws_size;

  const int E = in_sizes[1];
  const int N = in_sizes[4];
  const int G = out_size;

  // ---- workspace layout: peak ~88 MB ----
  char* base = (char*)d_ws;
  size_t off = 0;
  #define ALLOC(ty, name, count) ty* name = (ty*)(base + off); off = (off + (size_t)(count)*sizeof(ty) + 255) & ~(size_t)255;
  ALLOC(float, r2,    E)
  ALLOC(int,   src2,  E)
  ALLOC(int,   dst2,  E)
  ALLOC(u16,   ebf,   (size_t)E*64)
  ALLOC(u16,   vbf,   (size_t)E*64)
  ALLOC(float, exb,   (size_t)E*4)
  ALLOC(u16,   hbf,   (size_t)N*64)
  ALLOC(u16,   aggbf, (size_t)N*64)
  ALLOC(u16,   xbf,   (size_t)N*64)
  ALLOC(float, Qt,    (size_t)N*64)
  ALLOC(float, xb,    (size_t)N*64)
  ALLOC(int,   deg,   N)
  ALLOC(int,   rowptr,N+1)
  ALLOC(int,   cursor,N)
  ALLOC(int,   csr,   E)
  ALLOC(float, pooled,G)
  ALLOC(u16, ele_bf, 120*32)
  ALLOC(u16, WembT, 64*32)
  ALLOC(u16, WedgeT,64*160)
  ALLOC(u16, WqT,  6*64*64)   // WqT..WoT contiguous for transpose5
  ALLOC(u16, WkT,  6*64*64)
  ALLOC(u16, WvT,  6*64*64)
  ALLOC(u16, Wr1T, 6*64*64)
  ALLOC(u16, WoT,  6*64*64)
  ALLOC(u16, W1T,  6*256*64)
  ALLOC(u16, W2T,  6*64*256)
  ALLOC(u16, WfT,  512*64)
  ALLOC(u16, hW1T, 64*512)
  ALLOC(u16, hW2T, 64*64)
  #undef ALLOC
  // tail aliases into loop-dead regions:
  u16* featbf = ebf;          // 16 MB <= 32 MB
  u16* hh1    = (u16*)exb;    // 2 MB <= 4 MB

  auto cdiv = [](int a, int b){ return (a + b - 1)/b; };

  k_convert<<<cdiv(120*32,256),256,0,stream>>>(ele, ele_bf, 120*32);
  k_transpose<<<cdiv(64*32,256),256,0,stream>>>(W_embed, WembT, 1, 32, 64, 32);
  k_transpose<<<cdiv(64*160,256),256,0,stream>>>(W_edge, WedgeT, 1, 137, 64, 160);
  k_transpose5<<<cdiv(5*6*64*64,256),256,0,stream>>>(Wq, Wk, Wv, Wr1, Wo, WqT);
  k_transpose<<<cdiv(6*256*64,256),256,0,stream>>>(W1, W1T, 6, 64, 256, 64);
  k_transpose<<<cdiv(6*64*256,256),256,0,stream>>>(W2, W2T, 6, 256, 64, 256);
  k_transpose<<<cdiv(512*64,256),256,0,stream>>>(W_feat, WfT, 1, 64, 512, 64);
  k_transpose<<<cdiv(64*512,256),256,0,stream>>>(hW1, hW1T, 1, 512, 64, 512);
  k_transpose<<<cdiv(64*64,256),256,0,stream>>>(hW2, hW2T, 1, 64, 64, 64);

  hipMemsetAsync(deg, 0, (size_t)N*sizeof(int), stream);
  hipMemsetAsync(pooled, 0, (size_t)G*sizeof(float), stream);

  // CSR build first; edge_embed writes edge data in CSR (dst-sorted) order
  k_count<<<cdiv(E,256),256,0,stream>>>(edge_dst, deg, E);
  k_scan<<<1,1024,0,stream>>>(deg, rowptr, cursor, N);
  k_scatter<<<cdiv(E,256),256,0,stream>>>(edge_dst, cursor, csr, E);
  k_edge_embed<<<E/64, 256, 0, stream>>>(csr, edge_src, edge_dst, node_atom, ele_bf, edge_vec,
                                         WedgeT, ebf, r2, src2, dst2, E);
  k_pre<<<N/64,256,0,stream>>>(node_atom, ele_bf, WembT, WqT, xb, hbf, Qt, N);

  for(int l=0; l<6; l++){
    k_kvrad<<<E/64,256,0,stream>>>(hbf, ebf, src2, dst2, Qt, r2,
                                   WkT + l*4096, WvT + l*4096, Wr1T + l*4096, Wr2 + l*256,
                                   vbf, exb, E);
    k_agg<<<cdiv(N,4),256,0,stream>>>(rowptr, exb, vbf, aggbf, N);
    k_mega<<<N/64,256,0,stream>>>(aggbf, WoT + l*4096, xb,
                                  W1T + l*16384, W2T + l*16384,
                                  WqT + ((l<5)?(l+1):0)*4096, Qt, hbf, xbf,
                                  (l==5)?1:0, (l<5)?1:0, N);
  }

  k_feat_ln<<<N/64,256,0,stream>>>(xbf, WfT, featbf, N);
  k_head1_ln<<<N/64,256,0,stream>>>(featbf, hW1T, hb1, hh1, N);
  k_head2_energy<<<N/64,256,0,stream>>>(hh1, hW2T, hb2, hW3, hb3, batch, pooled, N);
  k_out<<<cdiv(G,256),256,0,stream>>>(pooled, (float*)d_out, G);
}

// Round 13
// 815.990 us; speedup vs baseline: 7.3080x; 1.0093x over previous
//
#include <hip/hip_runtime.h>

typedef short s8v __attribute__((ext_vector_type(8)));
typedef float f32x4 __attribute__((ext_vector_type(4)));
typedef unsigned short u16;

__device__ __forceinline__ float bf2f(u16 h){
  union { unsigned u; float f; } v; v.u = ((unsigned)h) << 16; return v.f;
}
__device__ __forceinline__ u16 f2bf(float f){
  union { float f; unsigned u; } v; v.f = f;
  unsigned u = v.u;
  return (u16)((u + 0x7fffu + ((u >> 16) & 1u)) >> 16);
}
#define MFMA(a,b,c) __builtin_amdgcn_mfma_f32_16x16x32_bf16((a),(b),(c),0,0,0)

#define WREDUCE64(s) { s += __shfl_xor(s,1); s += __shfl_xor(s,2); s += __shfl_xor(s,4); \
                       s += __shfl_xor(s,8); s += __shfl_xor(s,16); s += __shfl_xor(s,32); }
#define QREDUCE16(s) { s += __shfl_xor(s,1); s += __shfl_xor(s,2); s += __shfl_xor(s,4); s += __shfl_xor(s,8); }

// 16-value butterfly within 16-lane quads: lane c (0..15) ends with sum-over-quad of val[c]
__device__ __forceinline__ float quad_butterfly16(float* val, int c){
  float v8[8], v4[4], v2[2];
  #pragma unroll
  for(int t=0;t<8;t++){
    float sent = (c&1) ? val[2*t] : val[2*t+1];
    float got = __shfl_xor(sent, 1);
    v8[t] = ((c&1) ? val[2*t+1] : val[2*t]) + got;
  }
  #pragma unroll
  for(int t=0;t<4;t++){
    float sent = ((c>>1)&1) ? v8[2*t] : v8[2*t+1];
    float got = __shfl_xor(sent, 2);
    v4[t] = (((c>>1)&1) ? v8[2*t+1] : v8[2*t]) + got;
  }
  #pragma unroll
  for(int t=0;t<2;t++){
    float sent = ((c>>2)&1) ? v4[2*t] : v4[2*t+1];
    float got = __shfl_xor(sent, 4);
    v2[t] = (((c>>2)&1) ? v4[2*t+1] : v4[2*t]) + got;
  }
  float sent = ((c>>3)&1) ? v2[0] : v2[1];
  float got = __shfl_xor(sent, 8);
  return (((c>>3)&1) ? v2[1] : v2[0]) + got;
}

// ---------------- ONE-SHOT prep: convert + all weight transposes (contiguous dst regions) ----------------
__global__ __launch_bounds__(256) void k_prep(const float* ele, const float* W_embed, const float* W_edge,
    const float* Wq, const float* Wk, const float* Wv, const float* Wr1, const float* Wo,
    const float* W1, const float* W2, const float* W_feat, const float* hW1, const float* hW2,
    u16* dst){
  int idx = blockIdx.x*256 + threadIdx.x;
  if(idx >= 405248) return;
  u16 v;
  if(idx < 3840){                    // ele convert
    v = f2bf(ele[idx]);
  } else if(idx < 5888){             // WembT: R=32,C=64,Rpad=32
    int l = idx - 3840;
    int cI = l >> 5, rI = l & 31;
    v = f2bf(W_embed[rI*64 + cI]);
  } else if(idx < 16128){            // WedgeT: R=137,C=64,Rpad=160
    int l = idx - 5888;
    int cI = l / 160, rI = l - cI*160;
    v = (rI < 137) ? f2bf(W_edge[rI*64 + cI]) : (u16)0;
  } else if(idx < 139008){           // Wq,Wk,Wv,Wr1,Wo: 5 x 6 x 64x64
    int l = idx - 16128;
    int which = l / 24576;
    int rem = l - which*24576;
    const float* src = (which==0)?Wq:(which==1)?Wk:(which==2)?Wv:(which==3)?Wr1:Wo;
    int b = rem >> 12;
    int r2 = rem & 4095;
    int cI = r2 >> 6, rI = r2 & 63;
    v = f2bf(src[b*4096 + rI*64 + cI]);
  } else if(idx < 237312){           // W1T: B=6,R=64,C=256,Rpad=64
    int l = idx - 139008;
    int b = l / 16384;
    int rem = l - b*16384;
    int cI = rem >> 6, rI = rem & 63;
    v = f2bf(W1[b*16384 + rI*256 + cI]);
  } else if(idx < 335616){           // W2T: B=6,R=256,C=64,Rpad=256
    int l = idx - 237312;
    int b = l / 16384;
    int rem = l - b*16384;
    int cI = rem >> 8, rI = rem & 255;
    v = f2bf(W2[b*16384 + rI*64 + cI]);
  } else if(idx < 368384){           // WfT: R=64,C=512,Rpad=64
    int l = idx - 335616;
    int cI = l >> 6, rI = l & 63;
    v = f2bf(W_feat[rI*512 + cI]);
  } else if(idx < 401152){           // hW1T: R=512,C=64,Rpad=512
    int l = idx - 368384;
    int cI = l >> 9, rI = l & 511;
    v = f2bf(hW1[rI*64 + cI]);
  } else {                           // hW2T: R=64,C=64
    int l = idx - 401152;
    int cI = l >> 6, rI = l & 63;
    v = f2bf(hW2[rI*64 + cI]);
  }
  dst[idx] = v;
}

// ---------------- CSR build ----------------
__global__ __launch_bounds__(256) void k_count(const int* dstI, int* deg, int E){
  int tid = blockIdx.x*256 + threadIdx.x;
  if(tid < E) atomicAdd(&deg[dstI[tid]], 1);
}
__global__ __launch_bounds__(1024) void k_scan(const int* deg, int* rowptr, int* cursor, int N){
  __shared__ int wsum[17];
  int tid = threadIdx.x;
  int per = (N + 1023) >> 10;
  int base = tid * per;
  int s = 0;
  for(int i=0;i<per;i++){ int idx = base+i; if(idx < N) s += deg[idx]; }
  int lane = tid & 63, wid = tid >> 6;
  int inc = s;
  for(int d=1; d<64; d<<=1){
    int t = __shfl_up(inc, d);
    if(lane >= d) inc += t;
  }
  if(lane == 63) wsum[wid+1] = inc;
  if(tid == 0) wsum[0] = 0;
  __syncthreads();
  if(tid == 0){ for(int w=1; w<=16; w++) wsum[w] += wsum[w-1]; }
  __syncthreads();
  int run = inc - s + wsum[wid];
  for(int i=0;i<per;i++){
    int idx = base + i;
    if(idx < N){ rowptr[idx] = run; cursor[idx] = run; run += deg[idx]; }
  }
  if(tid == 1023) rowptr[N] = wsum[16];
}
__global__ __launch_bounds__(256) void k_scatter(const int* dstI, int* cursor, int* csr, int E){
  int tid = blockIdx.x*256 + threadIdx.x;
  if(tid < E){
    int p = atomicAdd(&cursor[dstI[tid]], 1);
    csr[p] = tid;
  }
}

// ---------------- e = [nf_src, nf_dst, sh, rbf] @ W_edge in CSR-PERMUTED order ----------------
__global__ __launch_bounds__(256) void k_edge_embed(const int* csr, const int* srcI, const int* dstI,
    const int* atom, const u16* ele, const float* evec, const u16* Bt,
    u16* ebf, float* r2, int* src2, int* dst2, int E){
  int wave = (blockIdx.x*blockDim.x + threadIdx.x) >> 6;
  int lane = threadIdx.x & 63;
  int row0 = wave*16; if(row0 >= E) return;
  int c = lane & 15, q = lane >> 4;
  int p = row0 + c;
  int e = csr[p];
  int sn = srcI[e], dn = dstI[e];
  float vx = evec[(size_t)e*3+0];
  float vy = evec[(size_t)e*3+1];
  float vz = evec[(size_t)e*3+2];
  float r = sqrtf(vx*vx + vy*vy + vz*vz);
  if(q == 0){ r2[p] = r; src2[p] = sn; dst2[p] = dn; }
  float inv = 1.f/(r + 1e-12f);
  // u = edge_vec[:, [1,2,0]] / r -> x=v1, y=v2, z=v0
  float x = vy*inv, y = vz*inv, z = vx*inv;
  const float s3 = 1.7320508075688772f, s15 = 3.872983346207417f;
  const float s5h = 1.118033988749895f, s15h = 1.9364916731037085f;
  float sh[9];
  sh[0] = 1.f; sh[1] = s3*x; sh[2] = s3*y; sh[3] = s3*z;
  sh[4] = s15*x*y; sh[5] = s15*y*z; sh[6] = s5h*(3.f*z*z - 1.f);
  sh[7] = s15*x*z; sh[8] = s15h*(x*x - y*y);
  s8v a[5];
  a[0] = *reinterpret_cast<const s8v*>(ele + (size_t)atom[sn]*32 + q*8);
  a[1] = *reinterpret_cast<const s8v*>(ele + (size_t)atom[dn]*32 + q*8);
  #pragma unroll
  for(int j=0;j<8;j++){
    int col = 64 + q*8 + j;
    u16 v;
    if(q == 0)            v = f2bf(sh[j]);
    else if(col < 73)     v = f2bf(sh[8]);
    else { float d = r - (10.f/63.f)*(float)(col-73); v = f2bf(__expf(-81.92f*d*d)); }
    a[2][j] = (short)v;
  }
  #pragma unroll
  for(int j=0;j<8;j++){
    float d = r - (10.f/63.f)*(float)(23 + q*8 + j);
    a[3][j] = (short)f2bf(__expf(-81.92f*d*d));
  }
  #pragma unroll
  for(int j=0;j<8;j++){
    int col = 128 + q*8 + j;
    u16 v = 0;
    if(col < 137){ float d = r - (10.f/63.f)*(float)(col-73); v = f2bf(__expf(-81.92f*d*d)); }
    a[4][j] = (short)v;
  }
  #pragma unroll
  for(int ct=0; ct<4; ct++){
    f32x4 acc = {0.f,0.f,0.f,0.f};
    #pragma unroll
    for(int kc=0; kc<5; kc++){
      s8v b = *reinterpret_cast<const s8v*>(Bt + (ct*16+c)*160 + kc*32 + q*8);
      acc = MFMA(a[kc], b, acc);
    }
    #pragma unroll
    for(int r_=0;r_<4;r_++) ebf[(size_t)(row0+q*4+r_)*64 + ct*16 + c] = f2bf(acc[r_]);
  }
}

// ---------------- one-shot: radial[l][e][h] for all 6 layers (rbf frags built once) ----------------
__global__ __launch_bounds__(256) void k_radial6(const float* r2, const u16* Wr1T, const float* Wr2,
    float* rad6, int E){
  int wave = (blockIdx.x*256 + threadIdx.x) >> 6;
  int lane = threadIdx.x & 63;
  int row0 = wave*16; if(row0 >= E) return;
  int c = lane & 15, q = lane >> 4;
  float re = r2[row0 + c];
  s8v r0, r1;
  #pragma unroll
  for(int j=0;j<8;j++){
    float d0 = re - (10.f/63.f)*(float)(q*8+j);
    float d1 = re - (10.f/63.f)*(float)(32+q*8+j);
    r0[j] = (short)f2bf(__expf(-81.92f*d0*d0));
    r1[j] = (short)f2bf(__expf(-81.92f*d1*d1));
  }
  for(int l=0; l<6; l++){
    const u16* W1l = Wr1T + l*4096;
    const float4* wr2v = reinterpret_cast<const float4*>(Wr2 + l*256);
    float val[16];
    #pragma unroll
    for(int i=0;i<16;i++) val[i] = 0.f;
    #pragma unroll
    for(int ct=0; ct<4; ct++){
      s8v bw0 = *reinterpret_cast<const s8v*>(W1l + (ct*16+c)*64 + q*8);
      s8v bw1 = *reinterpret_cast<const s8v*>(W1l + (ct*16+c)*64 + 32 + q*8);
      f32x4 hacc = {0.f,0.f,0.f,0.f};
      hacc = MFMA(r0, bw0, hacc); hacc = MFMA(r1, bw1, hacc);
      float4 w2 = wr2v[ct*16 + c];
      #pragma unroll
      for(int r=0;r<4;r++){
        float y = hacc[r];
        float sv = y / (1.f + __expf(-y));
        val[r*4+0] += sv * w2.x;
        val[r*4+1] += sv * w2.y;
        val[r*4+2] += sv * w2.z;
        val[r*4+3] += sv * w2.w;
      }
    }
    float fin = quad_butterfly16(val, c);
    rad6[(size_t)l*E*4 + (size_t)row0*4 + lane] = fin;
  }
}

// ---------------- pre: x = ele[atom]@Wemb; h0 = LN(x); Q0 = h0@Wq0 (Qt layout) ----------------
__global__ __launch_bounds__(256) void k_pre(const int* atom, const u16* ele, const u16* WembT,
    const u16* WqT0, float* xb, u16* hbf, float* Qt, int M){
  __shared__ u16 ldsH[4][16*72];
  int widL = threadIdx.x >> 6;
  int wave = (blockIdx.x*256 + threadIdx.x) >> 6;
  int lane = threadIdx.x & 63;
  int row0 = wave*16; if(row0 >= M) return;
  int c = lane & 15, q = lane >> 4;
  u16* LH = ldsH[widL];
  int at = atom[row0 + c];
  s8v a = *reinterpret_cast<const s8v*>(ele + (size_t)at*32 + q*8);
  float nx[4][4];
  #pragma unroll
  for(int ct=0; ct<4; ct++){
    s8v b = *reinterpret_cast<const s8v*>(WembT + (ct*16+c)*32 + q*8);
    f32x4 acc = {0.f,0.f,0.f,0.f};
    acc = MFMA(a, b, acc);
    #pragma unroll
    for(int r=0;r<4;r++){
      xb[(size_t)(row0+q*4+r)*64 + ct*16 + c] = acc[r];
      nx[ct][r] = acc[r];
    }
  }
  #pragma unroll
  for(int r=0;r<4;r++){
    float s = nx[0][r]+nx[1][r]+nx[2][r]+nx[3][r];
    QREDUCE16(s);
    float m = s*(1.f/64.f);
    float vv = 0.f;
    #pragma unroll
    for(int ct=0;ct<4;ct++){ float d = nx[ct][r]-m; vv += d*d; }
    QREDUCE16(vv);
    float rs = rsqrtf(vv*(1.f/64.f) + 1e-6f);
    #pragma unroll
    for(int ct=0;ct<4;ct++){
      u16 hb = f2bf((nx[ct][r]-m)*rs);
      hbf[(size_t)(row0+q*4+r)*64 + ct*16 + c] = hb;
      LH[(q*4+r)*72 + ct*16 + c] = hb;
    }
  }
  s8v h0 = *reinterpret_cast<const s8v*>(LH + c*72 + q*8);
  s8v h1 = *reinterpret_cast<const s8v*>(LH + c*72 + 32 + q*8);
  #pragma unroll
  for(int ct=0; ct<4; ct++){
    s8v b0 = *reinterpret_cast<const s8v*>(WqT0 + (ct*16+c)*64 + q*8);
    s8v b1 = *reinterpret_cast<const s8v*>(WqT0 + (ct*16+c)*64 + 32 + q*8);
    f32x4 acc = {0.f,0.f,0.f,0.f};
    acc = MFMA(h0, b0, acc);
    acc = MFMA(h1, b1, acc);
    #pragma unroll
    for(int r=0;r<4;r++) Qt[(size_t)(row0+q*4+r)*64 + c*4 + ct] = acc[r];
  }
}

// ---------------- fused k,v MFMAs + qk logits (butterfly) + radial table + exp ----------------
__global__ __launch_bounds__(256) void k_kvrad(const u16* hbf, const u16* ebf,
    const int* src2, const int* dst2, const float* Qt, const float* r2, const float* radial,
    const u16* WkT, const u16* WvT, u16* vbf, float* exb, int E){
  int wave = (blockIdx.x*256 + threadIdx.x) >> 6;
  int lane = threadIdx.x & 63;
  int row0 = wave*16;
  int c = lane & 15, q = lane >> 4;
  int sr = src2[row0 + c];
  s8v a0, a1;
  {
    s8v h0 = *reinterpret_cast<const s8v*>(hbf + (size_t)sr*64 + q*8);
    s8v h1 = *reinterpret_cast<const s8v*>(hbf + (size_t)sr*64 + 32 + q*8);
    s8v e0 = *reinterpret_cast<const s8v*>(ebf + (size_t)(row0+c)*64 + q*8);
    s8v e1 = *reinterpret_cast<const s8v*>(ebf + (size_t)(row0+c)*64 + 32 + q*8);
    #pragma unroll
    for(int j=0;j<8;j++){
      a0[j] = (short)f2bf(bf2f((u16)h0[j]) + bf2f((u16)e0[j]));
      a1[j] = (short)f2bf(bf2f((u16)h1[j]) + bf2f((u16)e1[j]));
    }
  }
  const float4* QtV = reinterpret_cast<const float4*>(Qt);
  float4 qv[4];
  #pragma unroll
  for(int r=0;r<4;r++){
    int dr = dst2[row0 + q*4 + r];
    qv[r] = QtV[(size_t)dr*16 + c];
  }
  float val[16];
  #pragma unroll
  for(int i=0;i<16;i++) val[i] = 0.f;
  #pragma unroll
  for(int ct=0; ct<4; ct++){
    s8v bk0 = *reinterpret_cast<const s8v*>(WkT + (ct*16+c)*64 + q*8);
    s8v bk1 = *reinterpret_cast<const s8v*>(WkT + (ct*16+c)*64 + 32 + q*8);
    s8v bv0 = *reinterpret_cast<const s8v*>(WvT + (ct*16+c)*64 + q*8);
    s8v bv1 = *reinterpret_cast<const s8v*>(WvT + (ct*16+c)*64 + 32 + q*8);
    f32x4 kacc = {0.f,0.f,0.f,0.f};
    kacc = MFMA(a0, bk0, kacc); kacc = MFMA(a1, bk1, kacc);
    f32x4 vacc = {0.f,0.f,0.f,0.f};
    vacc = MFMA(a0, bv0, vacc); vacc = MFMA(a1, bv1, vacc);
    #pragma unroll
    for(int r=0;r<4;r++){
      vbf[(size_t)row0*64 + (r*4+ct)*64 + q*16 + c] = f2bf(vacc[r]);
      float qc = (ct==0)?qv[r].x:(ct==1)?qv[r].y:(ct==2)?qv[r].z:qv[r].w;
      val[r*4+ct] += 0.25f * kacc[r] * qc;
    }
  }
  float qk = quad_butterfly16(val, c);   // lane c: (r=c>>2, h=c&3)
  float logit = qk + radial[(size_t)row0*4 + lane];
  int row = row0 + q*4 + (c>>2);
  exb[(size_t)row0*4 + lane] = (r2[row] < 10.f) ? __expf(logit) : 0.f;
}

// ---------------- softmax-denominator + aggregation; edges contiguous per node ----------------
__global__ __launch_bounds__(256) void k_agg(const int* rowptr, const float* exb, const u16* vbf, u16* aggbf, int N){
  int wave = (blockIdx.x*256 + threadIdx.x) >> 6;
  int lane = threadIdx.x & 63;
  if(wave >= N) return;
  int s0 = rowptr[wave], s1 = rowptr[wave+1];
  float s[4] = {0.f,0.f,0.f,0.f};
  for(int p = s0 + lane; p < s1; p += 64){
    float4 ev = *reinterpret_cast<const float4*>(exb + (size_t)p*4);
    s[0] += ev.x; s[1] += ev.y; s[2] += ev.z; s[3] += ev.w;
  }
  #pragma unroll
  for(int i=0;i<4;i++){ WREDUCE64(s[i]); }
  int ep = lane >> 4, cc = lane & 15;
  int hh = cc >> 2;
  int swz = hh*64 + (cc&3)*4;
  float inv = 1.f/(s[hh] + 1e-9f);
  float a0=0.f, a1=0.f, a2=0.f, a3=0.f;
  for(int p = s0 + ep; p < s1; p += 4){
    int t = p & 15;
    size_t base = (size_t)(p & ~15)*64 + (size_t)((t&3)*256) + (size_t)((t>>2)*16) + swz;
    ushort4 v4 = *reinterpret_cast<const ushort4*>(vbf + base);
    float ex = exb[(size_t)p*4 + hh];
    a0 += ex*bf2f(v4.x); a1 += ex*bf2f(v4.y); a2 += ex*bf2f(v4.z); a3 += ex*bf2f(v4.w);
  }
  a0 += __shfl_xor(a0,16); a0 += __shfl_xor(a0,32);
  a1 += __shfl_xor(a1,16); a1 += __shfl_xor(a1,32);
  a2 += __shfl_xor(a2,16); a2 += __shfl_xor(a2,32);
  a3 += __shfl_xor(a3,16); a3 += __shfl_xor(a3,32);
  if(ep == 0){
    ushort4 o;
    o.x = f2bf(a0*inv); o.y = f2bf(a1*inv); o.z = f2bf(a2*inv); o.w = f2bf(a3*inv);
    *reinterpret_cast<ushort4*>(aggbf + (size_t)wave*64 + cc*4) = o;
  }
}

// ---------------- MEGA: x+=agg@Wo; LN; FFN1; FFN2+residual; LN->hbf; Q_next->Qt ----------------
__global__ __launch_bounds__(256) void k_mega(const u16* aggbf, const u16* WoT, float* x,
    const u16* W1T, const u16* W2T, const u16* WqTn, float* Qt, u16* hbf, u16* xbf,
    int writex, int haveQ, int M){
  __shared__ u16 ldsH[4][16*72];
  __shared__ u16 ldsT[4][16*264];
  int widL = threadIdx.x >> 6;
  int wave = (blockIdx.x*256 + threadIdx.x) >> 6;
  int lane = threadIdx.x & 63;
  int row0 = wave*16; if(row0 >= M) return;
  int c = lane & 15, q = lane >> 4;
  u16* LH = ldsH[widL];
  u16* LT = ldsT[widL];
  {
    s8v a0 = *reinterpret_cast<const s8v*>(aggbf + (size_t)(row0+c)*64 + q*8);
    s8v a1 = *reinterpret_cast<const s8v*>(aggbf + (size_t)(row0+c)*64 + 32 + q*8);
    float nx[4][4];
    #pragma unroll
    for(int ct=0; ct<4; ct++){
      s8v b0 = *reinterpret_cast<const s8v*>(WoT + (ct*16+c)*64 + q*8);
      s8v b1 = *reinterpret_cast<const s8v*>(WoT + (ct*16+c)*64 + 32 + q*8);
      f32x4 acc = {0.f,0.f,0.f,0.f};
      acc = MFMA(a0, b0, acc);
      acc = MFMA(a1, b1, acc);
      #pragma unroll
      for(int r=0;r<4;r++){
        size_t idx = (size_t)(row0+q*4+r)*64 + ct*16 + c;
        float t = x[idx] + acc[r];
        x[idx] = t;
        nx[ct][r] = t;
      }
    }
    #pragma unroll
    for(int r=0;r<4;r++){
      float s = nx[0][r]+nx[1][r]+nx[2][r]+nx[3][r];
      QREDUCE16(s);
      float m = s*(1.f/64.f);
      float vv = 0.f;
      #pragma unroll
      for(int ct=0;ct<4;ct++){ float d = nx[ct][r]-m; vv += d*d; }
      QREDUCE16(vv);
      float rs = rsqrtf(vv*(1.f/64.f) + 1e-6f);
      #pragma unroll
      for(int ct=0;ct<4;ct++)
        LH[(q*4+r)*72 + ct*16 + c] = f2bf((nx[ct][r]-m)*rs);
    }
  }
  {
    s8v h0 = *reinterpret_cast<const s8v*>(LH + c*72 + q*8);
    s8v h1 = *reinterpret_cast<const s8v*>(LH + c*72 + 32 + q*8);
    #pragma unroll
    for(int ct=0; ct<16; ct++){
      s8v b0 = *reinterpret_cast<const s8v*>(W1T + (ct*16+c)*64 + q*8);
      s8v b1 = *reinterpret_cast<const s8v*>(W1T + (ct*16+c)*64 + 32 + q*8);
      f32x4 acc = {0.f,0.f,0.f,0.f};
      acc = MFMA(h0, b0, acc);
      acc = MFMA(h1, b1, acc);
      #pragma unroll
      for(int r=0;r<4;r++){
        float y = acc[r];
        LT[(q*4+r)*264 + ct*16 + c] = f2bf(y / (1.f + __expf(-y)));
      }
    }
  }
  {
    s8v a[8];
    #pragma unroll
    for(int kc=0; kc<8; kc++)
      a[kc] = *reinterpret_cast<const s8v*>(LT + c*264 + kc*32 + q*8);
    float nx[4][4];
    #pragma unroll
    for(int ct=0; ct<4; ct++){
      f32x4 acc = {0.f,0.f,0.f,0.f};
      #pragma unroll
      for(int kc=0; kc<8; kc++){
        s8v b = *reinterpret_cast<const s8v*>(W2T + (ct*16+c)*256 + kc*32 + q*8);
        acc = MFMA(a[kc], b, acc);
      }
      #pragma unroll
      for(int r=0;r<4;r++){
        size_t idx = (size_t)(row0+q*4+r)*64 + ct*16 + c;
        float t = x[idx] + acc[r];
        x[idx] = t;
        nx[ct][r] = t;
        if(writex) xbf[idx] = f2bf(t);
      }
    }
    #pragma unroll
    for(int r=0;r<4;r++){
      float s = nx[0][r]+nx[1][r]+nx[2][r]+nx[3][r];
      QREDUCE16(s);
      float m = s*(1.f/64.f);
      float vv = 0.f;
      #pragma unroll
      for(int ct=0;ct<4;ct++){ float d = nx[ct][r]-m; vv += d*d; }
      QREDUCE16(vv);
      float rs = rsqrtf(vv*(1.f/64.f) + 1e-6f);
      #pragma unroll
      for(int ct=0;ct<4;ct++){
        u16 hb = f2bf((nx[ct][r]-m)*rs);
        hbf[(size_t)(row0+q*4+r)*64 + ct*16 + c] = hb;
        LH[(q*4+r)*72 + ct*16 + c] = hb;
      }
    }
  }
  if(haveQ){
    s8v h0 = *reinterpret_cast<const s8v*>(LH + c*72 + q*8);
    s8v h1 = *reinterpret_cast<const s8v*>(LH + c*72 + 32 + q*8);
    #pragma unroll
    for(int ct=0; ct<4; ct++){
      s8v b0 = *reinterpret_cast<const s8v*>(WqTn + (ct*16+c)*64 + q*8);
      s8v b1 = *reinterpret_cast<const s8v*>(WqTn + (ct*16+c)*64 + 32 + q*8);
      f32x4 acc = {0.f,0.f,0.f,0.f};
      acc = MFMA(h0, b0, acc);
      acc = MFMA(h1, b1, acc);
      #pragma unroll
      for(int r=0;r<4;r++) Qt[(size_t)(row0+q*4+r)*64 + c*4 + ct] = acc[r];
    }
  }
}

// ---------------- feat = x @ W_feat with in-register LN over 512 -> featbf ----------------
__global__ __launch_bounds__(256) void k_feat_ln(const u16* A, const u16* Bt, u16* out, int M){
  int wave = (blockIdx.x*256 + threadIdx.x) >> 6;
  int lane = threadIdx.x & 63;
  int row0 = wave*16; if(row0 >= M) return;
  int c = lane & 15, q = lane >> 4;
  s8v a0 = *reinterpret_cast<const s8v*>(A + (size_t)(row0+c)*64 + q*8);
  s8v a1 = *reinterpret_cast<const s8v*>(A + (size_t)(row0+c)*64 + 32 + q*8);
  float fa[32][4];
  #pragma unroll
  for(int ct=0; ct<32; ct++){
    s8v b0 = *reinterpret_cast<const s8v*>(Bt + (ct*16+c)*64 + q*8);
    s8v b1 = *reinterpret_cast<const s8v*>(Bt + (ct*16+c)*64 + 32 + q*8);
    f32x4 acc = {0.f,0.f,0.f,0.f};
    acc = MFMA(a0, b0, acc);
    acc = MFMA(a1, b1, acc);
    #pragma unroll
    for(int r=0;r<4;r++) fa[ct][r] = acc[r];
  }
  #pragma unroll
  for(int r=0;r<4;r++){
    float s = 0.f;
    #pragma unroll
    for(int ct=0;ct<32;ct++) s += fa[ct][r];
    QREDUCE16(s);
    float m = s*(1.f/512.f);
    float vv = 0.f;
    #pragma unroll
    for(int ct=0;ct<32;ct++){ float d = fa[ct][r]-m; vv += d*d; }
    QREDUCE16(vv);
    float rs = rsqrtf(vv*(1.f/512.f) + 1e-6f);
    #pragma unroll
    for(int ct=0;ct<32;ct++)
      out[(size_t)(row0+q*4+r)*512 + ct*16 + c] = f2bf((fa[ct][r]-m)*rs);
  }
}

// ---------------- head1 (K=512) + bias + LN + relu -> hh1 ----------------
__global__ __launch_bounds__(256) void k_head1_ln(const u16* A, const u16* Bt, const float* hb, u16* out, int M){
  int wave = (blockIdx.x*256 + threadIdx.x) >> 6;
  int lane = threadIdx.x & 63;
  int row0 = wave*16; if(row0 >= M) return;
  int c = lane & 15, q = lane >> 4;
  s8v a[16];
  #pragma unroll
  for(int kc=0; kc<16; kc++)
    a[kc] = *reinterpret_cast<const s8v*>(A + (size_t)(row0+c)*512 + kc*32 + q*8);
  float y[4][4];
  #pragma unroll
  for(int ct=0; ct<4; ct++){
    f32x4 acc = {0.f,0.f,0.f,0.f};
    #pragma unroll
    for(int kc=0; kc<16; kc++){
      s8v b = *reinterpret_cast<const s8v*>(Bt + (size_t)(ct*16+c)*512 + kc*32 + q*8);
      acc = MFMA(a[kc], b, acc);
    }
    float bi = hb[ct*16+c];
    #pragma unroll
    for(int r=0;r<4;r++) y[ct][r] = acc[r] + bi;
  }
  #pragma unroll
  for(int r=0;r<4;r++){
    float s = y[0][r]+y[1][r]+y[2][r]+y[3][r];
    QREDUCE16(s);
    float m = s*(1.f/64.f);
    float vv = 0.f;
    #pragma unroll
    for(int ct=0;ct<4;ct++){ float d = y[ct][r]-m; vv += d*d; }
    QREDUCE16(vv);
    float rs = rsqrtf(vv*(1.f/64.f) + 1e-6f);
    #pragma unroll
    for(int ct=0;ct<4;ct++)
      out[(size_t)(row0+q*4+r)*64 + ct*16 + c] = f2bf(fmaxf((y[ct][r]-m)*rs, 0.f));
  }
}

// ---------------- head2 + bias + LN + relu + dot(hW3) + pooled atomicAdd ----------------
__global__ __launch_bounds__(256) void k_head2_energy(const u16* A, const u16* Bt, const float* hb,
    const float* hW3, const float* hb3, const int* batch, float* pooled, int M){
  int wave = (blockIdx.x*256 + threadIdx.x) >> 6;
  int lane = threadIdx.x & 63;
  int row0 = wave*16; if(row0 >= M) return;
  int c = lane & 15, q = lane >> 4;
  s8v a0 = *reinterpret_cast<const s8v*>(A + (size_t)(row0+c)*64 + q*8);
  s8v a1 = *reinterpret_cast<const s8v*>(A + (size_t)(row0+c)*64 + 32 + q*8);
  float y[4][4];
  #pragma unroll
  for(int ct=0; ct<4; ct++){
    s8v b0 = *reinterpret_cast<const s8v*>(Bt + (ct*16+c)*64 + q*8);
    s8v b1 = *reinterpret_cast<const s8v*>(Bt + (ct*16+c)*64 + 32 + q*8);
    f32x4 acc = {0.f,0.f,0.f,0.f};
    acc = MFMA(a0, b0, acc);
    acc = MFMA(a1, b1, acc);
    float bi = hb[ct*16+c];
    #pragma unroll
    for(int r=0;r<4;r++) y[ct][r] = acc[r] + bi;
  }
  float w3[4];
  #pragma unroll
  for(int ct=0;ct<4;ct++) w3[ct] = hW3[ct*16+c];
  float ep[4];
  #pragma unroll
  for(int r=0;r<4;r++){
    float s = y[0][r]+y[1][r]+y[2][r]+y[3][r];
    QREDUCE16(s);
    float m = s*(1.f/64.f);
    float vv = 0.f;
    #pragma unroll
    for(int ct=0;ct<4;ct++){ float d = y[ct][r]-m; vv += d*d; }
    QREDUCE16(vv);
    float rs = rsqrtf(vv*(1.f/64.f) + 1e-6f);
    float e = 0.f;
    #pragma unroll
    for(int ct=0;ct<4;ct++) e += fmaxf((y[ct][r]-m)*rs, 0.f) * w3[ct];
    QREDUCE16(e);
    ep[r] = e;
  }
  if(c < 4){
    float ev = (c==0)?ep[0]:(c==1)?ep[1]:(c==2)?ep[2]:ep[3];
    int row = row0 + q*4 + c;
    atomicAdd(&pooled[batch[row]], ev + hb3[0]);
  }
}

// ---------------- output f32 ----------------
__global__ __launch_bounds__(256) void k_out(const float* pooled, float* out, int G){
  int tid = blockIdx.x*256 + threadIdx.x;
  if(tid < G) out[tid] = pooled[tid] * 0.11785113019775793f; // 1/sqrt(72)
}

extern "C" void kernel_launch(void* const* d_in, const int* in_sizes, int n_in,
                              void* d_out, int out_size, void* d_ws, size_t ws_size,
                              hipStream_t stream){
  const int*   edge_src  = (const int*)d_in[1];
  const int*   edge_dst  = (const int*)d_in[2];
  const float* edge_vec  = (const float*)d_in[3];
  const int*   batch     = (const int*)d_in[4];
  const int*   node_atom = (const int*)d_in[5];
  const float* ele    = (const float*)d_in[6];
  const float* W_embed= (const float*)d_in[7];
  const float* W_edge = (const float*)d_in[8];
  const float* Wq = (const float*)d_in[9];
  const float* Wk = (const float*)d_in[10];
  const float* Wv = (const float*)d_in[11];
  const float* Wr1= (const float*)d_in[12];
  const float* Wr2= (const float*)d_in[13];
  const float* Wo = (const float*)d_in[14];
  const float* W1 = (const float*)d_in[15];
  const float* W2 = (const float*)d_in[16];
  const float* W_feat=(const float*)d_in[17];
  const float* hW1= (const float*)d_in[18];
  const float* hb1= (const float*)d_in[19];
  const float* hW2= (const float*)d_in[20];
  const float* hb2= (const float*)d_in[21];
  const float* hW3= (const float*)d_in[22];
  const float* hb3= (const float*)d_in[23];
  (void)n_in; (void)ws_size;

  const int E = in_sizes[1];
  const int N = in_sizes[4];
  const int G = out_size;

  // ---- workspace layout: peak ~113 MB ----
  char* base = (char*)d_ws;
  size_t off = 0;
  #define ALLOC(ty, name, count) ty* name = (ty*)(base + off); off = (off + (size_t)(count)*sizeof(ty) + 255) & ~(size_t)255;
  ALLOC(float, r2,    E)
  ALLOC(int,   src2,  E)
  ALLOC(int,   dst2,  E)
  ALLOC(u16,   ebf,   (size_t)E*64)
  ALLOC(u16,   vbf,   (size_t)E*64)
  ALLOC(float, exb,   (size_t)E*4)
  ALLOC(float, rad6,  (size_t)E*4*6)
  ALLOC(u16,   hbf,   (size_t)N*64)
  ALLOC(u16,   aggbf, (size_t)N*64)
  ALLOC(u16,   xbf,   (size_t)N*64)
  ALLOC(float, Qt,    (size_t)N*64)
  ALLOC(float, xb,    (size_t)N*64)
  ALLOC(int,   deg,   N)
  ALLOC(int,   rowptr,N+1)
  ALLOC(int,   cursor,N)
  ALLOC(int,   csr,   E)
  ALLOC(float, pooled,G)
  // contiguous prep-region (all counts x2 bytes are 256-multiples; no gaps)
  ALLOC(u16, ele_bf, 120*32)        // [0,3840)
  ALLOC(u16, WembT, 64*32)          // [3840,5888)
  ALLOC(u16, WedgeT,64*160)         // [5888,16128)
  ALLOC(u16, WqT,  6*64*64)         // [16128, ...)
  ALLOC(u16, WkT,  6*64*64)
  ALLOC(u16, WvT,  6*64*64)
  ALLOC(u16, Wr1T, 6*64*64)
  ALLOC(u16, WoT,  6*64*64)
  ALLOC(u16, W1T,  6*256*64)
  ALLOC(u16, W2T,  6*64*256)
  ALLOC(u16, WfT,  512*64)
  ALLOC(u16, hW1T, 64*512)
  ALLOC(u16, hW2T, 64*64)
  #undef ALLOC
  // tail aliases into loop-dead regions:
  u16* featbf = ebf;          // 16 MB <= 32 MB
  u16* hh1    = (u16*)exb;    // 2 MB <= 4 MB

  auto cdiv = [](int a, int b){ return (a + b - 1)/b; };

  k_prep<<<cdiv(405248,256),256,0,stream>>>(ele, W_embed, W_edge, Wq, Wk, Wv, Wr1, Wo,
                                            W1, W2, W_feat, hW1, hW2, ele_bf);

  hipMemsetAsync(deg, 0, (size_t)N*sizeof(int), stream);
  hipMemsetAsync(pooled, 0, (size_t)G*sizeof(float), stream);

  k_count<<<cdiv(E,256),256,0,stream>>>(edge_dst, deg, E);
  k_scan<<<1,1024,0,stream>>>(deg, rowptr, cursor, N);
  k_scatter<<<cdiv(E,256),256,0,stream>>>(edge_dst, cursor, csr, E);
  k_edge_embed<<<E/64, 256, 0, stream>>>(csr, edge_src, edge_dst, node_atom, ele_bf, edge_vec,
                                         WedgeT, ebf, r2, src2, dst2, E);
  k_radial6<<<E/64,256,0,stream>>>(r2, Wr1T, Wr2, rad6, E);
  k_pre<<<N/64,256,0,stream>>>(node_atom, ele_bf, WembT, WqT, xb, hbf, Qt, N);

  for(int l=0; l<6; l++){
    k_kvrad<<<E/64,256,0,stream>>>(hbf, ebf, src2, dst2, Qt, r2, rad6 + (size_t)l*E*4,
                                   WkT + l*4096, WvT + l*4096, vbf, exb, E);
    k_agg<<<cdiv(N,4),256,0,stream>>>(rowptr, exb, vbf, aggbf, N);
    k_mega<<<N/64,256,0,stream>>>(aggbf, WoT + l*4096, xb,
                                  W1T + l*16384, W2T + l*16384,
                                  WqT + ((l<5)?(l+1):0)*4096, Qt, hbf, xbf,
                                  (l==5)?1:0, (l<5)?1:0, N);
  }

  k_feat_ln<<<N/64,256,0,stream>>>(xbf, WfT, featbf, N);
  k_head1_ln<<<N/64,256,0,stream>>>(featbf, hW1T, hb1, hh1, N);
  k_head2_energy<<<N/64,256,0,stream>>>(hh1, hW2T, hb2, hW3, hb3, batch, pooled, N);
  k_out<<<cdiv(G,256),256,0,stream>>>(pooled, (float*)d_out, G);
}